// Round 15
// baseline (424.017 us; speedup 1.0000x reference)
//
#include <hip/hip_runtime.h>
#include <hip/hip_bf16.h>
#include <stdint.h>

#define BB 4
#define SS 1024
#define DIM 2048
#define NH 16
#define QR 1024
#define KVR 512
#define NOPE 128
#define ROPE 64
#define VH 128
#define QKH 192
#define NTOK 4096
#define NFUSE 1600   // QR + 576

static constexpr float SCALE_ = 0.07216878364870322f; // 192^-0.5
static constexpr float EPS_ = 1e-6f;

typedef unsigned short u16;
typedef unsigned int u32;
using f32x4  = __attribute__((ext_vector_type(4))) float;
using bf16x8 = __attribute__((ext_vector_type(8))) __bf16;

#define MFMA16 __builtin_amdgcn_mfma_f32_16x16x32_bf16

__device__ __forceinline__ u16 f2b(float f) {
  u32 u = __float_as_uint(f);
  u32 r = u + 0x7fffu + ((u >> 16) & 1u);   // RNE
  return (u16)(r >> 16);
}
__device__ __forceinline__ u32 pk2(float a, float b) {
  return (u32)f2b(a) | ((u32)f2b(b) << 16);
}
__device__ __forceinline__ float b2f(u32 hi16) {
  return __uint_as_float(hi16 << 16);
}
__device__ __forceinline__ void gll16(const u16* g, u16* l) {
  __builtin_amdgcn_global_load_lds(
      (const __attribute__((address_space(1))) void*)g,
      (__attribute__((address_space(3))) void*)l, 16, 0, 0);
}

// ---------------- fused f32->bf16 conversions (6 regions, 1 launch) ----------------
__global__ __launch_bounds__(256) void cvt_all(
    const float* __restrict__ x, u16* __restrict__ x_bf,
    const float* __restrict__ wqa, const float* __restrict__ wkva,
    u16* __restrict__ wcat,
    const float* __restrict__ wqb, u16* __restrict__ wqb_b,
    const float* __restrict__ wo, u16* __restrict__ wo_b,
    const float* __restrict__ wkvb, u16* __restrict__ wbv) {
  int bid = blockIdx.x;
  const float* src; u16* dst; long i;
  if (bid < 4096)      { src = x;    dst = x_bf;  i = (long)bid * 2048; }
  else if (bid < 5120) { src = wqa;  dst = wcat;  i = (long)(bid - 4096) * 2048; }
  else if (bid < 6656) { src = wqb;  dst = wqb_b; i = (long)(bid - 5120) * 2048; }
  else if (bid < 7232) { src = wkva; dst = wcat + (long)QR * DIM; i = (long)(bid - 6656) * 2048; }
  else if (bid < 9280) { src = wo;   dst = wo_b;  i = (long)(bid - 7232) * 2048; }
  else {  // wbv: head h, rem over (128 x 512)
    long e = (long)(bid - 9280) * 2048;
    int h = (int)(e >> 16);
    int rem = (int)(e & 65535);
    src = wkvb + (((long)h * 256 + 128) << 9) + rem;
    dst = wbv + ((long)h << 16) + rem;
    i = 0;
  }
  i += threadIdx.x * 8;
  float4 a = *(const float4*)&src[i];
  float4 b = *(const float4*)&src[i + 4];
  uint4 o;
  o.x = pk2(a.x, a.y); o.y = pk2(a.z, a.w);
  o.z = pk2(b.x, b.y); o.w = pk2(b.z, b.w);
  *(uint4*)&dst[i] = o;
}

// ---------------- wbkt transpose: (h, dr<128, c) -> wbkt (h, c, dr), coalesced via LDS ----------------
__global__ __launch_bounds__(256) void wbkt_tr(const float* __restrict__ wkvb,
                                               u16* __restrict__ wbkt) {
  const int c0 = blockIdx.x * 64, dr0 = blockIdx.y * 64, h = blockIdx.z;
  const int tid = threadIdx.x;
  __shared__ u16 L[64][72];
  {
    int row = tid >> 2, cq = (tid & 3) * 16;
    const float* p = wkvb + (((long)h * 256 + dr0 + row) << 9) + c0 + cq;
    float4 v0 = *(const float4*)&p[0];
    float4 v1 = *(const float4*)&p[4];
    float4 v2 = *(const float4*)&p[8];
    float4 v3 = *(const float4*)&p[12];
    uint2 w0, w1;
    w0.x = pk2(v0.x, v0.y); w0.y = pk2(v0.z, v0.w);
    w1.x = pk2(v1.x, v1.y); w1.y = pk2(v1.z, v1.w);
    *(uint2*)&L[row][cq]     = w0;
    *(uint2*)&L[row][cq + 4] = w1;
    w0.x = pk2(v2.x, v2.y); w0.y = pk2(v2.z, v2.w);
    w1.x = pk2(v3.x, v3.y); w1.y = pk2(v3.z, v3.w);
    *(uint2*)&L[row][cq + 8]  = w0;
    *(uint2*)&L[row][cq + 12] = w1;
  }
  __syncthreads();
  {
    int crow = tid >> 2, dq = (tid & 3) * 16;
    u16 tmp[16];
#pragma unroll
    for (int e = 0; e < 16; ++e) tmp[e] = L[dq + e][crow];
    u16* dst = wbkt + (((long)h * 512 + c0 + crow) << 7) + dr0 + dq;
    *(uint4*)&dst[0] = *(uint4*)&tmp[0];
    *(uint4*)&dst[8] = *(uint4*)&tmp[8];
  }
}

// ---------------- RMSNorm over 1024 (q path), C1 ldc=1600 ----------------
__global__ __launch_bounds__(256) void rms_q_kernel(const float* __restrict__ X,
                                                    const float* __restrict__ w,
                                                    u16* __restrict__ out) {
  int r = blockIdx.x, tid = threadIdx.x;
  const float4 v = *(const float4*)&X[(long)r * NFUSE + tid * 4];
  float ss = v.x * v.x + v.y * v.y + v.z * v.z + v.w * v.w;
  for (int m = 1; m < 64; m <<= 1) ss += __shfl_xor(ss, m);
  __shared__ float red[4];
  if ((tid & 63) == 0) red[tid >> 6] = ss;
  __syncthreads();
  float tot = red[0] + red[1] + red[2] + red[3];
  float sc = rsqrtf(tot / QR + EPS_);
  float4 wv = *(const float4*)&w[tid * 4];
  uint2 o;
  o.x = pk2(v.x * sc * wv.x, v.y * sc * wv.y);
  o.y = pk2(v.z * sc * wv.z, v.w * sc * wv.w);
  *(uint2*)&out[(long)r * QR + tid * 4] = o;
}

// ---------------- q post (bf16 input): split nope / rope(pe)*SCALE, head-major ----------------
__global__ __launch_bounds__(256) void post_q_kernel(const u16* __restrict__ C2,
                                                     const float* __restrict__ fc,
                                                     const float* __restrict__ fs,
                                                     u16* __restrict__ qn,
                                                     u16* __restrict__ qp) {
  int r = blockIdx.x, tid = threadIdx.x;
  int s = r & (SS - 1);
  const u16* row = C2 + (long)r * (NH * QKH);
  for (int j = tid; j < NH * QKH / 2; j += 256) {
    int col = j * 2;
    int h = col / QKH;
    int dd = col - h * QKH;
    u32 pair = *(const u32*)&row[col];
    if (dd < NOPE) {
      *(u32*)&qn[((long)h * NTOK + r) * NOPE + dd] = pair;   // already bf16
    } else {
      float x0 = b2f(pair & 0xffffu), x1 = b2f(pair >> 16);
      int jr = (dd - NOPE) >> 1;
      float c = fc[s * 32 + jr], sn = fs[s * 32 + jr];
      *(u32*)&qp[((long)h * NTOK + r) * ROPE + (dd - NOPE)] =
          pk2((x0 * c - x1 * sn) * SCALE_, (x0 * sn + x1 * c) * SCALE_);
    }
  }
}

// ---------------- kv post: rmsnorm(512) -> kv_sw (XOR-swizzled) + v8 (k-subtiled), rope k_pe_sw ----
__global__ __launch_bounds__(256) void post_kv_kernel(const float* __restrict__ C3,
                                                      const float* __restrict__ w,
                                                      const float* __restrict__ fc,
                                                      const float* __restrict__ fs,
                                                      u16* __restrict__ kv_sw,
                                                      u16* __restrict__ v8,
                                                      u16* __restrict__ kpe_sw) {
  int r = blockIdx.x, tid = threadIdx.x;
  int b = r >> 10, t = r & (SS - 1);
  const float* row = C3 + (long)r * NFUSE + QR;
  float2 v = *(const float2*)&row[tid * 2];
  float ss = v.x * v.x + v.y * v.y;
  for (int m = 1; m < 64; m <<= 1) ss += __shfl_xor(ss, m);
  __shared__ float red[4];
  if ((tid & 63) == 0) red[tid >> 6] = ss;
  __syncthreads();
  float tot = red[0] + red[1] + red[2] + red[3];
  float sc = rsqrtf(tot / KVR + EPS_);
  int c = tid * 2;
  int xm = (t & 7) << 3;
  float y0 = v.x * sc * w[c], y1 = v.y * sc * w[c + 1];
  *(u32*)&kv_sw[((long)b * SS + t) * KVR + (c ^ xm)] = pk2(y0, y1);
  long o8 = (long)b * SS * KVR + ((long)(t >> 3) * 512 + c) * 8 + (t & 7);
  v8[o8]     = f2b(y0);
  v8[o8 + 8] = f2b(y1);
  if (tid < 32) {
    float x0 = row[KVR + tid * 2], x1 = row[KVR + tid * 2 + 1];
    float cc = fc[t * 32 + tid], sn = fs[t * 32 + tid];
    *(u32*)&kpe_sw[((long)b * SS + t) * ROPE + ((tid * 2) ^ xm)] =
        pk2(x0 * cc - x1 * sn, x0 * sn + x1 * cc);
  }
}

// ---------------- GEMM: C(M,N) = A(M,K) * B(N,K)^T, bf16 in, f32/bf16 out ----------------
template <bool CBF16>
__global__ __launch_bounds__(256) void gemm_bt(const u16* __restrict__ Ag,
                                               const u16* __restrict__ Bg,
                                               void* __restrict__ Cg,
                                               int M, int N, int K,
                                               int lda, int ldb, int ldc,
                                               long sA, long sB, long sC,
                                               float oscale) {
  const u16* A = Ag + (long)blockIdx.z * sA;
  const u16* Bm = Bg + (long)blockIdx.z * sB;
  const int nbx = gridDim.x;
  int bidf = blockIdx.y * nbx + blockIdx.x;
  {
    const int nwg = nbx * gridDim.y;
    if ((nwg & 7) == 0)
      bidf = (bidf & 7) * (nwg >> 3) + (bidf >> 3);   // bijective XCD chunks
  }
  const int row0 = (bidf / nbx) * 128;
  const int col0 = (bidf % nbx) * 128;
  const int tid = threadIdx.x;
  const int wave = tid >> 6, lane = tid & 63;
  const int g = lane >> 4, r = lane & 15;
  const int wr = wave >> 1, wc = wave & 1;

  __shared__ u16 As[2][128 * 32];
  __shared__ u16 Bs[2][128 * 32];

  f32x4 acc[4][4] = {};
  const int nk = K >> 5;

  auto stage = [&](int kt, int p) {
    int k0 = kt << 5;
#pragma unroll
    for (int j = 0; j < 2; ++j) {
      int ldsoff = (j * 4096 + wave * 1024) >> 1;
      int rowi = j * 64 + wave * 16 + (lane >> 2);
      int coli = (lane & 3) << 3;
      const u16* ga = A + (long)(row0 + rowi) * lda + k0 + coli;
      gll16(ga, &As[p][ldsoff]);
      int rb = col0 + rowi; if (rb > N - 1) rb = N - 1;
      const u16* gb = Bm + (long)rb * ldb + k0 + coli;
      gll16(gb, &Bs[p][ldsoff]);
    }
  };

  stage(0, 0);
  for (int kt = 0; kt < nk; ++kt) {
    __syncthreads();
    if (kt + 1 < nk) stage(kt + 1, (kt + 1) & 1);
    const int p = kt & 1;
    bf16x8 af[4], bf[4];
#pragma unroll
    for (int i = 0; i < 4; i++) {
      af[i] = *(const bf16x8*)&As[p][(wr * 64 + i * 16 + r) * 32 + g * 8];
      bf[i] = *(const bf16x8*)&Bs[p][(wc * 64 + i * 16 + r) * 32 + g * 8];
    }
#pragma unroll
    for (int i = 0; i < 4; i++)
#pragma unroll
      for (int j = 0; j < 4; j++)
        acc[i][j] = MFMA16(af[i], bf[j], acc[i][j], 0, 0, 0);
  }

#pragma unroll
  for (int i = 0; i < 4; i++)
#pragma unroll
    for (int j = 0; j < 4; j++) {
      int rowb = row0 + wr * 64 + i * 16 + g * 4;
      int colc = col0 + wc * 64 + j * 16 + r;
      if (colc < N) {
        if constexpr (CBF16) {
          u16* C = (u16*)Cg + (long)blockIdx.z * sC;
#pragma unroll
          for (int e = 0; e < 4; e++)
            C[(long)(rowb + e) * ldc + colc] = f2b(acc[i][j][e] * oscale);
        } else {
          float* C = (float*)Cg + (long)blockIdx.z * sC;
#pragma unroll
          for (int e = 0; e < 4; e++)
            C[(long)(rowb + e) * ldc + colc] = acc[i][j][e] * oscale;
        }
      }
    }
}

// ---------------- flash attention v15: r13 structure + s_setprio around MFMA ----------------
// r13 (= r12) proven attn: 4 waves, 64 q-rows, classic rescale, keb/kob bases,
// nomask fast path. Added T5: setprio(1) around QK and PV MFMA clusters so the
// CU scheduler favors MFMA-issuing waves over the co-resident block's
// load/softmax waves (independent blocks/CU -> phase diversity exists).
__global__ __launch_bounds__(256) void attn_kernel(
    const u16* __restrict__ q_lat, const u16* __restrict__ q_pe,
    const u16* __restrict__ kv_sw, const u16* __restrict__ v8g,
    const u16* __restrict__ kpe_sw, u16* __restrict__ o_lat) {
  const int bid = blockIdx.x;
  const int xcd = bid & 7, idx = bid >> 3;
  const int b = xcd >> 1;
  const int h = idx & 15;
  const int jp = (idx >> 4) | ((xcd & 1) << 2);   // 0..7
  const int wv = threadIdx.x >> 6, lane = threadIdx.x & 63;
  const int g = lane >> 4, r = lane & 15;
  const int xm = (r & 7) << 3;
  const int keb = (g * 8) ^ xm;
  const int kob = keb - 2 * (xm & 32);

  __shared__ __attribute__((aligned(16))) u16 Ks[32 * 512];   // 32 KB swz K
  __shared__ __attribute__((aligned(16))) u16 Vs[32 * 512];   // 32 KB subtiled V
  __shared__ __attribute__((aligned(16))) u16 Kp[32 * 64];    // 4 KB swz kpe
  __shared__ __attribute__((aligned(16))) u16 P[64][40];      // 5 KB
  __shared__ float alphab[64];
  __shared__ float lbuf[64];

  const u16* KVg = kv_sw + (long)b * SS * KVR;
  const u16* VGg = v8g   + (long)b * SS * KVR;
  const u16* KPg = kpe_sw + (long)b * SS * ROPE;

  auto stage = [&](int t0) {
#pragma unroll
    for (int i = 0; i < 8; ++i) {
      int row = wv * 8 + i;
      gll16(KVg + (long)(t0 + row) * KVR + lane * 8, &Ks[row * 512]);
      gll16(VGg + (long)t0 * KVR + wv * 4096 + i * 512 + lane * 8,
            &Vs[wv * 4096 + i * 512]);
    }
    gll16(KPg + (long)t0 * ROPE + wv * 512 + lane * 8, &Kp[wv * 512]);
  };

  for (int seg = 0; seg < 2; ++seg) {
    const int j = seg ? jp : (15 - jp);    // big chunk first
    const int qa = j * 64;
    const int nt = 2 * (j + 1);            // 32-key tiles
    const int q_row = qa + wv * 16 + r;

    const u16* Q  = q_lat + ((long)h * NTOK + (long)b * SS + q_row) * KVR;
    const u16* Qp = q_pe  + ((long)h * NTOK + (long)b * SS + q_row) * ROPE;
    bf16x8 qf[18];
#pragma unroll
    for (int c = 0; c < 16; ++c) qf[c] = *(const bf16x8*)&Q[c * 32 + g * 8];
    qf[16] = *(const bf16x8*)&Qp[g * 8];
    qf[17] = *(const bf16x8*)&Qp[32 + g * 8];

    f32x4 acc[4][8];
#pragma unroll
    for (int i = 0; i < 4; i++)
#pragma unroll
      for (int jn = 0; jn < 8; jn++) acc[i][jn] = f32x4{0.f, 0.f, 0.f, 0.f};
    float m_run = -1e30f, l_run = 0.f;

    stage(0);
    __syncthreads();

    for (int tt = 0; tt < nt; ++tt) {
      const int t0 = tt << 5;

      // QK^T over 32 keys (2 row-groups of 16), 18 c-steps, imm-offset addrs
      f32x4 st0 = {0.f, 0.f, 0.f, 0.f}, st1 = {0.f, 0.f, 0.f, 0.f};
      __builtin_amdgcn_s_setprio(1);
#pragma unroll
      for (int c = 0; c < 16; ++c) {
        int off = ((c & 1) ? kob : keb) + c * 32;
        bf16x8 k0 = *(const bf16x8*)&Ks[r * 512 + off];
        bf16x8 k1 = *(const bf16x8*)&Ks[(16 + r) * 512 + off];
        st0 = MFMA16(k0, qf[c], st0, 0, 0, 0);
        st1 = MFMA16(k1, qf[c], st1, 0, 0, 0);
      }
      {
        bf16x8 k0 = *(const bf16x8*)&Kp[r * 64 + keb];
        bf16x8 k1 = *(const bf16x8*)&Kp[(16 + r) * 64 + keb];
        st0 = MFMA16(k0, qf[16], st0, 0, 0, 0);
        st1 = MFMA16(k1, qf[16], st1, 0, 0, 0);
        bf16x8 k2 = *(const bf16x8*)&Kp[r * 64 + kob + 32];
        bf16x8 k3 = *(const bf16x8*)&Kp[(16 + r) * 64 + kob + 32];
        st0 = MFMA16(k2, qf[17], st0, 0, 0, 0);
        st1 = MFMA16(k3, qf[17], st1, 0, 0, 0);
      }
      __builtin_amdgcn_s_setprio(0);

      // V fragments -> regs (must precede B1; stage overwrites Vs)
      bf16x8 vf[8];
#pragma unroll
      for (int nc = 0; nc < 8; ++nc)
        vf[nc] = *(const bf16x8*)&Vs[((g << 9) + (wv << 7) + (nc << 4) + r) << 3];

      // scores -> sv (mask only for last 2 tiles), row max
      float sv[8];
      float smax = -1e30f;
      if (t0 + 31 > qa) {
#pragma unroll
        for (int i = 0; i < 4; i++) {
          int t = t0 + g * 4 + i;
          sv[i]     = (t      <= q_row) ? st0[i] : -1e30f;
          sv[4 + i] = (t + 16 <= q_row) ? st1[i] : -1e30f;
          smax = fmaxf(smax, fmaxf(sv[i], sv[4 + i]));
        }
      } else {
#pragma unroll
        for (int i = 0; i < 4; i++) {
          sv[i] = st0[i]; sv[4 + i] = st1[i];
          smax = fmaxf(smax, fmaxf(sv[i], sv[4 + i]));
        }
      }
      smax = fmaxf(smax, __shfl_xor(smax, 16));
      smax = fmaxf(smax, __shfl_xor(smax, 32));
      float m_new = fmaxf(m_run, smax);
      float alpha = __expf(m_run - m_new);
      float ps = 0.f;
#pragma unroll
      for (int i = 0; i < 8; i++) {
        sv[i] = (sv[i] < -1e29f) ? 0.f : __expf(sv[i] - m_new);
        ps += sv[i];
      }
      ps += __shfl_xor(ps, 16);
      ps += __shfl_xor(ps, 32);
      l_run = l_run * alpha + ps;
      m_run = m_new;

      uint2 pw0, pw1;
      pw0.x = pk2(sv[0], sv[1]); pw0.y = pk2(sv[2], sv[3]);
      pw1.x = pk2(sv[4], sv[5]); pw1.y = pk2(sv[6], sv[7]);
      *(uint2*)&P[wv * 16 + r][g * 4]      = pw0;
      *(uint2*)&P[wv * 16 + r][16 + g * 4] = pw1;
      if (g == 0) alphab[wv * 16 + r] = alpha;
      __syncthreads();                   // B1: P/alpha visible; all LDS reads done
      if (tt + 1 < nt) stage(t0 + 32);   // overwrite K/V/kpe; drained at B2

      // PV: all 64 rows x own 128 cols (vf in regs)
      __builtin_amdgcn_s_setprio(1);
#pragma unroll
      for (int mc = 0; mc < 4; ++mc) {
        bf16x8 pa = *(const bf16x8*)&P[mc * 16 + r][g * 8];
        f32x4 a4 = *(const f32x4*)&alphab[mc * 16 + g * 4];
#pragma unroll
        for (int nc = 0; nc < 8; ++nc) {
          f32x4 t = acc[mc][nc] * a4;
          acc[mc][nc] = MFMA16(pa, vf[nc], t, 0, 0, 0);
        }
      }
      __builtin_amdgcn_s_setprio(0);
      __syncthreads();                   // B2: stage drained; P safe to rewrite
    }

    if (g == 0) lbuf[wv * 16 + r] = l_run;
    __syncthreads();
    u16* O = o_lat + ((long)h * NTOK + (long)b * SS + qa) * KVR;
#pragma unroll
    for (int mc = 0; mc < 4; ++mc) {
      f32x4 li = *(const f32x4*)&lbuf[mc * 16 + g * 4];
#pragma unroll
      for (int e = 0; e < 4; e++) li[e] = 1.f / li[e];
#pragma unroll
      for (int nc = 0; nc < 8; ++nc) {
        int col = wv * 128 + nc * 16 + r;
#pragma unroll
        for (int e = 0; e < 4; e++)
          O[(long)(mc * 16 + g * 4 + e) * KVR + col] = f2b(acc[mc][nc][e] * li[e]);
      }
    }
    __syncthreads();                     // lbuf/LDS safe for next seg
  }
}

// ---------------- host launch ----------------
extern "C" void kernel_launch(void* const* d_in, const int* in_sizes, int n_in,
                              void* d_out, int out_size, void* d_ws, size_t ws_size,
                              hipStream_t stream) {
  (void)in_sizes; (void)n_in; (void)out_size; (void)ws_size;
  const float* x    = (const float*)d_in[0];
  const float* fc   = (const float*)d_in[2];
  const float* fs   = (const float*)d_in[3];
  const float* wqa  = (const float*)d_in[4];
  const float* qnw  = (const float*)d_in[5];
  const float* wqb  = (const float*)d_in[6];
  const float* wkva = (const float*)d_in[7];
  const float* kvnw = (const float*)d_in[8];
  const float* wkvb = (const float*)d_in[9];
  const float* wo   = (const float*)d_in[10];
  float* out = (float*)d_out;

  char* w = (char*)d_ws;
  size_t off = 0;
  auto alloc = [&](size_t bytes) {
    void* p = w + off;
    off += (bytes + 255) & ~(size_t)255;
    return p;
  };
  // ---- persistent region ----
  u16* wbkt   = (u16*)alloc((size_t)NH * KVR * NOPE * 2);
  u16* wbv    = (u16*)alloc((size_t)NH * VH * KVR * 2);
  u16* wo_b   = (u16*)alloc((size_t)DIM * DIM * 2);
  u16* qnope  = (u16*)alloc((size_t)NH * NTOK * NOPE * 2);
  u16* qpe    = (u16*)alloc((size_t)NH * NTOK * ROPE * 2);
  u16* kv_sw  = (u16*)alloc((size_t)BB * SS * KVR * 2);
  u16* v8b    = (u16*)alloc((size_t)BB * SS * KVR * 2);
  u16* kpe_sw = (u16*)alloc((size_t)BB * SS * ROPE * 2);
  u16* oflat  = (u16*)alloc((size_t)NTOK * DIM * 2);
  // ---- transient region, later overlaid by qlat/olat ----
  u16* qlat   = (u16*)(w + off);            // overlay base
  u16* olat   = qlat;                       // attention writes O in-place over Q
  u16* x_bf   = (u16*)alloc((size_t)NTOK * DIM * 2);
  u16* wcat   = (u16*)alloc((size_t)NFUSE * DIM * 2);
  u16* wqb_b  = (u16*)alloc((size_t)NH * QKH * QR * 2);
  u16* qn     = (u16*)alloc((size_t)NTOK * QR * 2);
  float* C1   = (float*)alloc((size_t)NTOK * NFUSE * 4);
  u16* C2b    = (u16*)alloc((size_t)NTOK * NH * QKH * 2);

  cvt_all<<<9792, 256, 0, stream>>>(x, x_bf, wqa, wkva, wcat, wqb, wqb_b,
                                    wo, wo_b, wkvb, wbv);
  wbkt_tr<<<dim3(8, 2, 16), 256, 0, stream>>>(wkvb, wbkt);

  // fused [q_a | kv_full] = x @ [wq_a; wkv_a]^T   (4096 x 1600, K=2048)
  gemm_bt<false><<<dim3(13, NTOK / 128, 1), 256, 0, stream>>>(
      x_bf, wcat, C1, NTOK, NFUSE, DIM, DIM, DIM, NFUSE, 0, 0, 0, 1.f);
  rms_q_kernel<<<NTOK, 256, 0, stream>>>(C1, qnw, qn);
  gemm_bt<true><<<dim3(NH * QKH / 128, NTOK / 128, 1), 256, 0, stream>>>(
      qn, wqb_b, C2b, NTOK, NH * QKH, QR, QR, QR, NH * QKH, 0, 0, 0, 1.f);
  post_q_kernel<<<NTOK, 256, 0, stream>>>(C2b, fc, fs, qnope, qpe);
  post_kv_kernel<<<NTOK, 256, 0, stream>>>(C1, kvnw, fc, fs, kv_sw, v8b, kpe_sw);
  // q_lat pre-scaled by SCALE_ (softmax scale folded into Q)
  gemm_bt<true><<<dim3(KVR / 128, NTOK / 128, NH), 256, 0, stream>>>(
      qnope, wbkt, qlat, NTOK, KVR, NOPE, NOPE, NOPE, KVR,
      (long)NTOK * NOPE, (long)KVR * NOPE, (long)NTOK * KVR, SCALE_);
  attn_kernel<<<dim3(512, 1, 1), 256, 0, stream>>>(
      qlat, qpe, kv_sw, v8b, kpe_sw, olat);
  gemm_bt<true><<<dim3(1, NTOK / 128, NH), 256, 0, stream>>>(
      olat, wbv, oflat, NTOK, VH, KVR, KVR, KVR, DIM,
      (long)NTOK * KVR, (long)VH * KVR, (long)VH, 1.f);
  gemm_bt<false><<<dim3(DIM / 128, NTOK / 128, 1), 256, 0, stream>>>(
      oflat, wo_b, out, NTOK, DIM, DIM, DIM, DIM, DIM, 0, 0, 0, 1.f);
}

// Round 16
// 393.680 us; speedup vs baseline: 1.0771x; 1.0771x over previous
//
#include <hip/hip_runtime.h>
#include <hip/hip_bf16.h>
#include <stdint.h>

#define BB 4
#define SS 1024
#define DIM 2048
#define NH 16
#define QR 1024
#define KVR 512
#define NOPE 128
#define ROPE 64
#define VH 128
#define QKH 192
#define NTOK 4096
#define NFUSE 1600   // QR + 576

static constexpr float SCALE_ = 0.07216878364870322f; // 192^-0.5
static constexpr float EPS_ = 1e-6f;

typedef unsigned short u16;
typedef unsigned int u32;
using f32x4  = __attribute__((ext_vector_type(4))) float;
using bf16x8 = __attribute__((ext_vector_type(8))) __bf16;

#define MFMA16 __builtin_amdgcn_mfma_f32_16x16x32_bf16

__device__ __forceinline__ u16 f2b(float f) {
  u32 u = __float_as_uint(f);
  u32 r = u + 0x7fffu + ((u >> 16) & 1u);   // RNE
  return (u16)(r >> 16);
}
__device__ __forceinline__ u32 pk2(float a, float b) {
  return (u32)f2b(a) | ((u32)f2b(b) << 16);
}
__device__ __forceinline__ float b2f(u32 hi16) {
  return __uint_as_float(hi16 << 16);
}
__device__ __forceinline__ void gll16(const u16* g, u16* l) {
  __builtin_amdgcn_global_load_lds(
      (const __attribute__((address_space(1))) void*)g,
      (__attribute__((address_space(3))) void*)l, 16, 0, 0);
}

// ---------------- fused f32->bf16 conversions (6 regions, 1 launch) ----------------
__global__ __launch_bounds__(256) void cvt_all(
    const float* __restrict__ x, u16* __restrict__ x_bf,
    const float* __restrict__ wqa, const float* __restrict__ wkva,
    u16* __restrict__ wcat,
    const float* __restrict__ wqb, u16* __restrict__ wqb_b,
    const float* __restrict__ wo, u16* __restrict__ wo_b,
    const float* __restrict__ wkvb, u16* __restrict__ wbv) {
  int bid = blockIdx.x;
  const float* src; u16* dst; long i;
  if (bid < 4096)      { src = x;    dst = x_bf;  i = (long)bid * 2048; }
  else if (bid < 5120) { src = wqa;  dst = wcat;  i = (long)(bid - 4096) * 2048; }
  else if (bid < 6656) { src = wqb;  dst = wqb_b; i = (long)(bid - 5120) * 2048; }
  else if (bid < 7232) { src = wkva; dst = wcat + (long)QR * DIM; i = (long)(bid - 6656) * 2048; }
  else if (bid < 9280) { src = wo;   dst = wo_b;  i = (long)(bid - 7232) * 2048; }
  else {  // wbv: head h, rem over (128 x 512)
    long e = (long)(bid - 9280) * 2048;
    int h = (int)(e >> 16);
    int rem = (int)(e & 65535);
    src = wkvb + (((long)h * 256 + 128) << 9) + rem;
    dst = wbv + ((long)h << 16) + rem;
    i = 0;
  }
  i += threadIdx.x * 8;
  float4 a = *(const float4*)&src[i];
  float4 b = *(const float4*)&src[i + 4];
  uint4 o;
  o.x = pk2(a.x, a.y); o.y = pk2(a.z, a.w);
  o.z = pk2(b.x, b.y); o.w = pk2(b.z, b.w);
  *(uint4*)&dst[i] = o;
}

// ---------------- wbkt transpose: (h, dr<128, c) -> wbkt (h, c, dr), coalesced via LDS ----------------
__global__ __launch_bounds__(256) void wbkt_tr(const float* __restrict__ wkvb,
                                               u16* __restrict__ wbkt) {
  const int c0 = blockIdx.x * 64, dr0 = blockIdx.y * 64, h = blockIdx.z;
  const int tid = threadIdx.x;
  __shared__ u16 L[64][72];
  {
    int row = tid >> 2, cq = (tid & 3) * 16;
    const float* p = wkvb + (((long)h * 256 + dr0 + row) << 9) + c0 + cq;
    float4 v0 = *(const float4*)&p[0];
    float4 v1 = *(const float4*)&p[4];
    float4 v2 = *(const float4*)&p[8];
    float4 v3 = *(const float4*)&p[12];
    uint2 w0, w1;
    w0.x = pk2(v0.x, v0.y); w0.y = pk2(v0.z, v0.w);
    w1.x = pk2(v1.x, v1.y); w1.y = pk2(v1.z, v1.w);
    *(uint2*)&L[row][cq]     = w0;
    *(uint2*)&L[row][cq + 4] = w1;
    w0.x = pk2(v2.x, v2.y); w0.y = pk2(v2.z, v2.w);
    w1.x = pk2(v3.x, v3.y); w1.y = pk2(v3.z, v3.w);
    *(uint2*)&L[row][cq + 8]  = w0;
    *(uint2*)&L[row][cq + 12] = w1;
  }
  __syncthreads();
  {
    int crow = tid >> 2, dq = (tid & 3) * 16;
    u16 tmp[16];
#pragma unroll
    for (int e = 0; e < 16; ++e) tmp[e] = L[dq + e][crow];
    u16* dst = wbkt + (((long)h * 512 + c0 + crow) << 7) + dr0 + dq;
    *(uint4*)&dst[0] = *(uint4*)&tmp[0];
    *(uint4*)&dst[8] = *(uint4*)&tmp[8];
  }
}

// ---------------- RMSNorm over 1024 (q path), C1 ldc=1600 ----------------
__global__ __launch_bounds__(256) void rms_q_kernel(const float* __restrict__ X,
                                                    const float* __restrict__ w,
                                                    u16* __restrict__ out) {
  int r = blockIdx.x, tid = threadIdx.x;
  const float4 v = *(const float4*)&X[(long)r * NFUSE + tid * 4];
  float ss = v.x * v.x + v.y * v.y + v.z * v.z + v.w * v.w;
  for (int m = 1; m < 64; m <<= 1) ss += __shfl_xor(ss, m);
  __shared__ float red[4];
  if ((tid & 63) == 0) red[tid >> 6] = ss;
  __syncthreads();
  float tot = red[0] + red[1] + red[2] + red[3];
  float sc = rsqrtf(tot / QR + EPS_);
  float4 wv = *(const float4*)&w[tid * 4];
  uint2 o;
  o.x = pk2(v.x * sc * wv.x, v.y * sc * wv.y);
  o.y = pk2(v.z * sc * wv.z, v.w * sc * wv.w);
  *(uint2*)&out[(long)r * QR + tid * 4] = o;
}

// ---------------- rope_q: in-place rope on qpe (head-major [h][tok][64]), *SCALE ----------------
__global__ __launch_bounds__(256) void rope_q(u16* __restrict__ qp,
                                              const float* __restrict__ fc,
                                              const float* __restrict__ fs) {
  int r = blockIdx.x, tid = threadIdx.x;
  int s = r & (SS - 1);
#pragma unroll
  for (int pp = 0; pp < 2; ++pp) {
    int p = tid + pp * 256;                 // pair index over 16h x 32
    int h = p >> 5, jr = p & 31;
    u32* addr = (u32*)&qp[((long)h * NTOK + r) * ROPE + jr * 2];
    u32 pair = *addr;
    float x0 = b2f(pair & 0xffffu), x1 = b2f(pair >> 16);
    float c = fc[s * 32 + jr], sn = fs[s * 32 + jr];
    *addr = pk2((x0 * c - x1 * sn) * SCALE_, (x0 * sn + x1 * c) * SCALE_);
  }
}

// ---------------- kv post: rmsnorm(512) -> kv_sw (XOR-swizzled) + v8 (k-subtiled), rope k_pe_sw ----
__global__ __launch_bounds__(256) void post_kv_kernel(const float* __restrict__ C3,
                                                      const float* __restrict__ w,
                                                      const float* __restrict__ fc,
                                                      const float* __restrict__ fs,
                                                      u16* __restrict__ kv_sw,
                                                      u16* __restrict__ v8,
                                                      u16* __restrict__ kpe_sw) {
  int r = blockIdx.x, tid = threadIdx.x;
  int b = r >> 10, t = r & (SS - 1);
  const float* row = C3 + (long)r * NFUSE + QR;
  float2 v = *(const float2*)&row[tid * 2];
  float ss = v.x * v.x + v.y * v.y;
  for (int m = 1; m < 64; m <<= 1) ss += __shfl_xor(ss, m);
  __shared__ float red[4];
  if ((tid & 63) == 0) red[tid >> 6] = ss;
  __syncthreads();
  float tot = red[0] + red[1] + red[2] + red[3];
  float sc = rsqrtf(tot / KVR + EPS_);
  int c = tid * 2;
  int xm = (t & 7) << 3;
  float y0 = v.x * sc * w[c], y1 = v.y * sc * w[c + 1];
  *(u32*)&kv_sw[((long)b * SS + t) * KVR + (c ^ xm)] = pk2(y0, y1);
  long o8 = (long)b * SS * KVR + ((long)(t >> 3) * 512 + c) * 8 + (t & 7);
  v8[o8]     = f2b(y0);
  v8[o8 + 8] = f2b(y1);
  if (tid < 32) {
    float x0 = row[KVR + tid * 2], x1 = row[KVR + tid * 2 + 1];
    float cc = fc[t * 32 + tid], sn = fs[t * 32 + tid];
    *(u32*)&kpe_sw[((long)b * SS + t) * ROPE + ((tid * 2) ^ xm)] =
        pk2(x0 * cc - x1 * sn, x0 * sn + x1 * cc);
  }
}

// ---------------- GEMM: C(M,N) = A(M,K) * B(N,K)^T ----------------
// MODE 0: f32 C.  MODE 1: bf16 C.  MODE 2: q-split epilogue (Cg=qnope head-major,
// Cg2=qpe raw head-major) — eliminates the C2b round-trip.
template <int MODE>
__global__ __launch_bounds__(256) void gemm_bt(const u16* __restrict__ Ag,
                                               const u16* __restrict__ Bg,
                                               void* __restrict__ Cg,
                                               void* __restrict__ Cg2,
                                               int M, int N, int K,
                                               int lda, int ldb, int ldc,
                                               long sA, long sB, long sC,
                                               float oscale) {
  const u16* A = Ag + (long)blockIdx.z * sA;
  const u16* Bm = Bg + (long)blockIdx.z * sB;
  const int nbx = gridDim.x;
  int bidf = blockIdx.y * nbx + blockIdx.x;
  {
    const int nwg = nbx * gridDim.y;
    if ((nwg & 7) == 0)
      bidf = (bidf & 7) * (nwg >> 3) + (bidf >> 3);   // bijective XCD chunks
  }
  const int row0 = (bidf / nbx) * 128;
  const int col0 = (bidf % nbx) * 128;
  const int tid = threadIdx.x;
  const int wave = tid >> 6, lane = tid & 63;
  const int g = lane >> 4, r = lane & 15;
  const int wr = wave >> 1, wc = wave & 1;

  __shared__ u16 As[2][128 * 32];
  __shared__ u16 Bs[2][128 * 32];

  f32x4 acc[4][4] = {};
  const int nk = K >> 5;

  auto stage = [&](int kt, int p) {
    int k0 = kt << 5;
#pragma unroll
    for (int j = 0; j < 2; ++j) {
      int ldsoff = (j * 4096 + wave * 1024) >> 1;
      int rowi = j * 64 + wave * 16 + (lane >> 2);
      int coli = (lane & 3) << 3;
      const u16* ga = A + (long)(row0 + rowi) * lda + k0 + coli;
      gll16(ga, &As[p][ldsoff]);
      int rb = col0 + rowi; if (rb > N - 1) rb = N - 1;
      const u16* gb = Bm + (long)rb * ldb + k0 + coli;
      gll16(gb, &Bs[p][ldsoff]);
    }
  };

  stage(0, 0);
  for (int kt = 0; kt < nk; ++kt) {
    __syncthreads();
    if (kt + 1 < nk) stage(kt + 1, (kt + 1) & 1);
    const int p = kt & 1;
    bf16x8 af[4], bf[4];
#pragma unroll
    for (int i = 0; i < 4; i++) {
      af[i] = *(const bf16x8*)&As[p][(wr * 64 + i * 16 + r) * 32 + g * 8];
      bf[i] = *(const bf16x8*)&Bs[p][(wc * 64 + i * 16 + r) * 32 + g * 8];
    }
#pragma unroll
    for (int i = 0; i < 4; i++)
#pragma unroll
      for (int j = 0; j < 4; j++)
        acc[i][j] = MFMA16(af[i], bf[j], acc[i][j], 0, 0, 0);
  }

#pragma unroll
  for (int i = 0; i < 4; i++)
#pragma unroll
    for (int j = 0; j < 4; j++) {
      int rowb = row0 + wr * 64 + i * 16 + g * 4;
      int colc = col0 + wc * 64 + j * 16 + r;
      if constexpr (MODE == 2) {
        int hh = colc / QKH;
        int dd = colc - hh * QKH;
        if (dd < NOPE) {
          u16* qn = (u16*)Cg;
#pragma unroll
          for (int e = 0; e < 4; e++)
            qn[((long)hh * NTOK + rowb + e) * NOPE + dd] = f2b(acc[i][j][e]);
        } else {
          u16* qpr = (u16*)Cg2;
#pragma unroll
          for (int e = 0; e < 4; e++)
            qpr[((long)hh * NTOK + rowb + e) * ROPE + (dd - NOPE)] = f2b(acc[i][j][e]);
        }
      } else if (colc < N) {
        if constexpr (MODE == 1) {
          u16* C = (u16*)Cg + (long)blockIdx.z * sC;
#pragma unroll
          for (int e = 0; e < 4; e++)
            C[(long)(rowb + e) * ldc + colc] = f2b(acc[i][j][e] * oscale);
        } else {
          float* C = (float*)Cg + (long)blockIdx.z * sC;
#pragma unroll
          for (int e = 0; e < 4; e++)
            C[(long)(rowb + e) * ldc + colc] = acc[i][j][e] * oscale;
        }
      }
    }
}

// ---------------- flash attention (r13-exact: proven 198.6 us) ----------------
__global__ __launch_bounds__(256) void attn_kernel(
    const u16* __restrict__ q_lat, const u16* __restrict__ q_pe,
    const u16* __restrict__ kv_sw, const u16* __restrict__ v8g,
    const u16* __restrict__ kpe_sw, u16* __restrict__ o_lat) {
  const int bid = blockIdx.x;
  const int xcd = bid & 7, idx = bid >> 3;
  const int b = xcd >> 1;
  const int h = idx & 15;
  const int jp = (idx >> 4) | ((xcd & 1) << 2);   // 0..7
  const int wv = threadIdx.x >> 6, lane = threadIdx.x & 63;
  const int g = lane >> 4, r = lane & 15;
  const int xm = (r & 7) << 3;
  const int keb = (g * 8) ^ xm;
  const int kob = keb - 2 * (xm & 32);

  __shared__ __attribute__((aligned(16))) u16 Ks[32 * 512];   // 32 KB swz K
  __shared__ __attribute__((aligned(16))) u16 Vs[32 * 512];   // 32 KB subtiled V
  __shared__ __attribute__((aligned(16))) u16 Kp[32 * 64];    // 4 KB swz kpe
  __shared__ __attribute__((aligned(16))) u16 P[64][40];      // 5 KB
  __shared__ float alphab[64];
  __shared__ float lbuf[64];

  const u16* KVg = kv_sw + (long)b * SS * KVR;
  const u16* VGg = v8g   + (long)b * SS * KVR;
  const u16* KPg = kpe_sw + (long)b * SS * ROPE;

  auto stage = [&](int t0) {
#pragma unroll
    for (int i = 0; i < 8; ++i) {
      int row = wv * 8 + i;
      gll16(KVg + (long)(t0 + row) * KVR + lane * 8, &Ks[row * 512]);
      gll16(VGg + (long)t0 * KVR + wv * 4096 + i * 512 + lane * 8,
            &Vs[wv * 4096 + i * 512]);
    }
    gll16(KPg + (long)t0 * ROPE + wv * 512 + lane * 8, &Kp[wv * 512]);
  };

  for (int seg = 0; seg < 2; ++seg) {
    const int j = seg ? jp : (15 - jp);    // big chunk first
    const int qa = j * 64;
    const int nt = 2 * (j + 1);            // 32-key tiles
    const int q_row = qa + wv * 16 + r;

    const u16* Q  = q_lat + ((long)h * NTOK + (long)b * SS + q_row) * KVR;
    const u16* Qp = q_pe  + ((long)h * NTOK + (long)b * SS + q_row) * ROPE;
    bf16x8 qf[18];
#pragma unroll
    for (int c = 0; c < 16; ++c) qf[c] = *(const bf16x8*)&Q[c * 32 + g * 8];
    qf[16] = *(const bf16x8*)&Qp[g * 8];
    qf[17] = *(const bf16x8*)&Qp[32 + g * 8];

    f32x4 acc[4][8];
#pragma unroll
    for (int i = 0; i < 4; i++)
#pragma unroll
      for (int jn = 0; jn < 8; jn++) acc[i][jn] = f32x4{0.f, 0.f, 0.f, 0.f};
    float m_run = -1e30f, l_run = 0.f;

    stage(0);
    __syncthreads();

    for (int tt = 0; tt < nt; ++tt) {
      const int t0 = tt << 5;

      f32x4 st0 = {0.f, 0.f, 0.f, 0.f}, st1 = {0.f, 0.f, 0.f, 0.f};
#pragma unroll
      for (int c = 0; c < 16; ++c) {
        int off = ((c & 1) ? kob : keb) + c * 32;
        bf16x8 k0 = *(const bf16x8*)&Ks[r * 512 + off];
        bf16x8 k1 = *(const bf16x8*)&Ks[(16 + r) * 512 + off];
        st0 = MFMA16(k0, qf[c], st0, 0, 0, 0);
        st1 = MFMA16(k1, qf[c], st1, 0, 0, 0);
      }
      {
        bf16x8 k0 = *(const bf16x8*)&Kp[r * 64 + keb];
        bf16x8 k1 = *(const bf16x8*)&Kp[(16 + r) * 64 + keb];
        st0 = MFMA16(k0, qf[16], st0, 0, 0, 0);
        st1 = MFMA16(k1, qf[16], st1, 0, 0, 0);
        bf16x8 k2 = *(const bf16x8*)&Kp[r * 64 + kob + 32];
        bf16x8 k3 = *(const bf16x8*)&Kp[(16 + r) * 64 + kob + 32];
        st0 = MFMA16(k2, qf[17], st0, 0, 0, 0);
        st1 = MFMA16(k3, qf[17], st1, 0, 0, 0);
      }

      bf16x8 vf[8];
#pragma unroll
      for (int nc = 0; nc < 8; ++nc)
        vf[nc] = *(const bf16x8*)&Vs[((g << 9) + (wv << 7) + (nc << 4) + r) << 3];

      float sv[8];
      float smax = -1e30f;
      if (t0 + 31 > qa) {
#pragma unroll
        for (int i = 0; i < 4; i++) {
          int t = t0 + g * 4 + i;
          sv[i]     = (t      <= q_row) ? st0[i] : -1e30f;
          sv[4 + i] = (t + 16 <= q_row) ? st1[i] : -1e30f;
          smax = fmaxf(smax, fmaxf(sv[i], sv[4 + i]));
        }
      } else {
#pragma unroll
        for (int i = 0; i < 4; i++) {
          sv[i] = st0[i]; sv[4 + i] = st1[i];
          smax = fmaxf(smax, fmaxf(sv[i], sv[4 + i]));
        }
      }
      smax = fmaxf(smax, __shfl_xor(smax, 16));
      smax = fmaxf(smax, __shfl_xor(smax, 32));
      float m_new = fmaxf(m_run, smax);
      float alpha = __expf(m_run - m_new);
      float ps = 0.f;
#pragma unroll
      for (int i = 0; i < 8; i++) {
        sv[i] = (sv[i] < -1e29f) ? 0.f : __expf(sv[i] - m_new);
        ps += sv[i];
      }
      ps += __shfl_xor(ps, 16);
      ps += __shfl_xor(ps, 32);
      l_run = l_run * alpha + ps;
      m_run = m_new;

      uint2 pw0, pw1;
      pw0.x = pk2(sv[0], sv[1]); pw0.y = pk2(sv[2], sv[3]);
      pw1.x = pk2(sv[4], sv[5]); pw1.y = pk2(sv[6], sv[7]);
      *(uint2*)&P[wv * 16 + r][g * 4]      = pw0;
      *(uint2*)&P[wv * 16 + r][16 + g * 4] = pw1;
      if (g == 0) alphab[wv * 16 + r] = alpha;
      __syncthreads();                   // B1: P/alpha visible; all LDS reads done
      if (tt + 1 < nt) stage(t0 + 32);   // overwrite K/V/kpe; drained at B2

#pragma unroll
      for (int mc = 0; mc < 4; ++mc) {
        bf16x8 pa = *(const bf16x8*)&P[mc * 16 + r][g * 8];
        f32x4 a4 = *(const f32x4*)&alphab[mc * 16 + g * 4];
#pragma unroll
        for (int nc = 0; nc < 8; ++nc) {
          f32x4 t = acc[mc][nc] * a4;
          acc[mc][nc] = MFMA16(pa, vf[nc], t, 0, 0, 0);
        }
      }
      __syncthreads();                   // B2: stage drained; P safe to rewrite
    }

    if (g == 0) lbuf[wv * 16 + r] = l_run;
    __syncthreads();
    u16* O = o_lat + ((long)h * NTOK + (long)b * SS + qa) * KVR;
#pragma unroll
    for (int mc = 0; mc < 4; ++mc) {
      f32x4 li = *(const f32x4*)&lbuf[mc * 16 + g * 4];
#pragma unroll
      for (int e = 0; e < 4; e++) li[e] = 1.f / li[e];
#pragma unroll
      for (int nc = 0; nc < 8; ++nc) {
        int col = wv * 128 + nc * 16 + r;
#pragma unroll
        for (int e = 0; e < 4; e++)
          O[(long)(mc * 16 + g * 4 + e) * KVR + col] = f2b(acc[mc][nc][e] * li[e]);
      }
    }
    __syncthreads();                     // lbuf/LDS safe for next seg
  }
}

// ---------------- host launch ----------------
extern "C" void kernel_launch(void* const* d_in, const int* in_sizes, int n_in,
                              void* d_out, int out_size, void* d_ws, size_t ws_size,
                              hipStream_t stream) {
  (void)in_sizes; (void)n_in; (void)out_size; (void)ws_size;
  const float* x    = (const float*)d_in[0];
  const float* fc   = (const float*)d_in[2];
  const float* fs   = (const float*)d_in[3];
  const float* wqa  = (const float*)d_in[4];
  const float* qnw  = (const float*)d_in[5];
  const float* wqb  = (const float*)d_in[6];
  const float* wkva = (const float*)d_in[7];
  const float* kvnw = (const float*)d_in[8];
  const float* wkvb = (const float*)d_in[9];
  const float* wo   = (const float*)d_in[10];
  float* out = (float*)d_out;

  char* w = (char*)d_ws;
  size_t off = 0;
  auto alloc = [&](size_t bytes) {
    void* p = w + off;
    off += (bytes + 255) & ~(size_t)255;
    return p;
  };
  // ---- persistent region ----
  u16* wbkt   = (u16*)alloc((size_t)NH * KVR * NOPE * 2);
  u16* wbv    = (u16*)alloc((size_t)NH * VH * KVR * 2);
  u16* wo_b   = (u16*)alloc((size_t)DIM * DIM * 2);
  u16* qnope  = (u16*)alloc((size_t)NH * NTOK * NOPE * 2);
  u16* qpe    = (u16*)alloc((size_t)NH * NTOK * ROPE * 2);
  u16* kv_sw  = (u16*)alloc((size_t)BB * SS * KVR * 2);
  u16* v8b    = (u16*)alloc((size_t)BB * SS * KVR * 2);
  u16* kpe_sw = (u16*)alloc((size_t)BB * SS * ROPE * 2);
  u16* oflat  = (u16*)alloc((size_t)NTOK * DIM * 2);
  // ---- transient region, later overlaid by qlat/olat ----
  u16* qlat   = (u16*)(w + off);            // overlay base
  u16* olat   = qlat;                       // attention writes O in-place over Q
  u16* x_bf   = (u16*)alloc((size_t)NTOK * DIM * 2);
  u16* wcat   = (u16*)alloc((size_t)NFUSE * DIM * 2);
  u16* wqb_b  = (u16*)alloc((size_t)NH * QKH * QR * 2);
  u16* qn     = (u16*)alloc((size_t)NTOK * QR * 2);
  float* C1   = (float*)alloc((size_t)NTOK * NFUSE * 4);

  cvt_all<<<9792, 256, 0, stream>>>(x, x_bf, wqa, wkva, wcat, wqb, wqb_b,
                                    wo, wo_b, wkvb, wbv);
  wbkt_tr<<<dim3(8, 2, 16), 256, 0, stream>>>(wkvb, wbkt);

  // fused [q_a | kv_full] = x @ [wq_a; wkv_a]^T   (4096 x 1600, K=2048)
  gemm_bt<0><<<dim3(13, NTOK / 128, 1), 256, 0, stream>>>(
      x_bf, wcat, C1, nullptr, NTOK, NFUSE, DIM, DIM, DIM, NFUSE, 0, 0, 0, 1.f);
  rms_q_kernel<<<NTOK, 256, 0, stream>>>(C1, qnw, qn);
  // q = qn @ wq_b^T with q-split epilogue -> qnope + raw qpe (head-major)
  gemm_bt<2><<<dim3(NH * QKH / 128, NTOK / 128, 1), 256, 0, stream>>>(
      qn, wqb_b, qnope, qpe, NTOK, NH * QKH, QR, QR, QR, 0, 0, 0, 0, 1.f);
  rope_q<<<NTOK, 256, 0, stream>>>(qpe, fc, fs);
  post_kv_kernel<<<NTOK, 256, 0, stream>>>(C1, kvnw, fc, fs, kv_sw, v8b, kpe_sw);
  // q_lat pre-scaled by SCALE_ (softmax scale folded into Q)
  gemm_bt<1><<<dim3(KVR / 128, NTOK / 128, NH), 256, 0, stream>>>(
      qnope, wbkt, qlat, nullptr, NTOK, KVR, NOPE, NOPE, NOPE, KVR,
      (long)NTOK * NOPE, (long)KVR * NOPE, (long)NTOK * KVR, SCALE_);
  attn_kernel<<<dim3(512, 1, 1), 256, 0, stream>>>(
      qlat, qpe, kv_sw, v8b, kpe_sw, olat);
  gemm_bt<1><<<dim3(1, NTOK / 128, NH), 256, 0, stream>>>(
      olat, wbv, oflat, nullptr, NTOK, VH, KVR, KVR, KVR, DIM,
      (long)NTOK * KVR, (long)VH * KVR, (long)VH, 1.f);
  gemm_bt<0><<<dim3(DIM / 128, NTOK / 128, 1), 256, 0, stream>>>(
      oflat, wo_b, out, nullptr, NTOK, DIM, DIM, DIM, DIM, DIM, 0, 0, 0, 1.f);
}

// Round 17
// 387.457 us; speedup vs baseline: 1.0944x; 1.0161x over previous
//
#include <hip/hip_runtime.h>
#include <hip/hip_bf16.h>
#include <stdint.h>

#define BB 4
#define SS 1024
#define DIM 2048
#define NH 16
#define QR 1024
#define KVR 512
#define NOPE 128
#define ROPE 64
#define VH 128
#define QKH 192
#define NTOK 4096
#define NFUSE 1600   // QR + 576

static constexpr float SCALE_ = 0.07216878364870322f; // 192^-0.5
static constexpr float EPS_ = 1e-6f;

typedef unsigned short u16;
typedef unsigned int u32;
using f32x4  = __attribute__((ext_vector_type(4))) float;
using bf16x8 = __attribute__((ext_vector_type(8))) __bf16;

#define MFMA16 __builtin_amdgcn_mfma_f32_16x16x32_bf16

__device__ __forceinline__ u16 f2b(float f) {
  u32 u = __float_as_uint(f);
  u32 r = u + 0x7fffu + ((u >> 16) & 1u);   // RNE
  return (u16)(r >> 16);
}
__device__ __forceinline__ u32 pk2(float a, float b) {
  return (u32)f2b(a) | ((u32)f2b(b) << 16);
}
__device__ __forceinline__ float b2f(u32 hi16) {
  return __uint_as_float(hi16 << 16);
}
__device__ __forceinline__ void gll16(const u16* g, u16* l) {
  __builtin_amdgcn_global_load_lds(
      (const __attribute__((address_space(1))) void*)g,
      (__attribute__((address_space(3))) void*)l, 16, 0, 0);
}

// ---------------- fused f32->bf16 conversions + wbkt transpose (1 launch) ----------------
// bids [0,9792): vectorized copy regions; bids [9792,10048): wbkt 64x64 transpose tiles.
__global__ __launch_bounds__(256) void cvt_all(
    const float* __restrict__ x, u16* __restrict__ x_bf,
    const float* __restrict__ wqa, const float* __restrict__ wkva,
    u16* __restrict__ wcat,
    const float* __restrict__ wqb, u16* __restrict__ wqb_b,
    const float* __restrict__ wo, u16* __restrict__ wo_b,
    const float* __restrict__ wkvb, u16* __restrict__ wbv,
    u16* __restrict__ wbkt) {
  int bid = blockIdx.x;
  int tid = threadIdx.x;
  __shared__ u16 L[64][72];
  if (bid >= 9792) {   // ---- wbkt transpose: (h, dr<128, c) -> (h, c, dr) ----
    int b2 = bid - 9792;
    const int c0 = (b2 & 7) * 64, dr0 = ((b2 >> 3) & 1) * 64, h = b2 >> 4;
    {
      int row = tid >> 2, cq = (tid & 3) * 16;
      const float* p = wkvb + (((long)h * 256 + dr0 + row) << 9) + c0 + cq;
      float4 v0 = *(const float4*)&p[0];
      float4 v1 = *(const float4*)&p[4];
      float4 v2 = *(const float4*)&p[8];
      float4 v3 = *(const float4*)&p[12];
      uint2 w0, w1;
      w0.x = pk2(v0.x, v0.y); w0.y = pk2(v0.z, v0.w);
      w1.x = pk2(v1.x, v1.y); w1.y = pk2(v1.z, v1.w);
      *(uint2*)&L[row][cq]     = w0;
      *(uint2*)&L[row][cq + 4] = w1;
      w0.x = pk2(v2.x, v2.y); w0.y = pk2(v2.z, v2.w);
      w1.x = pk2(v3.x, v3.y); w1.y = pk2(v3.z, v3.w);
      *(uint2*)&L[row][cq + 8]  = w0;
      *(uint2*)&L[row][cq + 12] = w1;
    }
    __syncthreads();
    {
      int crow = tid >> 2, dq = (tid & 3) * 16;
      u16 tmp[16];
#pragma unroll
      for (int e = 0; e < 16; ++e) tmp[e] = L[dq + e][crow];
      u16* dst = wbkt + (((long)h * 512 + c0 + crow) << 7) + dr0 + dq;
      *(uint4*)&dst[0] = *(uint4*)&tmp[0];
      *(uint4*)&dst[8] = *(uint4*)&tmp[8];
    }
    return;
  }
  const float* src; u16* dst; long i;
  if (bid < 4096)      { src = x;    dst = x_bf;  i = (long)bid * 2048; }
  else if (bid < 5120) { src = wqa;  dst = wcat;  i = (long)(bid - 4096) * 2048; }
  else if (bid < 6656) { src = wqb;  dst = wqb_b; i = (long)(bid - 5120) * 2048; }
  else if (bid < 7232) { src = wkva; dst = wcat + (long)QR * DIM; i = (long)(bid - 6656) * 2048; }
  else if (bid < 9280) { src = wo;   dst = wo_b;  i = (long)(bid - 7232) * 2048; }
  else {  // wbv: head h, rem over (128 x 512)
    long e = (long)(bid - 9280) * 2048;
    int h = (int)(e >> 16);
    int rem = (int)(e & 65535);
    src = wkvb + (((long)h * 256 + 128) << 9) + rem;
    dst = wbv + ((long)h << 16) + rem;
    i = 0;
  }
  i += tid * 8;
  float4 a = *(const float4*)&src[i];
  float4 b = *(const float4*)&src[i + 4];
  uint4 o;
  o.x = pk2(a.x, a.y); o.y = pk2(a.z, a.w);
  o.z = pk2(b.x, b.y); o.w = pk2(b.z, b.w);
  *(uint4*)&dst[i] = o;
}

// ---------------- post_qkv: rms_q + kv post fused (C1 is bf16, ldc=1600) ----------------
// q half: rmsnorm(1024) -> qn.  kv half: rmsnorm(512) -> kv_sw (XOR-swizzled) +
// v8 (k-subtiled); rope(k_pe) -> kpe_sw.
__global__ __launch_bounds__(256) void post_qkv(
    const u16* __restrict__ C1, const float* __restrict__ qw,
    const float* __restrict__ kw, const float* __restrict__ fc,
    const float* __restrict__ fs, u16* __restrict__ qn,
    u16* __restrict__ kv_sw, u16* __restrict__ v8,
    u16* __restrict__ kpe_sw) {
  int r = blockIdx.x, tid = threadIdx.x;
  int b = r >> 10, t = r & (SS - 1);
  const u16* row = C1 + (long)r * NFUSE;
  u32 qa_ = *(const u32*)&row[tid * 4];
  u32 qb_ = *(const u32*)&row[tid * 4 + 2];
  float q0 = b2f(qa_ & 0xffffu), q1 = b2f(qa_ >> 16);
  float q2 = b2f(qb_ & 0xffffu), q3 = b2f(qb_ >> 16);
  float ssq = q0 * q0 + q1 * q1 + q2 * q2 + q3 * q3;
  u32 ka_ = *(const u32*)&row[QR + tid * 2];
  float k0 = b2f(ka_ & 0xffffu), k1 = b2f(ka_ >> 16);
  float ssk = k0 * k0 + k1 * k1;
  for (int m = 1; m < 64; m <<= 1) {
    ssq += __shfl_xor(ssq, m);
    ssk += __shfl_xor(ssk, m);
  }
  __shared__ float redq[4], redk[4];
  if ((tid & 63) == 0) { redq[tid >> 6] = ssq; redk[tid >> 6] = ssk; }
  __syncthreads();
  float scq = rsqrtf((redq[0] + redq[1] + redq[2] + redq[3]) / QR + EPS_);
  float sck = rsqrtf((redk[0] + redk[1] + redk[2] + redk[3]) / KVR + EPS_);
  const float4 wv4 = *(const float4*)&qw[tid * 4];
  uint2 o;
  o.x = pk2(q0 * scq * wv4.x, q1 * scq * wv4.y);
  o.y = pk2(q2 * scq * wv4.z, q3 * scq * wv4.w);
  *(uint2*)&qn[(long)r * QR + tid * 4] = o;
  int c = tid * 2;
  int xm = (t & 7) << 3;
  float y0 = k0 * sck * kw[c], y1 = k1 * sck * kw[c + 1];
  *(u32*)&kv_sw[((long)b * SS + t) * KVR + (c ^ xm)] = pk2(y0, y1);
  long o8 = (long)b * SS * KVR + ((long)(t >> 3) * 512 + c) * 8 + (t & 7);
  v8[o8]     = f2b(y0);
  v8[o8 + 8] = f2b(y1);
  if (tid < 32) {
    u32 pa = *(const u32*)&row[QR + KVR + tid * 2];
    float x0 = b2f(pa & 0xffffu), x1 = b2f(pa >> 16);
    float cc = fc[t * 32 + tid], sn = fs[t * 32 + tid];
    *(u32*)&kpe_sw[((long)b * SS + t) * ROPE + ((tid * 2) ^ xm)] =
        pk2(x0 * cc - x1 * sn, x0 * sn + x1 * cc);
  }
}

// ---------------- rope_q: in-place rope on qpe (head-major [h][tok][64]), *SCALE ----------------
__global__ __launch_bounds__(256) void rope_q(u16* __restrict__ qp,
                                              const float* __restrict__ fc,
                                              const float* __restrict__ fs) {
  int r = blockIdx.x, tid = threadIdx.x;
  int s = r & (SS - 1);
#pragma unroll
  for (int pp = 0; pp < 2; ++pp) {
    int p = tid + pp * 256;                 // pair index over 16h x 32
    int h = p >> 5, jr = p & 31;
    u32* addr = (u32*)&qp[((long)h * NTOK + r) * ROPE + jr * 2];
    u32 pair = *addr;
    float x0 = b2f(pair & 0xffffu), x1 = b2f(pair >> 16);
    float c = fc[s * 32 + jr], sn = fs[s * 32 + jr];
    *addr = pk2((x0 * c - x1 * sn) * SCALE_, (x0 * sn + x1 * c) * SCALE_);
  }
}

// ---------------- GEMM: C(M,N) = A(M,K) * B(N,K)^T ----------------
// MODE 0: f32 C.  MODE 1: bf16 C.  MODE 2: q-split epilogue (Cg=qnope head-major,
// Cg2=qpe raw head-major).
template <int MODE>
__global__ __launch_bounds__(256) void gemm_bt(const u16* __restrict__ Ag,
                                               const u16* __restrict__ Bg,
                                               void* __restrict__ Cg,
                                               void* __restrict__ Cg2,
                                               int M, int N, int K,
                                               int lda, int ldb, int ldc,
                                               long sA, long sB, long sC,
                                               float oscale) {
  const u16* A = Ag + (long)blockIdx.z * sA;
  const u16* Bm = Bg + (long)blockIdx.z * sB;
  const int nbx = gridDim.x;
  int bidf = blockIdx.y * nbx + blockIdx.x;
  {
    const int nwg = nbx * gridDim.y;
    if ((nwg & 7) == 0)
      bidf = (bidf & 7) * (nwg >> 3) + (bidf >> 3);   // bijective XCD chunks
  }
  const int row0 = (bidf / nbx) * 128;
  const int col0 = (bidf % nbx) * 128;
  const int tid = threadIdx.x;
  const int wave = tid >> 6, lane = tid & 63;
  const int g = lane >> 4, r = lane & 15;
  const int wr = wave >> 1, wc = wave & 1;

  __shared__ u16 As[2][128 * 32];
  __shared__ u16 Bs[2][128 * 32];

  f32x4 acc[4][4] = {};
  const int nk = K >> 5;

  auto stage = [&](int kt, int p) {
    int k0 = kt << 5;
#pragma unroll
    for (int j = 0; j < 2; ++j) {
      int ldsoff = (j * 4096 + wave * 1024) >> 1;
      int rowi = j * 64 + wave * 16 + (lane >> 2);
      int coli = (lane & 3) << 3;
      const u16* ga = A + (long)(row0 + rowi) * lda + k0 + coli;
      gll16(ga, &As[p][ldsoff]);
      int rb = col0 + rowi; if (rb > N - 1) rb = N - 1;
      const u16* gb = Bm + (long)rb * ldb + k0 + coli;
      gll16(gb, &Bs[p][ldsoff]);
    }
  };

  stage(0, 0);
  for (int kt = 0; kt < nk; ++kt) {
    __syncthreads();
    if (kt + 1 < nk) stage(kt + 1, (kt + 1) & 1);
    const int p = kt & 1;
    bf16x8 af[4], bf[4];
#pragma unroll
    for (int i = 0; i < 4; i++) {
      af[i] = *(const bf16x8*)&As[p][(wr * 64 + i * 16 + r) * 32 + g * 8];
      bf[i] = *(const bf16x8*)&Bs[p][(wc * 64 + i * 16 + r) * 32 + g * 8];
    }
#pragma unroll
    for (int i = 0; i < 4; i++)
#pragma unroll
      for (int j = 0; j < 4; j++)
        acc[i][j] = MFMA16(af[i], bf[j], acc[i][j], 0, 0, 0);
  }

#pragma unroll
  for (int i = 0; i < 4; i++)
#pragma unroll
    for (int j = 0; j < 4; j++) {
      int rowb = row0 + wr * 64 + i * 16 + g * 4;
      int colc = col0 + wc * 64 + j * 16 + r;
      if constexpr (MODE == 2) {
        int hh = colc / QKH;
        int dd = colc - hh * QKH;
        if (dd < NOPE) {
          u16* qn = (u16*)Cg;
#pragma unroll
          for (int e = 0; e < 4; e++)
            qn[((long)hh * NTOK + rowb + e) * NOPE + dd] = f2b(acc[i][j][e]);
        } else {
          u16* qpr = (u16*)Cg2;
#pragma unroll
          for (int e = 0; e < 4; e++)
            qpr[((long)hh * NTOK + rowb + e) * ROPE + (dd - NOPE)] = f2b(acc[i][j][e]);
        }
      } else if (colc < N) {
        if constexpr (MODE == 1) {
          u16* C = (u16*)Cg + (long)blockIdx.z * sC;
#pragma unroll
          for (int e = 0; e < 4; e++)
            C[(long)(rowb + e) * ldc + colc] = f2b(acc[i][j][e] * oscale);
        } else {
          float* C = (float*)Cg + (long)blockIdx.z * sC;
#pragma unroll
          for (int e = 0; e < 4; e++)
            C[(long)(rowb + e) * ldc + colc] = acc[i][j][e] * oscale;
        }
      }
    }
}

// ---------------- flash attention (r13-exact: proven 198.6 us) ----------------
__global__ __launch_bounds__(256) void attn_kernel(
    const u16* __restrict__ q_lat, const u16* __restrict__ q_pe,
    const u16* __restrict__ kv_sw, const u16* __restrict__ v8g,
    const u16* __restrict__ kpe_sw, u16* __restrict__ o_lat) {
  const int bid = blockIdx.x;
  const int xcd = bid & 7, idx = bid >> 3;
  const int b = xcd >> 1;
  const int h = idx & 15;
  const int jp = (idx >> 4) | ((xcd & 1) << 2);   // 0..7
  const int wv = threadIdx.x >> 6, lane = threadIdx.x & 63;
  const int g = lane >> 4, r = lane & 15;
  const int xm = (r & 7) << 3;
  const int keb = (g * 8) ^ xm;
  const int kob = keb - 2 * (xm & 32);

  __shared__ __attribute__((aligned(16))) u16 Ks[32 * 512];   // 32 KB swz K
  __shared__ __attribute__((aligned(16))) u16 Vs[32 * 512];   // 32 KB subtiled V
  __shared__ __attribute__((aligned(16))) u16 Kp[32 * 64];    // 4 KB swz kpe
  __shared__ __attribute__((aligned(16))) u16 P[64][40];      // 5 KB
  __shared__ float alphab[64];
  __shared__ float lbuf[64];

  const u16* KVg = kv_sw + (long)b * SS * KVR;
  const u16* VGg = v8g   + (long)b * SS * KVR;
  const u16* KPg = kpe_sw + (long)b * SS * ROPE;

  auto stage = [&](int t0) {
#pragma unroll
    for (int i = 0; i < 8; ++i) {
      int row = wv * 8 + i;
      gll16(KVg + (long)(t0 + row) * KVR + lane * 8, &Ks[row * 512]);
      gll16(VGg + (long)t0 * KVR + wv * 4096 + i * 512 + lane * 8,
            &Vs[wv * 4096 + i * 512]);
    }
    gll16(KPg + (long)t0 * ROPE + wv * 512 + lane * 8, &Kp[wv * 512]);
  };

  for (int seg = 0; seg < 2; ++seg) {
    const int j = seg ? jp : (15 - jp);    // big chunk first
    const int qa = j * 64;
    const int nt = 2 * (j + 1);            // 32-key tiles
    const int q_row = qa + wv * 16 + r;

    const u16* Q  = q_lat + ((long)h * NTOK + (long)b * SS + q_row) * KVR;
    const u16* Qp = q_pe  + ((long)h * NTOK + (long)b * SS + q_row) * ROPE;
    bf16x8 qf[18];
#pragma unroll
    for (int c = 0; c < 16; ++c) qf[c] = *(const bf16x8*)&Q[c * 32 + g * 8];
    qf[16] = *(const bf16x8*)&Qp[g * 8];
    qf[17] = *(const bf16x8*)&Qp[32 + g * 8];

    f32x4 acc[4][8];
#pragma unroll
    for (int i = 0; i < 4; i++)
#pragma unroll
      for (int jn = 0; jn < 8; jn++) acc[i][jn] = f32x4{0.f, 0.f, 0.f, 0.f};
    float m_run = -1e30f, l_run = 0.f;

    stage(0);
    __syncthreads();

    for (int tt = 0; tt < nt; ++tt) {
      const int t0 = tt << 5;

      f32x4 st0 = {0.f, 0.f, 0.f, 0.f}, st1 = {0.f, 0.f, 0.f, 0.f};
#pragma unroll
      for (int c = 0; c < 16; ++c) {
        int off = ((c & 1) ? kob : keb) + c * 32;
        bf16x8 k0 = *(const bf16x8*)&Ks[r * 512 + off];
        bf16x8 k1 = *(const bf16x8*)&Ks[(16 + r) * 512 + off];
        st0 = MFMA16(k0, qf[c], st0, 0, 0, 0);
        st1 = MFMA16(k1, qf[c], st1, 0, 0, 0);
      }
      {
        bf16x8 k0 = *(const bf16x8*)&Kp[r * 64 + keb];
        bf16x8 k1 = *(const bf16x8*)&Kp[(16 + r) * 64 + keb];
        st0 = MFMA16(k0, qf[16], st0, 0, 0, 0);
        st1 = MFMA16(k1, qf[16], st1, 0, 0, 0);
        bf16x8 k2 = *(const bf16x8*)&Kp[r * 64 + kob + 32];
        bf16x8 k3 = *(const bf16x8*)&Kp[(16 + r) * 64 + kob + 32];
        st0 = MFMA16(k2, qf[17], st0, 0, 0, 0);
        st1 = MFMA16(k3, qf[17], st1, 0, 0, 0);
      }

      bf16x8 vf[8];
#pragma unroll
      for (int nc = 0; nc < 8; ++nc)
        vf[nc] = *(const bf16x8*)&Vs[((g << 9) + (wv << 7) + (nc << 4) + r) << 3];

      float sv[8];
      float smax = -1e30f;
      if (t0 + 31 > qa) {
#pragma unroll
        for (int i = 0; i < 4; i++) {
          int t = t0 + g * 4 + i;
          sv[i]     = (t      <= q_row) ? st0[i] : -1e30f;
          sv[4 + i] = (t + 16 <= q_row) ? st1[i] : -1e30f;
          smax = fmaxf(smax, fmaxf(sv[i], sv[4 + i]));
        }
      } else {
#pragma unroll
        for (int i = 0; i < 4; i++) {
          sv[i] = st0[i]; sv[4 + i] = st1[i];
          smax = fmaxf(smax, fmaxf(sv[i], sv[4 + i]));
        }
      }
      smax = fmaxf(smax, __shfl_xor(smax, 16));
      smax = fmaxf(smax, __shfl_xor(smax, 32));
      float m_new = fmaxf(m_run, smax);
      float alpha = __expf(m_run - m_new);
      float ps = 0.f;
#pragma unroll
      for (int i = 0; i < 8; i++) {
        sv[i] = (sv[i] < -1e29f) ? 0.f : __expf(sv[i] - m_new);
        ps += sv[i];
      }
      ps += __shfl_xor(ps, 16);
      ps += __shfl_xor(ps, 32);
      l_run = l_run * alpha + ps;
      m_run = m_new;

      uint2 pw0, pw1;
      pw0.x = pk2(sv[0], sv[1]); pw0.y = pk2(sv[2], sv[3]);
      pw1.x = pk2(sv[4], sv[5]); pw1.y = pk2(sv[6], sv[7]);
      *(uint2*)&P[wv * 16 + r][g * 4]      = pw0;
      *(uint2*)&P[wv * 16 + r][16 + g * 4] = pw1;
      if (g == 0) alphab[wv * 16 + r] = alpha;
      __syncthreads();                   // B1: P/alpha visible; all LDS reads done
      if (tt + 1 < nt) stage(t0 + 32);   // overwrite K/V/kpe; drained at B2

#pragma unroll
      for (int mc = 0; mc < 4; ++mc) {
        bf16x8 pa = *(const bf16x8*)&P[mc * 16 + r][g * 8];
        f32x4 a4 = *(const f32x4*)&alphab[mc * 16 + g * 4];
#pragma unroll
        for (int nc = 0; nc < 8; ++nc) {
          f32x4 t = acc[mc][nc] * a4;
          acc[mc][nc] = MFMA16(pa, vf[nc], t, 0, 0, 0);
        }
      }
      __syncthreads();                   // B2: stage drained; P safe to rewrite
    }

    if (g == 0) lbuf[wv * 16 + r] = l_run;
    __syncthreads();
    u16* O = o_lat + ((long)h * NTOK + (long)b * SS + qa) * KVR;
#pragma unroll
    for (int mc = 0; mc < 4; ++mc) {
      f32x4 li = *(const f32x4*)&lbuf[mc * 16 + g * 4];
#pragma unroll
      for (int e = 0; e < 4; e++) li[e] = 1.f / li[e];
#pragma unroll
      for (int nc = 0; nc < 8; ++nc) {
        int col = wv * 128 + nc * 16 + r;
#pragma unroll
        for (int e = 0; e < 4; e++)
          O[(long)(mc * 16 + g * 4 + e) * KVR + col] = f2b(acc[mc][nc][e] * li[e]);
      }
    }
    __syncthreads();                     // lbuf/LDS safe for next seg
  }
}

// ---------------- host launch ----------------
extern "C" void kernel_launch(void* const* d_in, const int* in_sizes, int n_in,
                              void* d_out, int out_size, void* d_ws, size_t ws_size,
                              hipStream_t stream) {
  (void)in_sizes; (void)n_in; (void)out_size; (void)ws_size;
  const float* x    = (const float*)d_in[0];
  const float* fc   = (const float*)d_in[2];
  const float* fs   = (const float*)d_in[3];
  const float* wqa  = (const float*)d_in[4];
  const float* qnw  = (const float*)d_in[5];
  const float* wqb  = (const float*)d_in[6];
  const float* wkva = (const float*)d_in[7];
  const float* kvnw = (const float*)d_in[8];
  const float* wkvb = (const float*)d_in[9];
  const float* wo   = (const float*)d_in[10];
  float* out = (float*)d_out;

  char* w = (char*)d_ws;
  size_t off = 0;
  auto alloc = [&](size_t bytes) {
    void* p = w + off;
    off += (bytes + 255) & ~(size_t)255;
    return p;
  };
  // ---- persistent region ----
  u16* wbkt   = (u16*)alloc((size_t)NH * KVR * NOPE * 2);
  u16* wbv    = (u16*)alloc((size_t)NH * VH * KVR * 2);
  u16* wo_b   = (u16*)alloc((size_t)DIM * DIM * 2);
  u16* qnope  = (u16*)alloc((size_t)NH * NTOK * NOPE * 2);
  u16* qpe    = (u16*)alloc((size_t)NH * NTOK * ROPE * 2);
  u16* kv_sw  = (u16*)alloc((size_t)BB * SS * KVR * 2);
  u16* v8b    = (u16*)alloc((size_t)BB * SS * KVR * 2);
  u16* kpe_sw = (u16*)alloc((size_t)BB * SS * ROPE * 2);
  u16* oflat  = (u16*)alloc((size_t)NTOK * DIM * 2);
  // ---- transient region, later overlaid by qlat/olat ----
  u16* qlat   = (u16*)(w + off);            // overlay base
  u16* olat   = qlat;                       // attention writes O in-place over Q
  u16* x_bf   = (u16*)alloc((size_t)NTOK * DIM * 2);
  u16* wcat   = (u16*)alloc((size_t)NFUSE * DIM * 2);
  u16* wqb_b  = (u16*)alloc((size_t)NH * QKH * QR * 2);
  u16* qn     = (u16*)alloc((size_t)NTOK * QR * 2);
  u16* C1     = (u16*)alloc((size_t)NTOK * NFUSE * 2);

  cvt_all<<<10048, 256, 0, stream>>>(x, x_bf, wqa, wkva, wcat, wqb, wqb_b,
                                     wo, wo_b, wkvb, wbv, wbkt);

  // fused [q_a | kv_full] = x @ [wq_a; wkv_a]^T   (4096 x 1600, K=2048) -> bf16 C1
  gemm_bt<1><<<dim3(13, NTOK / 128, 1), 256, 0, stream>>>(
      x_bf, wcat, C1, nullptr, NTOK, NFUSE, DIM, DIM, DIM, NFUSE, 0, 0, 0, 1.f);
  post_qkv<<<NTOK, 256, 0, stream>>>(C1, qnw, kvnw, fc, fs, qn, kv_sw, v8b, kpe_sw);
  // q = qn @ wq_b^T with q-split epilogue -> qnope + raw qpe (head-major)
  gemm_bt<2><<<dim3(NH * QKH / 128, NTOK / 128, 1), 256, 0, stream>>>(
      qn, wqb_b, qnope, qpe, NTOK, NH * QKH, QR, QR, QR, 0, 0, 0, 0, 1.f);
  rope_q<<<NTOK, 256, 0, stream>>>(qpe, fc, fs);
  // q_lat pre-scaled by SCALE_ (softmax scale folded into Q)
  gemm_bt<1><<<dim3(KVR / 128, NTOK / 128, NH), 256, 0, stream>>>(
      qnope, wbkt, qlat, nullptr, NTOK, KVR, NOPE, NOPE, NOPE, KVR,
      (long)NTOK * NOPE, (long)KVR * NOPE, (long)NTOK * KVR, SCALE_);
  attn_kernel<<<dim3(512, 1, 1), 256, 0, stream>>>(
      qlat, qpe, kv_sw, v8b, kpe_sw, olat);
  gemm_bt<1><<<dim3(1, NTOK / 128, NH), 256, 0, stream>>>(
      olat, wbv, oflat, nullptr, NTOK, VH, KVR, KVR, KVR, DIM,
      (long)NTOK * KVR, (long)VH * KVR, (long)VH, 1.f);
  gemm_bt<0><<<dim3(DIM / 128, NTOK / 128, 1), 256, 0, stream>>>(
      oflat, wo_b, out, nullptr, NTOK, DIM, DIM, DIM, DIM, DIM, 0, 0, 0, 1.f);
}

// Round 18
// 385.726 us; speedup vs baseline: 1.0993x; 1.0045x over previous
//
#include <hip/hip_runtime.h>
#include <hip/hip_bf16.h>
#include <stdint.h>

#define BB 4
#define SS 1024
#define DIM 2048
#define NH 16
#define QR 1024
#define KVR 512
#define NOPE 128
#define ROPE 64
#define VH 128
#define QKH 192
#define NTOK 4096
#define NFUSE 1600   // QR + 576

static constexpr float SCALE_ = 0.07216878364870322f; // 192^-0.5
static constexpr float EPS_ = 1e-6f;

typedef unsigned short u16;
typedef unsigned int u32;
using f32x4  = __attribute__((ext_vector_type(4))) float;
using bf16x8 = __attribute__((ext_vector_type(8))) __bf16;

#define MFMA16 __builtin_amdgcn_mfma_f32_16x16x32_bf16

__device__ __forceinline__ u16 f2b(float f) {
  u32 u = __float_as_uint(f);
  u32 r = u + 0x7fffu + ((u >> 16) & 1u);   // RNE
  return (u16)(r >> 16);
}
__device__ __forceinline__ u32 pk2(float a, float b) {
  return (u32)f2b(a) | ((u32)f2b(b) << 16);
}
__device__ __forceinline__ float b2f(u32 hi16) {
  return __uint_as_float(hi16 << 16);
}
__device__ __forceinline__ void gll16(const u16* g, u16* l) {
  __builtin_amdgcn_global_load_lds(
      (const __attribute__((address_space(1))) void*)g,
      (__attribute__((address_space(3))) void*)l, 16, 0, 0);
}

// ---------------- fused f32->bf16 conversions + wbkt transpose (1 launch) ----------------
__global__ __launch_bounds__(256) void cvt_all(
    const float* __restrict__ x, u16* __restrict__ x_bf,
    const float* __restrict__ wqa, const float* __restrict__ wkva,
    u16* __restrict__ wcat,
    const float* __restrict__ wqb, u16* __restrict__ wqb_b,
    const float* __restrict__ wo, u16* __restrict__ wo_b,
    const float* __restrict__ wkvb, u16* __restrict__ wbv,
    u16* __restrict__ wbkt) {
  int bid = blockIdx.x;
  int tid = threadIdx.x;
  __shared__ u16 L[64][72];
  if (bid >= 9792) {   // ---- wbkt transpose: (h, dr<128, c) -> (h, c, dr) ----
    int b2 = bid - 9792;
    const int c0 = (b2 & 7) * 64, dr0 = ((b2 >> 3) & 1) * 64, h = b2 >> 4;
    {
      int row = tid >> 2, cq = (tid & 3) * 16;
      const float* p = wkvb + (((long)h * 256 + dr0 + row) << 9) + c0 + cq;
      float4 v0 = *(const float4*)&p[0];
      float4 v1 = *(const float4*)&p[4];
      float4 v2 = *(const float4*)&p[8];
      float4 v3 = *(const float4*)&p[12];
      uint2 w0, w1;
      w0.x = pk2(v0.x, v0.y); w0.y = pk2(v0.z, v0.w);
      w1.x = pk2(v1.x, v1.y); w1.y = pk2(v1.z, v1.w);
      *(uint2*)&L[row][cq]     = w0;
      *(uint2*)&L[row][cq + 4] = w1;
      w0.x = pk2(v2.x, v2.y); w0.y = pk2(v2.z, v2.w);
      w1.x = pk2(v3.x, v3.y); w1.y = pk2(v3.z, v3.w);
      *(uint2*)&L[row][cq + 8]  = w0;
      *(uint2*)&L[row][cq + 12] = w1;
    }
    __syncthreads();
    {
      int crow = tid >> 2, dq = (tid & 3) * 16;
      u16 tmp[16];
#pragma unroll
      for (int e = 0; e < 16; ++e) tmp[e] = L[dq + e][crow];
      u16* dst = wbkt + (((long)h * 512 + c0 + crow) << 7) + dr0 + dq;
      *(uint4*)&dst[0] = *(uint4*)&tmp[0];
      *(uint4*)&dst[8] = *(uint4*)&tmp[8];
    }
    return;
  }
  const float* src; u16* dst; long i;
  if (bid < 4096)      { src = x;    dst = x_bf;  i = (long)bid * 2048; }
  else if (bid < 5120) { src = wqa;  dst = wcat;  i = (long)(bid - 4096) * 2048; }
  else if (bid < 6656) { src = wqb;  dst = wqb_b; i = (long)(bid - 5120) * 2048; }
  else if (bid < 7232) { src = wkva; dst = wcat + (long)QR * DIM; i = (long)(bid - 6656) * 2048; }
  else if (bid < 9280) { src = wo;   dst = wo_b;  i = (long)(bid - 7232) * 2048; }
  else {  // wbv: head h, rem over (128 x 512)
    long e = (long)(bid - 9280) * 2048;
    int h = (int)(e >> 16);
    int rem = (int)(e & 65535);
    src = wkvb + (((long)h * 256 + 128) << 9) + rem;
    dst = wbv + ((long)h << 16) + rem;
    i = 0;
  }
  i += tid * 8;
  float4 a = *(const float4*)&src[i];
  float4 b = *(const float4*)&src[i + 4];
  uint4 o;
  o.x = pk2(a.x, a.y); o.y = pk2(a.z, a.w);
  o.z = pk2(b.x, b.y); o.w = pk2(b.z, b.w);
  *(uint4*)&dst[i] = o;
}

// ---------------- post_qkv: rms_q + kv post fused (C1 is bf16, ldc=1600) ----------------
__global__ __launch_bounds__(256) void post_qkv(
    const u16* __restrict__ C1, const float* __restrict__ qw,
    const float* __restrict__ kw, const float* __restrict__ fc,
    const float* __restrict__ fs, u16* __restrict__ qn,
    u16* __restrict__ kv_sw, u16* __restrict__ v8,
    u16* __restrict__ kpe_sw) {
  int r = blockIdx.x, tid = threadIdx.x;
  int b = r >> 10, t = r & (SS - 1);
  const u16* row = C1 + (long)r * NFUSE;
  u32 qa_ = *(const u32*)&row[tid * 4];
  u32 qb_ = *(const u32*)&row[tid * 4 + 2];
  float q0 = b2f(qa_ & 0xffffu), q1 = b2f(qa_ >> 16);
  float q2 = b2f(qb_ & 0xffffu), q3 = b2f(qb_ >> 16);
  float ssq = q0 * q0 + q1 * q1 + q2 * q2 + q3 * q3;
  u32 ka_ = *(const u32*)&row[QR + tid * 2];
  float k0 = b2f(ka_ & 0xffffu), k1 = b2f(ka_ >> 16);
  float ssk = k0 * k0 + k1 * k1;
  for (int m = 1; m < 64; m <<= 1) {
    ssq += __shfl_xor(ssq, m);
    ssk += __shfl_xor(ssk, m);
  }
  __shared__ float redq[4], redk[4];
  if ((tid & 63) == 0) { redq[tid >> 6] = ssq; redk[tid >> 6] = ssk; }
  __syncthreads();
  float scq = rsqrtf((redq[0] + redq[1] + redq[2] + redq[3]) / QR + EPS_);
  float sck = rsqrtf((redk[0] + redk[1] + redk[2] + redk[3]) / KVR + EPS_);
  const float4 wv4 = *(const float4*)&qw[tid * 4];
  uint2 o;
  o.x = pk2(q0 * scq * wv4.x, q1 * scq * wv4.y);
  o.y = pk2(q2 * scq * wv4.z, q3 * scq * wv4.w);
  *(uint2*)&qn[(long)r * QR + tid * 4] = o;
  int c = tid * 2;
  int xm = (t & 7) << 3;
  float y0 = k0 * sck * kw[c], y1 = k1 * sck * kw[c + 1];
  *(u32*)&kv_sw[((long)b * SS + t) * KVR + (c ^ xm)] = pk2(y0, y1);
  long o8 = (long)b * SS * KVR + ((long)(t >> 3) * 512 + c) * 8 + (t & 7);
  v8[o8]     = f2b(y0);
  v8[o8 + 8] = f2b(y1);
  if (tid < 32) {
    u32 pa = *(const u32*)&row[QR + KVR + tid * 2];
    float x0 = b2f(pa & 0xffffu), x1 = b2f(pa >> 16);
    float cc = fc[t * 32 + tid], sn = fs[t * 32 + tid];
    *(u32*)&kpe_sw[((long)b * SS + t) * ROPE + ((tid * 2) ^ xm)] =
        pk2(x0 * cc - x1 * sn, x0 * sn + x1 * cc);
  }
}

// ---------------- GEMM: C(M,N) = A(M,K) * B(N,K)^T ----------------
// MODE 0: f32 C.  MODE 1: bf16 C.  MODE 2: q-split epilogue with FUSED ROPE
// (Cg=qnope head-major, Cg2=qpe head-major, rotated+scaled in-register via
// shfl_xor(1) pair exchange; dd<NOPE branch is wave-uniform since 16-col
// fragments never straddle the 128-boundary inside a 192-wide head).
template <int MODE>
__global__ __launch_bounds__(256) void gemm_bt(const u16* __restrict__ Ag,
                                               const u16* __restrict__ Bg,
                                               void* __restrict__ Cg,
                                               void* __restrict__ Cg2,
                                               const float* __restrict__ fcp,
                                               const float* __restrict__ fsp,
                                               int M, int N, int K,
                                               int lda, int ldb, int ldc,
                                               long sA, long sB, long sC,
                                               float oscale) {
  const u16* A = Ag + (long)blockIdx.z * sA;
  const u16* Bm = Bg + (long)blockIdx.z * sB;
  const int nbx = gridDim.x;
  int bidf = blockIdx.y * nbx + blockIdx.x;
  {
    const int nwg = nbx * gridDim.y;
    if ((nwg & 7) == 0)
      bidf = (bidf & 7) * (nwg >> 3) + (bidf >> 3);   // bijective XCD chunks
  }
  const int row0 = (bidf / nbx) * 128;
  const int col0 = (bidf % nbx) * 128;
  const int tid = threadIdx.x;
  const int wave = tid >> 6, lane = tid & 63;
  const int g = lane >> 4, r = lane & 15;
  const int wr = wave >> 1, wc = wave & 1;

  __shared__ u16 As[2][128 * 32];
  __shared__ u16 Bs[2][128 * 32];

  f32x4 acc[4][4] = {};
  const int nk = K >> 5;

  auto stage = [&](int kt, int p) {
    int k0 = kt << 5;
#pragma unroll
    for (int j = 0; j < 2; ++j) {
      int ldsoff = (j * 4096 + wave * 1024) >> 1;
      int rowi = j * 64 + wave * 16 + (lane >> 2);
      int coli = (lane & 3) << 3;
      const u16* ga = A + (long)(row0 + rowi) * lda + k0 + coli;
      gll16(ga, &As[p][ldsoff]);
      int rb = col0 + rowi; if (rb > N - 1) rb = N - 1;
      const u16* gb = Bm + (long)rb * ldb + k0 + coli;
      gll16(gb, &Bs[p][ldsoff]);
    }
  };

  stage(0, 0);
  for (int kt = 0; kt < nk; ++kt) {
    __syncthreads();
    if (kt + 1 < nk) stage(kt + 1, (kt + 1) & 1);
    const int p = kt & 1;
    bf16x8 af[4], bf[4];
#pragma unroll
    for (int i = 0; i < 4; i++) {
      af[i] = *(const bf16x8*)&As[p][(wr * 64 + i * 16 + r) * 32 + g * 8];
      bf[i] = *(const bf16x8*)&Bs[p][(wc * 64 + i * 16 + r) * 32 + g * 8];
    }
#pragma unroll
    for (int i = 0; i < 4; i++)
#pragma unroll
      for (int j = 0; j < 4; j++)
        acc[i][j] = MFMA16(af[i], bf[j], acc[i][j], 0, 0, 0);
  }

#pragma unroll
  for (int i = 0; i < 4; i++)
#pragma unroll
    for (int j = 0; j < 4; j++) {
      int rowb = row0 + wr * 64 + i * 16 + g * 4;
      int colc = col0 + wc * 64 + j * 16 + r;
      if constexpr (MODE == 2) {
        int hh = colc / QKH;
        int dd = colc - hh * QKH;
        if (dd < NOPE) {
          u16* qn = (u16*)Cg;
#pragma unroll
          for (int e = 0; e < 4; e++)
            qn[((long)hh * NTOK + rowb + e) * NOPE + dd] = f2b(acc[i][j][e]);
        } else {
          u16* qpr = (u16*)Cg2;
          int jr = (dd - NOPE) >> 1;
          const int odd = dd & 1;
#pragma unroll
          for (int e = 0; e < 4; e++) {
            float own = acc[i][j][e];
            float partner = __shfl_xor(own, 1);
            int s = (rowb + e) & (SS - 1);
            float cc = fcp[s * 32 + jr], sn = fsp[s * 32 + jr];
            float y = odd ? (partner * sn + own * cc) : (own * cc - partner * sn);
            qpr[((long)hh * NTOK + rowb + e) * ROPE + (dd - NOPE)] = f2b(y * SCALE_);
          }
        }
      } else if (colc < N) {
        if constexpr (MODE == 1) {
          u16* C = (u16*)Cg + (long)blockIdx.z * sC;
#pragma unroll
          for (int e = 0; e < 4; e++)
            C[(long)(rowb + e) * ldc + colc] = f2b(acc[i][j][e] * oscale);
        } else {
          float* C = (float*)Cg + (long)blockIdx.z * sC;
#pragma unroll
          for (int e = 0; e < 4; e++)
            C[(long)(rowb + e) * ldc + colc] = acc[i][j][e] * oscale;
        }
      }
    }
}

// ---------------- flash attention (r13-exact: proven 198.6 us) ----------------
__global__ __launch_bounds__(256) void attn_kernel(
    const u16* __restrict__ q_lat, const u16* __restrict__ q_pe,
    const u16* __restrict__ kv_sw, const u16* __restrict__ v8g,
    const u16* __restrict__ kpe_sw, u16* __restrict__ o_lat) {
  const int bid = blockIdx.x;
  const int xcd = bid & 7, idx = bid >> 3;
  const int b = xcd >> 1;
  const int h = idx & 15;
  const int jp = (idx >> 4) | ((xcd & 1) << 2);   // 0..7
  const int wv = threadIdx.x >> 6, lane = threadIdx.x & 63;
  const int g = lane >> 4, r = lane & 15;
  const int xm = (r & 7) << 3;
  const int keb = (g * 8) ^ xm;
  const int kob = keb - 2 * (xm & 32);

  __shared__ __attribute__((aligned(16))) u16 Ks[32 * 512];   // 32 KB swz K
  __shared__ __attribute__((aligned(16))) u16 Vs[32 * 512];   // 32 KB subtiled V
  __shared__ __attribute__((aligned(16))) u16 Kp[32 * 64];    // 4 KB swz kpe
  __shared__ __attribute__((aligned(16))) u16 P[64][40];      // 5 KB
  __shared__ float alphab[64];
  __shared__ float lbuf[64];

  const u16* KVg = kv_sw + (long)b * SS * KVR;
  const u16* VGg = v8g   + (long)b * SS * KVR;
  const u16* KPg = kpe_sw + (long)b * SS * ROPE;

  auto stage = [&](int t0) {
#pragma unroll
    for (int i = 0; i < 8; ++i) {
      int row = wv * 8 + i;
      gll16(KVg + (long)(t0 + row) * KVR + lane * 8, &Ks[row * 512]);
      gll16(VGg + (long)t0 * KVR + wv * 4096 + i * 512 + lane * 8,
            &Vs[wv * 4096 + i * 512]);
    }
    gll16(KPg + (long)t0 * ROPE + wv * 512 + lane * 8, &Kp[wv * 512]);
  };

  for (int seg = 0; seg < 2; ++seg) {
    const int j = seg ? jp : (15 - jp);    // big chunk first
    const int qa = j * 64;
    const int nt = 2 * (j + 1);            // 32-key tiles
    const int q_row = qa + wv * 16 + r;

    const u16* Q  = q_lat + ((long)h * NTOK + (long)b * SS + q_row) * KVR;
    const u16* Qp = q_pe  + ((long)h * NTOK + (long)b * SS + q_row) * ROPE;
    bf16x8 qf[18];
#pragma unroll
    for (int c = 0; c < 16; ++c) qf[c] = *(const bf16x8*)&Q[c * 32 + g * 8];
    qf[16] = *(const bf16x8*)&Qp[g * 8];
    qf[17] = *(const bf16x8*)&Qp[32 + g * 8];

    f32x4 acc[4][8];
#pragma unroll
    for (int i = 0; i < 4; i++)
#pragma unroll
      for (int jn = 0; jn < 8; jn++) acc[i][jn] = f32x4{0.f, 0.f, 0.f, 0.f};
    float m_run = -1e30f, l_run = 0.f;

    stage(0);
    __syncthreads();

    for (int tt = 0; tt < nt; ++tt) {
      const int t0 = tt << 5;

      f32x4 st0 = {0.f, 0.f, 0.f, 0.f}, st1 = {0.f, 0.f, 0.f, 0.f};
#pragma unroll
      for (int c = 0; c < 16; ++c) {
        int off = ((c & 1) ? kob : keb) + c * 32;
        bf16x8 k0 = *(const bf16x8*)&Ks[r * 512 + off];
        bf16x8 k1 = *(const bf16x8*)&Ks[(16 + r) * 512 + off];
        st0 = MFMA16(k0, qf[c], st0, 0, 0, 0);
        st1 = MFMA16(k1, qf[c], st1, 0, 0, 0);
      }
      {
        bf16x8 k0 = *(const bf16x8*)&Kp[r * 64 + keb];
        bf16x8 k1 = *(const bf16x8*)&Kp[(16 + r) * 64 + keb];
        st0 = MFMA16(k0, qf[16], st0, 0, 0, 0);
        st1 = MFMA16(k1, qf[16], st1, 0, 0, 0);
        bf16x8 k2 = *(const bf16x8*)&Kp[r * 64 + kob + 32];
        bf16x8 k3 = *(const bf16x8*)&Kp[(16 + r) * 64 + kob + 32];
        st0 = MFMA16(k2, qf[17], st0, 0, 0, 0);
        st1 = MFMA16(k3, qf[17], st1, 0, 0, 0);
      }

      bf16x8 vf[8];
#pragma unroll
      for (int nc = 0; nc < 8; ++nc)
        vf[nc] = *(const bf16x8*)&Vs[((g << 9) + (wv << 7) + (nc << 4) + r) << 3];

      float sv[8];
      float smax = -1e30f;
      if (t0 + 31 > qa) {
#pragma unroll
        for (int i = 0; i < 4; i++) {
          int t = t0 + g * 4 + i;
          sv[i]     = (t      <= q_row) ? st0[i] : -1e30f;
          sv[4 + i] = (t + 16 <= q_row) ? st1[i] : -1e30f;
          smax = fmaxf(smax, fmaxf(sv[i], sv[4 + i]));
        }
      } else {
#pragma unroll
        for (int i = 0; i < 4; i++) {
          sv[i] = st0[i]; sv[4 + i] = st1[i];
          smax = fmaxf(smax, fmaxf(sv[i], sv[4 + i]));
        }
      }
      smax = fmaxf(smax, __shfl_xor(smax, 16));
      smax = fmaxf(smax, __shfl_xor(smax, 32));
      float m_new = fmaxf(m_run, smax);
      float alpha = __expf(m_run - m_new);
      float ps = 0.f;
#pragma unroll
      for (int i = 0; i < 8; i++) {
        sv[i] = (sv[i] < -1e29f) ? 0.f : __expf(sv[i] - m_new);
        ps += sv[i];
      }
      ps += __shfl_xor(ps, 16);
      ps += __shfl_xor(ps, 32);
      l_run = l_run * alpha + ps;
      m_run = m_new;

      uint2 pw0, pw1;
      pw0.x = pk2(sv[0], sv[1]); pw0.y = pk2(sv[2], sv[3]);
      pw1.x = pk2(sv[4], sv[5]); pw1.y = pk2(sv[6], sv[7]);
      *(uint2*)&P[wv * 16 + r][g * 4]      = pw0;
      *(uint2*)&P[wv * 16 + r][16 + g * 4] = pw1;
      if (g == 0) alphab[wv * 16 + r] = alpha;
      __syncthreads();                   // B1: P/alpha visible; all LDS reads done
      if (tt + 1 < nt) stage(t0 + 32);   // overwrite K/V/kpe; drained at B2

#pragma unroll
      for (int mc = 0; mc < 4; ++mc) {
        bf16x8 pa = *(const bf16x8*)&P[mc * 16 + r][g * 8];
        f32x4 a4 = *(const f32x4*)&alphab[mc * 16 + g * 4];
#pragma unroll
        for (int nc = 0; nc < 8; ++nc) {
          f32x4 t = acc[mc][nc] * a4;
          acc[mc][nc] = MFMA16(pa, vf[nc], t, 0, 0, 0);
        }
      }
      __syncthreads();                   // B2: stage drained; P safe to rewrite
    }

    if (g == 0) lbuf[wv * 16 + r] = l_run;
    __syncthreads();
    u16* O = o_lat + ((long)h * NTOK + (long)b * SS + qa) * KVR;
#pragma unroll
    for (int mc = 0; mc < 4; ++mc) {
      f32x4 li = *(const f32x4*)&lbuf[mc * 16 + g * 4];
#pragma unroll
      for (int e = 0; e < 4; e++) li[e] = 1.f / li[e];
#pragma unroll
      for (int nc = 0; nc < 8; ++nc) {
        int col = wv * 128 + nc * 16 + r;
#pragma unroll
        for (int e = 0; e < 4; e++)
          O[(long)(mc * 16 + g * 4 + e) * KVR + col] = f2b(acc[mc][nc][e] * li[e]);
      }
    }
    __syncthreads();                     // lbuf/LDS safe for next seg
  }
}

// ---------------- host launch ----------------
extern "C" void kernel_launch(void* const* d_in, const int* in_sizes, int n_in,
                              void* d_out, int out_size, void* d_ws, size_t ws_size,
                              hipStream_t stream) {
  (void)in_sizes; (void)n_in; (void)out_size; (void)ws_size;
  const float* x    = (const float*)d_in[0];
  const float* fc   = (const float*)d_in[2];
  const float* fs   = (const float*)d_in[3];
  const float* wqa  = (const float*)d_in[4];
  const float* qnw  = (const float*)d_in[5];
  const float* wqb  = (const float*)d_in[6];
  const float* wkva = (const float*)d_in[7];
  const float* kvnw = (const float*)d_in[8];
  const float* wkvb = (const float*)d_in[9];
  const float* wo   = (const float*)d_in[10];
  float* out = (float*)d_out;

  char* w = (char*)d_ws;
  size_t off = 0;
  auto alloc = [&](size_t bytes) {
    void* p = w + off;
    off += (bytes + 255) & ~(size_t)255;
    return p;
  };
  // ---- persistent region ----
  u16* wbkt   = (u16*)alloc((size_t)NH * KVR * NOPE * 2);
  u16* wbv    = (u16*)alloc((size_t)NH * VH * KVR * 2);
  u16* wo_b   = (u16*)alloc((size_t)DIM * DIM * 2);
  u16* qnope  = (u16*)alloc((size_t)NH * NTOK * NOPE * 2);
  u16* qpe    = (u16*)alloc((size_t)NH * NTOK * ROPE * 2);
  u16* kv_sw  = (u16*)alloc((size_t)BB * SS * KVR * 2);
  u16* v8b    = (u16*)alloc((size_t)BB * SS * KVR * 2);
  u16* kpe_sw = (u16*)alloc((size_t)BB * SS * ROPE * 2);
  u16* oflat  = (u16*)alloc((size_t)NTOK * DIM * 2);
  // ---- transient region, later overlaid by qlat/olat ----
  u16* qlat   = (u16*)(w + off);            // overlay base
  u16* olat   = qlat;                       // attention writes O in-place over Q
  u16* x_bf   = (u16*)alloc((size_t)NTOK * DIM * 2);
  u16* wcat   = (u16*)alloc((size_t)NFUSE * DIM * 2);
  u16* wqb_b  = (u16*)alloc((size_t)NH * QKH * QR * 2);
  u16* qn     = (u16*)alloc((size_t)NTOK * QR * 2);
  u16* C1     = (u16*)alloc((size_t)NTOK * NFUSE * 2);

  cvt_all<<<10048, 256, 0, stream>>>(x, x_bf, wqa, wkva, wcat, wqb, wqb_b,
                                     wo, wo_b, wkvb, wbv, wbkt);

  // fused [q_a | kv_full] = x @ [wq_a; wkv_a]^T   (4096 x 1600, K=2048) -> bf16 C1
  gemm_bt<1><<<dim3(13, NTOK / 128, 1), 256, 0, stream>>>(
      x_bf, wcat, C1, nullptr, nullptr, nullptr,
      NTOK, NFUSE, DIM, DIM, DIM, NFUSE, 0, 0, 0, 1.f);
  post_qkv<<<NTOK, 256, 0, stream>>>(C1, qnw, kvnw, fc, fs, qn, kv_sw, v8b, kpe_sw);
  // q = qn @ wq_b^T with q-split + FUSED ROPE epilogue -> qnope + rotated qpe
  gemm_bt<2><<<dim3(NH * QKH / 128, NTOK / 128, 1), 256, 0, stream>>>(
      qn, wqb_b, qnope, qpe, fc, fs,
      NTOK, NH * QKH, QR, QR, QR, 0, 0, 0, 0, 1.f);
  // q_lat pre-scaled by SCALE_ (softmax scale folded into Q)
  gemm_bt<1><<<dim3(KVR / 128, NTOK / 128, NH), 256, 0, stream>>>(
      qnope, wbkt, qlat, nullptr, nullptr, nullptr,
      NTOK, KVR, NOPE, NOPE, NOPE, KVR,
      (long)NTOK * NOPE, (long)KVR * NOPE, (long)NTOK * KVR, SCALE_);
  attn_kernel<<<dim3(512, 1, 1), 256, 0, stream>>>(
      qlat, qpe, kv_sw, v8b, kpe_sw, olat);
  gemm_bt<1><<<dim3(1, NTOK / 128, NH), 256, 0, stream>>>(
      olat, wbv, oflat, nullptr, nullptr, nullptr,
      NTOK, VH, KVR, KVR, KVR, DIM,
      (long)NTOK * KVR, (long)VH * KVR, (long)VH, 1.f);
  gemm_bt<0><<<dim3(DIM / 128, NTOK / 128, 1), 256, 0, stream>>>(
      oflat, wo_b, out, nullptr, nullptr, nullptr,
      NTOK, DIM, DIM, DIM, DIM, DIM, 0, 0, 0, 1.f);
}

// Round 19
// 243.481 us; speedup vs baseline: 1.7415x; 1.5842x over previous
//
#include <hip/hip_runtime.h>
#include <hip/hip_bf16.h>
#include <stdint.h>

#define BB 4
#define SS 1024
#define DIM 2048
#define NH 16
#define QR 1024
#define KVR 512
#define NOPE 128
#define ROPE 64
#define VH 128
#define QKH 192
#define NTOK 4096
#define NFUSE 1600   // QR + 576

static constexpr float SCALE_ = 0.07216878364870322f; // 192^-0.5
static constexpr float EPS_ = 1e-6f;

typedef unsigned short u16;
typedef unsigned int u32;
using f32x4  = __attribute__((ext_vector_type(4))) float;
using bf16x8 = __attribute__((ext_vector_type(8))) __bf16;

#define MFMA16 __builtin_amdgcn_mfma_f32_16x16x32_bf16

__device__ __forceinline__ u16 f2b(float f) {
  u32 u = __float_as_uint(f);
  u32 r = u + 0x7fffu + ((u >> 16) & 1u);   // RNE
  return (u16)(r >> 16);
}
__device__ __forceinline__ u32 pk2(float a, float b) {
  return (u32)f2b(a) | ((u32)f2b(b) << 16);
}
__device__ __forceinline__ float b2f(u32 hi16) {
  return __uint_as_float(hi16 << 16);
}
__device__ __forceinline__ void gll16(const u16* g, u16* l) {
  __builtin_amdgcn_global_load_lds(
      (const __attribute__((address_space(1))) void*)g,
      (__attribute__((address_space(3))) void*)l, 16, 0, 0);
}

// ---------------- fused f32->bf16 conversions (7 regions, 1 launch) ----------------
// R0 x  R1 wqa->wcat  R2 wqb  R3 wkva->wcat  R4 wo  R5 wbv (v-half of wkvb)
// R6 wbk (k-half of wkvb, natural layout)
__global__ __launch_bounds__(256) void cvt_all(
    const float* __restrict__ x, u16* __restrict__ x_bf,
    const float* __restrict__ wqa, const float* __restrict__ wkva,
    u16* __restrict__ wcat,
    const float* __restrict__ wqb, u16* __restrict__ wqb_b,
    const float* __restrict__ wo, u16* __restrict__ wo_b,
    const float* __restrict__ wkvb, u16* __restrict__ wbv,
    u16* __restrict__ wbk) {
  int bid = blockIdx.x;
  int tid = threadIdx.x;
  const float* src; u16* dst; long i;
  if (bid < 4096)      { src = x;    dst = x_bf;  i = (long)bid * 2048; }
  else if (bid < 5120) { src = wqa;  dst = wcat;  i = (long)(bid - 4096) * 2048; }
  else if (bid < 6656) { src = wqb;  dst = wqb_b; i = (long)(bid - 5120) * 2048; }
  else if (bid < 7232) { src = wkva; dst = wcat + (long)QR * DIM; i = (long)(bid - 6656) * 2048; }
  else if (bid < 9280) { src = wo;   dst = wo_b;  i = (long)(bid - 7232) * 2048; }
  else if (bid < 9792) {  // wbv: rows 128..255 of each head
    long e = (long)(bid - 9280) * 2048;
    int h = (int)(e >> 16);
    int rem = (int)(e & 65535);
    src = wkvb + (((long)h * 256 + 128) << 9) + rem;
    dst = wbv + ((long)h << 16) + rem;
    i = 0;
  } else {               // wbk: rows 0..127 of each head (natural layout)
    long e = (long)(bid - 9792) * 2048;
    int h = (int)(e >> 16);
    int rem = (int)(e & 65535);
    src = wkvb + (((long)h * 256) << 9) + rem;
    dst = wbk + ((long)h << 16) + rem;
    i = 0;
  }
  i += tid * 8;
  float4 a = *(const float4*)&src[i];
  float4 b = *(const float4*)&src[i + 4];
  uint4 o;
  o.x = pk2(a.x, a.y); o.y = pk2(a.z, a.w);
  o.z = pk2(b.x, b.y); o.w = pk2(b.z, b.w);
  *(uint4*)&dst[i] = o;
}

// ---------------- post_qkv: rms_q + kv post fused (C1 bf16, ldc=1600) ----------------
// q half: rmsnorm(1024) -> qn.  kv half: rmsnorm(512) -> kv (plain bf16, GEMM A);
// rope(k_pe) -> kpe_sw (token-swizzled for attn LDS reads).
__global__ __launch_bounds__(256) void post_qkv(
    const u16* __restrict__ C1, const float* __restrict__ qw,
    const float* __restrict__ kw, const float* __restrict__ fc,
    const float* __restrict__ fs, u16* __restrict__ qn,
    u16* __restrict__ kv, u16* __restrict__ kpe_sw) {
  int r = blockIdx.x, tid = threadIdx.x;
  int b = r >> 10, t = r & (SS - 1);
  const u16* row = C1 + (long)r * NFUSE;
  u32 qa_ = *(const u32*)&row[tid * 4];
  u32 qb_ = *(const u32*)&row[tid * 4 + 2];
  float q0 = b2f(qa_ & 0xffffu), q1 = b2f(qa_ >> 16);
  float q2 = b2f(qb_ & 0xffffu), q3 = b2f(qb_ >> 16);
  float ssq = q0 * q0 + q1 * q1 + q2 * q2 + q3 * q3;
  u32 ka_ = *(const u32*)&row[QR + tid * 2];
  float k0 = b2f(ka_ & 0xffffu), k1 = b2f(ka_ >> 16);
  float ssk = k0 * k0 + k1 * k1;
  for (int m = 1; m < 64; m <<= 1) {
    ssq += __shfl_xor(ssq, m);
    ssk += __shfl_xor(ssk, m);
  }
  __shared__ float redq[4], redk[4];
  if ((tid & 63) == 0) { redq[tid >> 6] = ssq; redk[tid >> 6] = ssk; }
  __syncthreads();
  float scq = rsqrtf((redq[0] + redq[1] + redq[2] + redq[3]) / QR + EPS_);
  float sck = rsqrtf((redk[0] + redk[1] + redk[2] + redk[3]) / KVR + EPS_);
  const float4 wv4 = *(const float4*)&qw[tid * 4];
  uint2 o;
  o.x = pk2(q0 * scq * wv4.x, q1 * scq * wv4.y);
  o.y = pk2(q2 * scq * wv4.z, q3 * scq * wv4.w);
  *(uint2*)&qn[(long)r * QR + tid * 4] = o;
  int c = tid * 2;
  float y0 = k0 * sck * kw[c], y1 = k1 * sck * kw[c + 1];
  *(u32*)&kv[(long)r * KVR + c] = pk2(y0, y1);
  if (tid < 32) {
    int xm = (t & 7) << 3;
    u32 pa = *(const u32*)&row[QR + KVR + tid * 2];
    float x0 = b2f(pa & 0xffffu), x1 = b2f(pa >> 16);
    float cc = fc[t * 32 + tid], sn = fs[t * 32 + tid];
    *(u32*)&kpe_sw[((long)b * SS + t) * ROPE + ((tid * 2) ^ xm)] =
        pk2(x0 * cc - x1 * sn, x0 * sn + x1 * cc);
  }
}

// ---------------- GEMM: C(M,N) = A(M,K) * B(N,K)^T ----------------
// MODE 0: f32 C.  MODE 1: bf16 C.  MODE 2: q-split + rope epilogue (qnope
// scaled, qpe roped+scaled).  MODE 3: bf16 C with per-row col-XOR swizzle
// (knope for attn LDS reads).  MODE 4: v8-subtiled bf16 store (vhead).
template <int MODE>
__global__ __launch_bounds__(256) void gemm_bt(const u16* __restrict__ Ag,
                                               const u16* __restrict__ Bg,
                                               void* __restrict__ Cg,
                                               void* __restrict__ Cg2,
                                               const float* __restrict__ fcp,
                                               const float* __restrict__ fsp,
                                               int M, int N, int K,
                                               int lda, int ldb, int ldc,
                                               long sA, long sB, long sC,
                                               float oscale) {
  const u16* A = Ag + (long)blockIdx.z * sA;
  const u16* Bm = Bg + (long)blockIdx.z * sB;
  const int nbx = gridDim.x;
  int bidf = blockIdx.y * nbx + blockIdx.x;
  {
    const int nwg = nbx * gridDim.y;
    if ((nwg & 7) == 0)
      bidf = (bidf & 7) * (nwg >> 3) + (bidf >> 3);   // bijective XCD chunks
  }
  const int row0 = (bidf / nbx) * 128;
  const int col0 = (bidf % nbx) * 128;
  const int tid = threadIdx.x;
  const int wave = tid >> 6, lane = tid & 63;
  const int g = lane >> 4, r = lane & 15;
  const int wr = wave >> 1, wc = wave & 1;

  __shared__ u16 As[2][128 * 32];
  __shared__ u16 Bs[2][128 * 32];

  f32x4 acc[4][4] = {};
  const int nk = K >> 5;

  auto stage = [&](int kt, int p) {
    int k0 = kt << 5;
#pragma unroll
    for (int j = 0; j < 2; ++j) {
      int ldsoff = (j * 4096 + wave * 1024) >> 1;
      int rowi = j * 64 + wave * 16 + (lane >> 2);
      int coli = (lane & 3) << 3;
      const u16* ga = A + (long)(row0 + rowi) * lda + k0 + coli;
      gll16(ga, &As[p][ldsoff]);
      int rb = col0 + rowi; if (rb > N - 1) rb = N - 1;
      const u16* gb = Bm + (long)rb * ldb + k0 + coli;
      gll16(gb, &Bs[p][ldsoff]);
    }
  };

  stage(0, 0);
  for (int kt = 0; kt < nk; ++kt) {
    __syncthreads();
    if (kt + 1 < nk) stage(kt + 1, (kt + 1) & 1);
    const int p = kt & 1;
    bf16x8 af[4], bf[4];
#pragma unroll
    for (int i = 0; i < 4; i++) {
      af[i] = *(const bf16x8*)&As[p][(wr * 64 + i * 16 + r) * 32 + g * 8];
      bf[i] = *(const bf16x8*)&Bs[p][(wc * 64 + i * 16 + r) * 32 + g * 8];
    }
#pragma unroll
    for (int i = 0; i < 4; i++)
#pragma unroll
      for (int j = 0; j < 4; j++)
        acc[i][j] = MFMA16(af[i], bf[j], acc[i][j], 0, 0, 0);
  }

#pragma unroll
  for (int i = 0; i < 4; i++)
#pragma unroll
    for (int j = 0; j < 4; j++) {
      int rowb = row0 + wr * 64 + i * 16 + g * 4;
      int colc = col0 + wc * 64 + j * 16 + r;
      if constexpr (MODE == 2) {
        int hh = colc / QKH;
        int dd = colc - hh * QKH;
        if (dd < NOPE) {
          u16* qn = (u16*)Cg;
#pragma unroll
          for (int e = 0; e < 4; e++)
            qn[((long)hh * NTOK + rowb + e) * NOPE + dd] = f2b(acc[i][j][e] * oscale);
        } else {
          u16* qpr = (u16*)Cg2;
          int jr = (dd - NOPE) >> 1;
          const int odd = dd & 1;
#pragma unroll
          for (int e = 0; e < 4; e++) {
            float own = acc[i][j][e];
            float partner = __shfl_xor(own, 1);
            int s = (rowb + e) & (SS - 1);
            float cc = fcp[s * 32 + jr], sn = fsp[s * 32 + jr];
            float y = odd ? (partner * sn + own * cc) : (own * cc - partner * sn);
            qpr[((long)hh * NTOK + rowb + e) * ROPE + (dd - NOPE)] = f2b(y * SCALE_);
          }
        }
      } else if constexpr (MODE == 3) {
        u16* C = (u16*)Cg + (long)blockIdx.z * sC;
#pragma unroll
        for (int e = 0; e < 4; e++) {
          int rr = rowb + e;
          C[(long)rr * 128 + (colc ^ ((rr & 7) << 3))] = f2b(acc[i][j][e]);
        }
      } else if constexpr (MODE == 4) {
        u16* C = (u16*)Cg + (long)blockIdx.z * sC;
#pragma unroll
        for (int e = 0; e < 4; e++) {
          int rr = rowb + e;
          C[((long)(rr >> 3) * 128 + colc) * 8 + (rr & 7)] = f2b(acc[i][j][e]);
        }
      } else if (colc < N) {
        if constexpr (MODE == 1) {
          u16* C = (u16*)Cg + (long)blockIdx.z * sC;
#pragma unroll
          for (int e = 0; e < 4; e++)
            C[(long)(rowb + e) * ldc + colc] = f2b(acc[i][j][e] * oscale);
        } else {
          float* C = (float*)Cg + (long)blockIdx.z * sC;
#pragma unroll
          for (int e = 0; e < 4; e++)
            C[(long)(rowb + e) * ldc + colc] = acc[i][j][e] * oscale;
        }
      }
    }
}

// ---------------- flash attention v19: NON-ABSORBED (d=192, dv=128) ----------------
// 1024 blocks (4b x 16h x 16 chunks of 64 rows), big chunks first, XCD-pinned
// batches. 4 waves, 256 threads; wave owns 16 q-rows for QK+softmax (qf[6] in
// regs); PV: all 64 rows x own 32 V-cols (acc 32/lane). K/V/kpe staged in LDS
// (26 KB) via gll16; ~115 VGPR -> up to 4 blocks/CU. Same proven barrier/
// swizzle scheme as r13, scaled down.
__global__ __launch_bounds__(256) void attn_kernel(
    const u16* __restrict__ qnope, const u16* __restrict__ qpe,
    const u16* __restrict__ knope, const u16* __restrict__ vhead,
    const u16* __restrict__ kpe_sw, u16* __restrict__ oflat) {
  const int bid = blockIdx.x;
  const int xcd = bid & 7, idx = bid >> 3;
  const int b = xcd >> 1;
  const int h = idx & 15;
  const int jj = ((idx >> 4) << 1) | (xcd & 1);   // 0..15
  const int jc = 15 - jj;                         // big chunks first
  const int qa = jc * 64;
  const int nt = 2 * jc + 2;                      // 32-key tiles
  const int wv = threadIdx.x >> 6, lane = threadIdx.x & 63;
  const int g = lane >> 4, r = lane & 15;
  const int xm = (r & 7) << 3;
  const int keb = (g * 8) ^ xm;
  const int kob = keb - 2 * (xm & 32);

  __shared__ __attribute__((aligned(16))) u16 Ks[32 * 128];   // 8 KB swz K
  __shared__ __attribute__((aligned(16))) u16 Vs[32 * 128];   // 8 KB subtiled V
  __shared__ __attribute__((aligned(16))) u16 Kp[32 * 64];    // 4 KB swz kpe
  __shared__ __attribute__((aligned(16))) u16 P[64][40];      // 5 KB
  __shared__ float alphab[64];
  __shared__ float lbuf[64];

  const u16* KNg = knope + ((long)h * NTOK + (long)b * SS) * 128;
  const u16* VHg = vhead + (long)h * NTOK * 128;   // subtiled; tok = b*SS+t
  const u16* KPg = kpe_sw + (long)b * SS * ROPE;
  const long vbase = (long)b * SS * 128;

  auto stage = [&](int t0) {
#pragma unroll
    for (int i = 0; i < 2; ++i) {
      int row = wv * 8 + i * 4;   // wave-uniform; lanes cover 4 rows x 128
      gll16(KNg + (long)(t0 + row) * 128 + lane * 8, &Ks[row * 128]);
      gll16(VHg + vbase + (long)t0 * 128 + (wv * 2 + i) * 512 + lane * 8,
            &Vs[(wv * 2 + i) * 512]);
    }
    gll16(KPg + (long)(t0 + wv * 8) * ROPE + lane * 8, &Kp[wv * 8 * 64]);
  };

  const int q_row = qa + wv * 16 + r;
  const u16* Q  = qnope + ((long)h * NTOK + (long)b * SS + q_row) * 128;
  const u16* Qp = qpe   + ((long)h * NTOK + (long)b * SS + q_row) * ROPE;
  bf16x8 qf[6];
#pragma unroll
  for (int c = 0; c < 4; ++c) qf[c] = *(const bf16x8*)&Q[c * 32 + g * 8];
  qf[4] = *(const bf16x8*)&Qp[g * 8];
  qf[5] = *(const bf16x8*)&Qp[32 + g * 8];

  f32x4 acc[4][2];
#pragma unroll
  for (int i = 0; i < 4; i++)
#pragma unroll
    for (int jn = 0; jn < 2; jn++) acc[i][jn] = f32x4{0.f, 0.f, 0.f, 0.f};
  float m_run = -1e30f, l_run = 0.f;

  stage(0);
  __syncthreads();

  for (int tt = 0; tt < nt; ++tt) {
    const int t0 = tt << 5;

    // QK^T over 32 keys (2 row-groups of 16): 4 nope + 2 rope c-steps
    f32x4 st0 = {0.f, 0.f, 0.f, 0.f}, st1 = {0.f, 0.f, 0.f, 0.f};
#pragma unroll
    for (int c = 0; c < 4; ++c) {
      int off = ((c & 1) ? kob : keb) + c * 32;
      bf16x8 k0 = *(const bf16x8*)&Ks[r * 128 + off];
      bf16x8 k1 = *(const bf16x8*)&Ks[(16 + r) * 128 + off];
      st0 = MFMA16(k0, qf[c], st0, 0, 0, 0);
      st1 = MFMA16(k1, qf[c], st1, 0, 0, 0);
    }
    {
      bf16x8 k0 = *(const bf16x8*)&Kp[r * 64 + keb];
      bf16x8 k1 = *(const bf16x8*)&Kp[(16 + r) * 64 + keb];
      st0 = MFMA16(k0, qf[4], st0, 0, 0, 0);
      st1 = MFMA16(k1, qf[4], st1, 0, 0, 0);
      bf16x8 k2 = *(const bf16x8*)&Kp[r * 64 + kob + 32];
      bf16x8 k3 = *(const bf16x8*)&Kp[(16 + r) * 64 + kob + 32];
      st0 = MFMA16(k2, qf[5], st0, 0, 0, 0);
      st1 = MFMA16(k3, qf[5], st1, 0, 0, 0);
    }

    // V fragments -> regs (precede B1; stage overwrites Vs)
    bf16x8 vf[2];
#pragma unroll
    for (int nc = 0; nc < 2; ++nc)
      vf[nc] = *(const bf16x8*)&Vs[((g << 7) + (wv << 5) + (nc << 4) + r) << 3];

    // scores (mask only last 2 tiles) + softmax
    float sv[8];
    float smax = -1e30f;
    if (t0 + 31 > qa) {
#pragma unroll
      for (int i = 0; i < 4; i++) {
        int t = t0 + g * 4 + i;
        sv[i]     = (t      <= q_row) ? st0[i] : -1e30f;
        sv[4 + i] = (t + 16 <= q_row) ? st1[i] : -1e30f;
        smax = fmaxf(smax, fmaxf(sv[i], sv[4 + i]));
      }
    } else {
#pragma unroll
      for (int i = 0; i < 4; i++) {
        sv[i] = st0[i]; sv[4 + i] = st1[i];
        smax = fmaxf(smax, fmaxf(sv[i], sv[4 + i]));
      }
    }
    smax = fmaxf(smax, __shfl_xor(smax, 16));
    smax = fmaxf(smax, __shfl_xor(smax, 32));
    float m_new = fmaxf(m_run, smax);
    float alpha = __expf(m_run - m_new);
    float ps = 0.f;
#pragma unroll
    for (int i = 0; i < 8; i++) {
      sv[i] = (sv[i] < -1e29f) ? 0.f : __expf(sv[i] - m_new);
      ps += sv[i];
    }
    ps += __shfl_xor(ps, 16);
    ps += __shfl_xor(ps, 32);
    l_run = l_run * alpha + ps;
    m_run = m_new;

    uint2 pw0, pw1;
    pw0.x = pk2(sv[0], sv[1]); pw0.y = pk2(sv[2], sv[3]);
    pw1.x = pk2(sv[4], sv[5]); pw1.y = pk2(sv[6], sv[7]);
    *(uint2*)&P[wv * 16 + r][g * 4]      = pw0;
    *(uint2*)&P[wv * 16 + r][16 + g * 4] = pw1;
    if (g == 0) alphab[wv * 16 + r] = alpha;
    __syncthreads();                   // B1: P/alpha visible; all LDS reads done
    if (tt + 1 < nt) stage(t0 + 32);   // overwrite K/V/kpe; drained at B2

    // PV: all 64 rows x own 32 cols
#pragma unroll
    for (int mc = 0; mc < 4; ++mc) {
      bf16x8 pa = *(const bf16x8*)&P[mc * 16 + r][g * 8];
      f32x4 a4 = *(const f32x4*)&alphab[mc * 16 + g * 4];
#pragma unroll
      for (int nc = 0; nc < 2; ++nc) {
        f32x4 t = acc[mc][nc] * a4;
        acc[mc][nc] = MFMA16(pa, vf[nc], t, 0, 0, 0);
      }
    }
    __syncthreads();                   // B2: stage drained; P safe to rewrite
  }

  if (g == 0) lbuf[wv * 16 + r] = l_run;
  __syncthreads();
  u16* O = oflat + ((long)b * SS + qa) * DIM + h * VH;
#pragma unroll
  for (int mc = 0; mc < 4; ++mc) {
    f32x4 li = *(const f32x4*)&lbuf[mc * 16 + g * 4];
#pragma unroll
    for (int e = 0; e < 4; e++) li[e] = 1.f / li[e];
#pragma unroll
    for (int nc = 0; nc < 2; ++nc) {
      int col = wv * 32 + nc * 16 + r;
#pragma unroll
      for (int e = 0; e < 4; e++)
        O[(long)(mc * 16 + g * 4 + e) * DIM + col] = f2b(acc[mc][nc][e] * li[e]);
    }
  }
}

// ---------------- host launch ----------------
extern "C" void kernel_launch(void* const* d_in, const int* in_sizes, int n_in,
                              void* d_out, int out_size, void* d_ws, size_t ws_size,
                              hipStream_t stream) {
  (void)in_sizes; (void)n_in; (void)out_size; (void)ws_size;
  const float* x    = (const float*)d_in[0];
  const float* fc   = (const float*)d_in[2];
  const float* fs   = (const float*)d_in[3];
  const float* wqa  = (const float*)d_in[4];
  const float* qnw  = (const float*)d_in[5];
  const float* wqb  = (const float*)d_in[6];
  const float* wkva = (const float*)d_in[7];
  const float* kvnw = (const float*)d_in[8];
  const float* wkvb = (const float*)d_in[9];
  const float* wo   = (const float*)d_in[10];
  float* out = (float*)d_out;

  char* w = (char*)d_ws;
  size_t off = 0;
  auto alloc = [&](size_t bytes) {
    void* p = w + off;
    off += (bytes + 255) & ~(size_t)255;
    return p;
  };
  u16* wbk    = (u16*)alloc((size_t)NH * NOPE * KVR * 2);
  u16* wbv    = (u16*)alloc((size_t)NH * VH * KVR * 2);
  u16* wo_b   = (u16*)alloc((size_t)DIM * DIM * 2);
  u16* qnope  = (u16*)alloc((size_t)NH * NTOK * NOPE * 2);
  u16* qpe    = (u16*)alloc((size_t)NH * NTOK * ROPE * 2);
  u16* knope  = (u16*)alloc((size_t)NH * NTOK * NOPE * 2);
  u16* vhead  = (u16*)alloc((size_t)NH * NTOK * VH * 2);
  u16* kvb    = (u16*)alloc((size_t)NTOK * KVR * 2);
  u16* kpe_sw = (u16*)alloc((size_t)BB * SS * ROPE * 2);
  u16* oflat  = (u16*)alloc((size_t)NTOK * DIM * 2);
  u16* x_bf   = (u16*)alloc((size_t)NTOK * DIM * 2);
  u16* wcat   = (u16*)alloc((size_t)NFUSE * DIM * 2);
  u16* wqb_b  = (u16*)alloc((size_t)NH * QKH * QR * 2);
  u16* qn     = (u16*)alloc((size_t)NTOK * QR * 2);
  u16* C1     = (u16*)alloc((size_t)NTOK * NFUSE * 2);

  cvt_all<<<10304, 256, 0, stream>>>(x, x_bf, wqa, wkva, wcat, wqb, wqb_b,
                                     wo, wo_b, wkvb, wbv, wbk);

  // fused [q_a | kv_full] = x @ [wq_a; wkv_a]^T   (4096 x 1600, K=2048) -> bf16 C1
  gemm_bt<1><<<dim3(13, NTOK / 128, 1), 256, 0, stream>>>(
      x_bf, wcat, C1, nullptr, nullptr, nullptr,
      NTOK, NFUSE, DIM, DIM, DIM, NFUSE, 0, 0, 0, 1.f);
  post_qkv<<<NTOK, 256, 0, stream>>>(C1, qnw, kvnw, fc, fs, qn, kvb, kpe_sw);
  // q = qn @ wq_b^T with q-split + rope epilogue (both parts pre-scaled)
  gemm_bt<2><<<dim3(NH * QKH / 128, NTOK / 128, 1), 256, 0, stream>>>(
      qn, wqb_b, qnope, qpe, fc, fs,
      NTOK, NH * QKH, QR, QR, QR, 0, 0, 0, 0, SCALE_);
  // k_nope[h] = kv @ wb_k[h]^T  (4096 x 128, K=512) -> token-swizzled knope
  gemm_bt<3><<<dim3(1, NTOK / 128, NH), 256, 0, stream>>>(
      kvb, wbk, knope, nullptr, nullptr, nullptr,
      NTOK, NOPE, KVR, KVR, KVR, NOPE,
      0, (long)NOPE * KVR, (long)NTOK * NOPE, 1.f);
  // v[h] = kv @ wb_v[h]^T  (4096 x 128, K=512) -> v8-subtiled vhead
  gemm_bt<4><<<dim3(1, NTOK / 128, NH), 256, 0, stream>>>(
      kvb, wbv, vhead, nullptr, nullptr, nullptr,
      NTOK, VH, KVR, KVR, KVR, VH,
      0, (long)VH * KVR, (long)NTOK * VH, 1.f);
  attn_kernel<<<dim3(1024, 1, 1), 256, 0, stream>>>(
      qnope, qpe, knope, vhead, kpe_sw, oflat);
  gemm_bt<0><<<dim3(DIM / 128, NTOK / 128, 1), 256, 0, stream>>>(
      oflat, wo_b, out, nullptr, nullptr, nullptr,
      NTOK, DIM, DIM, DIM, DIM, DIM, 0, 0, 0, 1.f);
}

// Round 21
// 242.437 us; speedup vs baseline: 1.7490x; 1.0043x over previous
//
#include <hip/hip_runtime.h>
#include <hip/hip_bf16.h>
#include <stdint.h>

#define BB 4
#define SS 1024
#define DIM 2048
#define NH 16
#define QR 1024
#define KVR 512
#define NOPE 128
#define ROPE 64
#define VH 128
#define QKH 192
#define NTOK 4096
#define NFUSE 1600   // QR + 576

static constexpr float SCALE_ = 0.07216878364870322f; // 192^-0.5
static constexpr float EPS_ = 1e-6f;

typedef unsigned short u16;
typedef unsigned int u32;
using f32x4  = __attribute__((ext_vector_type(4))) float;
using bf16x8 = __attribute__((ext_vector_type(8))) __bf16;

#define MFMA16 __builtin_amdgcn_mfma_f32_16x16x32_bf16

__device__ __forceinline__ u16 f2b(float f) {
  u32 u = __float_as_uint(f);
  u32 r = u + 0x7fffu + ((u >> 16) & 1u);   // RNE
  return (u16)(r >> 16);
}
__device__ __forceinline__ u32 pk2(float a, float b) {
  return (u32)f2b(a) | ((u32)f2b(b) << 16);
}
__device__ __forceinline__ float b2f(u32 hi16) {
  return __uint_as_float(hi16 << 16);
}
__device__ __forceinline__ void gll16(const u16* g, u16* l) {
  __builtin_amdgcn_global_load_lds(
      (const __attribute__((address_space(1))) void*)g,
      (__attribute__((address_space(3))) void*)l, 16, 0, 0);
}

// ---------------- fused f32->bf16 conversions (6 regions, 1 launch) ----------------
// R0 x(4096 blk)  R1 wqa->wcat(1024)  R2 wqb(1536)  R3 wkva->wcat(576)
// R4 wo(2048)  R5 wkvb->wbcat(1024 blk: 16*256*512 floats)  => grid 10304
__global__ __launch_bounds__(256) void cvt_all(
    const float* __restrict__ x, u16* __restrict__ x_bf,
    const float* __restrict__ wqa, const float* __restrict__ wkva,
    u16* __restrict__ wcat,
    const float* __restrict__ wqb, u16* __restrict__ wqb_b,
    const float* __restrict__ wo, u16* __restrict__ wo_b,
    const float* __restrict__ wkvb, u16* __restrict__ wbcat) {
  int bid = blockIdx.x;
  int tid = threadIdx.x;
  const float* src; u16* dst; long i;
  if (bid < 4096)      { src = x;    dst = x_bf;  i = (long)bid * 2048; }
  else if (bid < 5120) { src = wqa;  dst = wcat;  i = (long)(bid - 4096) * 2048; }
  else if (bid < 6656) { src = wqb;  dst = wqb_b; i = (long)(bid - 5120) * 2048; }
  else if (bid < 7232) { src = wkva; dst = wcat + (long)QR * DIM; i = (long)(bid - 6656) * 2048; }
  else if (bid < 9280) { src = wo;   dst = wo_b;  i = (long)(bid - 7232) * 2048; }
  else                 { src = wkvb; dst = wbcat; i = (long)(bid - 9280) * 2048; }
  i += tid * 8;
  float4 a = *(const float4*)&src[i];
  float4 b = *(const float4*)&src[i + 4];
  uint4 o;
  o.x = pk2(a.x, a.y); o.y = pk2(a.z, a.w);
  o.z = pk2(b.x, b.y); o.w = pk2(b.z, b.w);
  *(uint4*)&dst[i] = o;
}

// ---------------- post_qkv: rms_q + kv post fused (C1 bf16, ldc=1600) ----------------
__global__ __launch_bounds__(256) void post_qkv(
    const u16* __restrict__ C1, const float* __restrict__ qw,
    const float* __restrict__ kw, const float* __restrict__ fc,
    const float* __restrict__ fs, u16* __restrict__ qn,
    u16* __restrict__ kv, u16* __restrict__ kpe_sw) {
  int r = blockIdx.x, tid = threadIdx.x;
  int b = r >> 10, t = r & (SS - 1);
  const u16* row = C1 + (long)r * NFUSE;
  u32 qa_ = *(const u32*)&row[tid * 4];
  u32 qb_ = *(const u32*)&row[tid * 4 + 2];
  float q0 = b2f(qa_ & 0xffffu), q1 = b2f(qa_ >> 16);
  float q2 = b2f(qb_ & 0xffffu), q3 = b2f(qb_ >> 16);
  float ssq = q0 * q0 + q1 * q1 + q2 * q2 + q3 * q3;
  u32 ka_ = *(const u32*)&row[QR + tid * 2];
  float k0 = b2f(ka_ & 0xffffu), k1 = b2f(ka_ >> 16);
  float ssk = k0 * k0 + k1 * k1;
  for (int m = 1; m < 64; m <<= 1) {
    ssq += __shfl_xor(ssq, m);
    ssk += __shfl_xor(ssk, m);
  }
  __shared__ float redq[4], redk[4];
  if ((tid & 63) == 0) { redq[tid >> 6] = ssq; redk[tid >> 6] = ssk; }
  __syncthreads();
  float scq = rsqrtf((redq[0] + redq[1] + redq[2] + redq[3]) / QR + EPS_);
  float sck = rsqrtf((redk[0] + redk[1] + redk[2] + redk[3]) / KVR + EPS_);
  const float4 wv4 = *(const float4*)&qw[tid * 4];
  uint2 o;
  o.x = pk2(q0 * scq * wv4.x, q1 * scq * wv4.y);
  o.y = pk2(q2 * scq * wv4.z, q3 * scq * wv4.w);
  *(uint2*)&qn[(long)r * QR + tid * 4] = o;
  int c = tid * 2;
  float y0 = k0 * sck * kw[c], y1 = k1 * sck * kw[c + 1];
  *(u32*)&kv[(long)r * KVR + c] = pk2(y0, y1);
  if (tid < 32) {
    int xm = (t & 7) << 3;
    u32 pa = *(const u32*)&row[QR + KVR + tid * 2];
    float x0 = b2f(pa & 0xffffu), x1 = b2f(pa >> 16);
    float cc = fc[t * 32 + tid], sn = fs[t * 32 + tid];
    *(u32*)&kpe_sw[((long)b * SS + t) * ROPE + ((tid * 2) ^ xm)] =
        pk2(x0 * cc - x1 * sn, x0 * sn + x1 * cc);
  }
}

// ---------------- GEMM: C(M,N) = A(M,K) * B(N,K)^T ----------------
// MODE 0: f32 C.  MODE 1: bf16 C.  MODE 2: q-split + rope epilogue.
// MODE 5: kv-split epilogue — cols 0..127 -> knope (row-XOR swizzle),
//         cols 128..255 -> vhead (v8-subtiled); head = blockIdx.z.
template <int MODE>
__global__ __launch_bounds__(256) void gemm_bt(const u16* __restrict__ Ag,
                                               const u16* __restrict__ Bg,
                                               void* __restrict__ Cg,
                                               void* __restrict__ Cg2,
                                               const float* __restrict__ fcp,
                                               const float* __restrict__ fsp,
                                               int M, int N, int K,
                                               int lda, int ldb, int ldc,
                                               long sA, long sB, long sC,
                                               float oscale) {
  const u16* A = Ag + (long)blockIdx.z * sA;
  const u16* Bm = Bg + (long)blockIdx.z * sB;
  const int nbx = gridDim.x;
  int bidf = blockIdx.y * nbx + blockIdx.x;
  {
    const int nwg = nbx * gridDim.y;
    if ((nwg & 7) == 0)
      bidf = (bidf & 7) * (nwg >> 3) + (bidf >> 3);   // bijective XCD chunks
  }
  const int row0 = (bidf / nbx) * 128;
  const int col0 = (bidf % nbx) * 128;
  const int tid = threadIdx.x;
  const int wave = tid >> 6, lane = tid & 63;
  const int g = lane >> 4, r = lane & 15;
  const int wr = wave >> 1, wc = wave & 1;

  __shared__ u16 As[2][128 * 32];
  __shared__ u16 Bs[2][128 * 32];

  f32x4 acc[4][4] = {};
  const int nk = K >> 5;

  auto stage = [&](int kt, int p) {
    int k0 = kt << 5;
#pragma unroll
    for (int j = 0; j < 2; ++j) {
      int ldsoff = (j * 4096 + wave * 1024) >> 1;
      int rowi = j * 64 + wave * 16 + (lane >> 2);
      int coli = (lane & 3) << 3;
      const u16* ga = A + (long)(row0 + rowi) * lda + k0 + coli;
      gll16(ga, &As[p][ldsoff]);
      int rb = col0 + rowi; if (rb > N - 1) rb = N - 1;
      const u16* gb = Bm + (long)rb * ldb + k0 + coli;
      gll16(gb, &Bs[p][ldsoff]);
    }
  };

  stage(0, 0);
  for (int kt = 0; kt < nk; ++kt) {
    __syncthreads();
    if (kt + 1 < nk) stage(kt + 1, (kt + 1) & 1);
    const int p = kt & 1;
    bf16x8 af[4], bf[4];
#pragma unroll
    for (int i = 0; i < 4; i++) {
      af[i] = *(const bf16x8*)&As[p][(wr * 64 + i * 16 + r) * 32 + g * 8];
      bf[i] = *(const bf16x8*)&Bs[p][(wc * 64 + i * 16 + r) * 32 + g * 8];
    }
#pragma unroll
    for (int i = 0; i < 4; i++)
#pragma unroll
      for (int j = 0; j < 4; j++)
        acc[i][j] = MFMA16(af[i], bf[j], acc[i][j], 0, 0, 0);
  }

#pragma unroll
  for (int i = 0; i < 4; i++)
#pragma unroll
    for (int j = 0; j < 4; j++) {
      int rowb = row0 + wr * 64 + i * 16 + g * 4;
      int colc = col0 + wc * 64 + j * 16 + r;
      if constexpr (MODE == 2) {
        int hh = colc / QKH;
        int dd = colc - hh * QKH;
        if (dd < NOPE) {
          u16* qn = (u16*)Cg;
#pragma unroll
          for (int e = 0; e < 4; e++)
            qn[((long)hh * NTOK + rowb + e) * NOPE + dd] = f2b(acc[i][j][e] * oscale);
        } else {
          u16* qpr = (u16*)Cg2;
          int jr = (dd - NOPE) >> 1;
          const int odd = dd & 1;
#pragma unroll
          for (int e = 0; e < 4; e++) {
            float own = acc[i][j][e];
            float partner = __shfl_xor(own, 1);
            int s = (rowb + e) & (SS - 1);
            float cc = fcp[s * 32 + jr], sn = fsp[s * 32 + jr];
            float y = odd ? (partner * sn + own * cc) : (own * cc - partner * sn);
            qpr[((long)hh * NTOK + rowb + e) * ROPE + (dd - NOPE)] = f2b(y * SCALE_);
          }
        }
      } else if constexpr (MODE == 5) {
        const int h = blockIdx.z;
        if (colc < NOPE) {   // knope, row-XOR swizzled
          u16* C = (u16*)Cg + (long)h * NTOK * NOPE;
#pragma unroll
          for (int e = 0; e < 4; e++) {
            int rr = rowb + e;
            C[(long)rr * NOPE + (colc ^ ((rr & 7) << 3))] = f2b(acc[i][j][e]);
          }
        } else {             // vhead, v8-subtiled
          u16* C = (u16*)Cg2 + (long)h * NTOK * VH;
          int vcol = colc - NOPE;
#pragma unroll
          for (int e = 0; e < 4; e++) {
            int rr = rowb + e;
            C[((long)(rr >> 3) * VH + vcol) * 8 + (rr & 7)] = f2b(acc[i][j][e]);
          }
        }
      } else if (colc < N) {
        if constexpr (MODE == 1) {
          u16* C = (u16*)Cg + (long)blockIdx.z * sC;
#pragma unroll
          for (int e = 0; e < 4; e++)
            C[(long)(rowb + e) * ldc + colc] = f2b(acc[i][j][e] * oscale);
        } else {
          float* C = (float*)Cg + (long)blockIdx.z * sC;
#pragma unroll
          for (int e = 0; e < 4; e++)
            C[(long)(rowb + e) * ldc + colc] = acc[i][j][e] * oscale;
        }
      }
    }
}

// ---------------- flash attention (r19-exact: non-absorbed, proven ~60 us) ----------------
__global__ __launch_bounds__(256) void attn_kernel(
    const u16* __restrict__ qnope, const u16* __restrict__ qpe,
    const u16* __restrict__ knope, const u16* __restrict__ vhead,
    const u16* __restrict__ kpe_sw, u16* __restrict__ oflat) {
  const int bid = blockIdx.x;
  const int xcd = bid & 7, idx = bid >> 3;
  const int b = xcd >> 1;
  const int h = idx & 15;
  const int jj = ((idx >> 4) << 1) | (xcd & 1);   // 0..15
  const int jc = 15 - jj;                         // big chunks first
  const int qa = jc * 64;
  const int nt = 2 * jc + 2;                      // 32-key tiles
  const int wv = threadIdx.x >> 6, lane = threadIdx.x & 63;
  const int g = lane >> 4, r = lane & 15;
  const int xm = (r & 7) << 3;
  const int keb = (g * 8) ^ xm;
  const int kob = keb - 2 * (xm & 32);

  __shared__ __attribute__((aligned(16))) u16 Ks[32 * 128];   // 8 KB swz K
  __shared__ __attribute__((aligned(16))) u16 Vs[32 * 128];   // 8 KB subtiled V
  __shared__ __attribute__((aligned(16))) u16 Kp[32 * 64];    // 4 KB swz kpe
  __shared__ __attribute__((aligned(16))) u16 P[64][40];      // 5 KB
  __shared__ float alphab[64];
  __shared__ float lbuf[64];

  const u16* KNg = knope + ((long)h * NTOK + (long)b * SS) * 128;
  const u16* VHg = vhead + (long)h * NTOK * 128;   // subtiled; tok = b*SS+t
  const u16* KPg = kpe_sw + (long)b * SS * ROPE;
  const long vbase = (long)b * SS * 128;

  auto stage = [&](int t0) {
#pragma unroll
    for (int i = 0; i < 2; ++i) {
      int row = wv * 8 + i * 4;   // wave-uniform; lanes cover 4 rows x 128
      gll16(KNg + (long)(t0 + row) * 128 + lane * 8, &Ks[row * 128]);
      gll16(VHg + vbase + (long)t0 * 128 + (wv * 2 + i) * 512 + lane * 8,
            &Vs[(wv * 2 + i) * 512]);
    }
    gll16(KPg + (long)(t0 + wv * 8) * ROPE + lane * 8, &Kp[wv * 8 * 64]);
  };

  const int q_row = qa + wv * 16 + r;
  const u16* Q  = qnope + ((long)h * NTOK + (long)b * SS + q_row) * 128;
  const u16* Qp = qpe   + ((long)h * NTOK + (long)b * SS + q_row) * ROPE;
  bf16x8 qf[6];
#pragma unroll
  for (int c = 0; c < 4; ++c) qf[c] = *(const bf16x8*)&Q[c * 32 + g * 8];
  qf[4] = *(const bf16x8*)&Qp[g * 8];
  qf[5] = *(const bf16x8*)&Qp[32 + g * 8];

  f32x4 acc[4][2];
#pragma unroll
  for (int i = 0; i < 4; i++)
#pragma unroll
    for (int jn = 0; jn < 2; jn++) acc[i][jn] = f32x4{0.f, 0.f, 0.f, 0.f};
  float m_run = -1e30f, l_run = 0.f;

  stage(0);
  __syncthreads();

  for (int tt = 0; tt < nt; ++tt) {
    const int t0 = tt << 5;

    f32x4 st0 = {0.f, 0.f, 0.f, 0.f}, st1 = {0.f, 0.f, 0.f, 0.f};
#pragma unroll
    for (int c = 0; c < 4; ++c) {
      int off = ((c & 1) ? kob : keb) + c * 32;
      bf16x8 k0 = *(const bf16x8*)&Ks[r * 128 + off];
      bf16x8 k1 = *(const bf16x8*)&Ks[(16 + r) * 128 + off];
      st0 = MFMA16(k0, qf[c], st0, 0, 0, 0);
      st1 = MFMA16(k1, qf[c], st1, 0, 0, 0);
    }
    {
      bf16x8 k0 = *(const bf16x8*)&Kp[r * 64 + keb];
      bf16x8 k1 = *(const bf16x8*)&Kp[(16 + r) * 64 + keb];
      st0 = MFMA16(k0, qf[4], st0, 0, 0, 0);
      st1 = MFMA16(k1, qf[4], st1, 0, 0, 0);
      bf16x8 k2 = *(const bf16x8*)&Kp[r * 64 + kob + 32];
      bf16x8 k3 = *(const bf16x8*)&Kp[(16 + r) * 64 + kob + 32];
      st0 = MFMA16(k2, qf[5], st0, 0, 0, 0);
      st1 = MFMA16(k3, qf[5], st1, 0, 0, 0);
    }

    bf16x8 vf[2];
#pragma unroll
    for (int nc = 0; nc < 2; ++nc)
      vf[nc] = *(const bf16x8*)&Vs[((g << 7) + (wv << 5) + (nc << 4) + r) << 3];

    float sv[8];
    float smax = -1e30f;
    if (t0 + 31 > qa) {
#pragma unroll
      for (int i = 0; i < 4; i++) {
        int t = t0 + g * 4 + i;
        sv[i]     = (t      <= q_row) ? st0[i] : -1e30f;
        sv[4 + i] = (t + 16 <= q_row) ? st1[i] : -1e30f;
        smax = fmaxf(smax, fmaxf(sv[i], sv[4 + i]));
      }
    } else {
#pragma unroll
      for (int i = 0; i < 4; i++) {
        sv[i] = st0[i]; sv[4 + i] = st1[i];
        smax = fmaxf(smax, fmaxf(sv[i], sv[4 + i]));
      }
    }
    smax = fmaxf(smax, __shfl_xor(smax, 16));
    smax = fmaxf(smax, __shfl_xor(smax, 32));
    float m_new = fmaxf(m_run, smax);
    float alpha = __expf(m_run - m_new);
    float ps = 0.f;
#pragma unroll
    for (int i = 0; i < 8; i++) {
      sv[i] = (sv[i] < -1e29f) ? 0.f : __expf(sv[i] - m_new);
      ps += sv[i];
    }
    ps += __shfl_xor(ps, 16);
    ps += __shfl_xor(ps, 32);
    l_run = l_run * alpha + ps;
    m_run = m_new;

    uint2 pw0, pw1;
    pw0.x = pk2(sv[0], sv[1]); pw0.y = pk2(sv[2], sv[3]);
    pw1.x = pk2(sv[4], sv[5]); pw1.y = pk2(sv[6], sv[7]);
    *(uint2*)&P[wv * 16 + r][g * 4]      = pw0;
    *(uint2*)&P[wv * 16 + r][16 + g * 4] = pw1;
    if (g == 0) alphab[wv * 16 + r] = alpha;
    __syncthreads();                   // B1: P/alpha visible; all LDS reads done
    if (tt + 1 < nt) stage(t0 + 32);   // overwrite K/V/kpe; drained at B2

#pragma unroll
    for (int mc = 0; mc < 4; ++mc) {
      bf16x8 pa = *(const bf16x8*)&P[mc * 16 + r][g * 8];
      f32x4 a4 = *(const f32x4*)&alphab[mc * 16 + g * 4];
#pragma unroll
      for (int nc = 0; nc < 2; ++nc) {
        f32x4 t = acc[mc][nc] * a4;
        acc[mc][nc] = MFMA16(pa, vf[nc], t, 0, 0, 0);
      }
    }
    __syncthreads();                   // B2: stage drained; P safe to rewrite
  }

  if (g == 0) lbuf[wv * 16 + r] = l_run;
  __syncthreads();
  u16* O = oflat + ((long)b * SS + qa) * DIM + h * VH;
#pragma unroll
  for (int mc = 0; mc < 4; ++mc) {
    f32x4 li = *(const f32x4*)&lbuf[mc * 16 + g * 4];
#pragma unroll
    for (int e = 0; e < 4; e++) li[e] = 1.f / li[e];
#pragma unroll
    for (int nc = 0; nc < 2; ++nc) {
      int col = wv * 32 + nc * 16 + r;
#pragma unroll
      for (int e = 0; e < 4; e++)
        O[(long)(mc * 16 + g * 4 + e) * DIM + col] = f2b(acc[mc][nc][e] * li[e]);
    }
  }
}

// ---------------- host launch ----------------
extern "C" void kernel_launch(void* const* d_in, const int* in_sizes, int n_in,
                              void* d_out, int out_size, void* d_ws, size_t ws_size,
                              hipStream_t stream) {
  (void)in_sizes; (void)n_in; (void)out_size; (void)ws_size;
  const float* x    = (const float*)d_in[0];
  const float* fc   = (const float*)d_in[2];
  const float* fs   = (const float*)d_in[3];
  const float* wqa  = (const float*)d_in[4];
  const float* qnw  = (const float*)d_in[5];
  const float* wqb  = (const float*)d_in[6];
  const float* wkva = (const float*)d_in[7];
  const float* kvnw = (const float*)d_in[8];
  const float* wkvb = (const float*)d_in[9];
  const float* wo   = (const float*)d_in[10];
  float* out = (float*)d_out;

  char* w = (char*)d_ws;
  size_t off = 0;
  auto alloc = [&](size_t bytes) {
    void* p = w + off;
    off += (bytes + 255) & ~(size_t)255;
    return p;
  };
  u16* wbcat  = (u16*)alloc((size_t)NH * 256 * KVR * 2);
  u16* wo_b   = (u16*)alloc((size_t)DIM * DIM * 2);
  u16* qnope  = (u16*)alloc((size_t)NH * NTOK * NOPE * 2);
  u16* qpe    = (u16*)alloc((size_t)NH * NTOK * ROPE * 2);
  u16* knope  = (u16*)alloc((size_t)NH * NTOK * NOPE * 2);
  u16* vhead  = (u16*)alloc((size_t)NH * NTOK * VH * 2);
  u16* kvb    = (u16*)alloc((size_t)NTOK * KVR * 2);
  u16* kpe_sw = (u16*)alloc((size_t)BB * SS * ROPE * 2);
  u16* oflat  = (u16*)alloc((size_t)NTOK * DIM * 2);
  u16* x_bf   = (u16*)alloc((size_t)NTOK * DIM * 2);
  u16* wcat   = (u16*)alloc((size_t)NFUSE * DIM * 2);
  u16* wqb_b  = (u16*)alloc((size_t)NH * QKH * QR * 2);
  u16* qn     = (u16*)alloc((size_t)NTOK * QR * 2);
  u16* C1     = (u16*)alloc((size_t)NTOK * NFUSE * 2);

  // FIX vs r20: wkvb region is 2,097,152 floats = 1024 blocks, grid 10304
  // (was 11328 -> 1024 extra blocks read/wrote 4MB past wkvb/wbcat -> fault).
  cvt_all<<<10304, 256, 0, stream>>>(x, x_bf, wqa, wkva, wcat, wqb, wqb_b,
                                     wo, wo_b, wkvb, wbcat);

  // fused [q_a | kv_full] = x @ [wq_a; wkv_a]^T   (4096 x 1600, K=2048) -> bf16 C1
  gemm_bt<1><<<dim3(13, NTOK / 128, 1), 256, 0, stream>>>(
      x_bf, wcat, C1, nullptr, nullptr, nullptr,
      NTOK, NFUSE, DIM, DIM, DIM, NFUSE, 0, 0, 0, 1.f);
  post_qkv<<<NTOK, 256, 0, stream>>>(C1, qnw, kvnw, fc, fs, qn, kvb, kpe_sw);
  // q = qn @ wq_b^T with q-split + rope epilogue (both parts pre-scaled)
  gemm_bt<2><<<dim3(NH * QKH / 128, NTOK / 128, 1), 256, 0, stream>>>(
      qn, wqb_b, qnope, qpe, fc, fs,
      NTOK, NH * QKH, QR, QR, QR, 0, 0, 0, 0, SCALE_);
  // [k_nope | v][h] = kv @ wkv_b[h]^T  (4096 x 256, K=512) -> knope + vhead
  gemm_bt<5><<<dim3(2, NTOK / 128, NH), 256, 0, stream>>>(
      kvb, wbcat, knope, vhead, nullptr, nullptr,
      NTOK, 256, KVR, KVR, KVR, 256,
      0, (long)256 * KVR, 0, 1.f);
  attn_kernel<<<dim3(1024, 1, 1), 256, 0, stream>>>(
      qnope, qpe, knope, vhead, kpe_sw, oflat);
  gemm_bt<0><<<dim3(DIM / 128, NTOK / 128, 1), 256, 0, stream>>>(
      oflat, wo_b, out, nullptr, nullptr, nullptr,
      NTOK, DIM, DIM, DIM, DIM, DIM, 0, 0, 0, 1.f);
}

// Round 22
// 241.326 us; speedup vs baseline: 1.7570x; 1.0046x over previous
//
#include <hip/hip_runtime.h>
#include <hip/hip_bf16.h>
#include <stdint.h>

#define BB 4
#define SS 1024
#define DIM 2048
#define NH 16
#define QR 1024
#define KVR 512
#define NOPE 128
#define ROPE 64
#define VH 128
#define QKH 192
#define NTOK 4096
#define NFUSE 1600   // QR + 576

static constexpr float SCALE_ = 0.07216878364870322f; // 192^-0.5
static constexpr float EPS_ = 1e-6f;

typedef unsigned short u16;
typedef unsigned int u32;
using f32x4  = __attribute__((ext_vector_type(4))) float;
using bf16x8 = __attribute__((ext_vector_type(8))) __bf16;

#define MFMA16 __builtin_amdgcn_mfma_f32_16x16x32_bf16

__device__ __forceinline__ u16 f2b(float f) {
  u32 u = __float_as_uint(f);
  u32 r = u + 0x7fffu + ((u >> 16) & 1u);   // RNE
  return (u16)(r >> 16);
}
__device__ __forceinline__ u32 pk2(float a, float b) {
  return (u32)f2b(a) | ((u32)f2b(b) << 16);
}
__device__ __forceinline__ float b2f(u32 hi16) {
  return __uint_as_float(hi16 << 16);
}
__device__ __forceinline__ void gll16(const u16* g, u16* l) {
  __builtin_amdgcn_global_load_lds(
      (const __attribute__((address_space(1))) void*)g,
      (__attribute__((address_space(3))) void*)l, 16, 0, 0);
}

// ---------------- fused f32->bf16 conversions (6 regions, 1 launch) ----------------
__global__ __launch_bounds__(256) void cvt_all(
    const float* __restrict__ x, u16* __restrict__ x_bf,
    const float* __restrict__ wqa, const float* __restrict__ wkva,
    u16* __restrict__ wcat,
    const float* __restrict__ wqb, u16* __restrict__ wqb_b,
    const float* __restrict__ wo, u16* __restrict__ wo_b,
    const float* __restrict__ wkvb, u16* __restrict__ wbcat) {
  int bid = blockIdx.x;
  int tid = threadIdx.x;
  const float* src; u16* dst; long i;
  if (bid < 4096)      { src = x;    dst = x_bf;  i = (long)bid * 2048; }
  else if (bid < 5120) { src = wqa;  dst = wcat;  i = (long)(bid - 4096) * 2048; }
  else if (bid < 6656) { src = wqb;  dst = wqb_b; i = (long)(bid - 5120) * 2048; }
  else if (bid < 7232) { src = wkva; dst = wcat + (long)QR * DIM; i = (long)(bid - 6656) * 2048; }
  else if (bid < 9280) { src = wo;   dst = wo_b;  i = (long)(bid - 7232) * 2048; }
  else                 { src = wkvb; dst = wbcat; i = (long)(bid - 9280) * 2048; }
  i += tid * 8;
  float4 a = *(const float4*)&src[i];
  float4 b = *(const float4*)&src[i + 4];
  uint4 o;
  o.x = pk2(a.x, a.y); o.y = pk2(a.z, a.w);
  o.z = pk2(b.x, b.y); o.w = pk2(b.z, b.w);
  *(uint4*)&dst[i] = o;
}

// ---------------- post_qkv: rms_q + kv post fused (C1 bf16, ldc=1600) ----------------
__global__ __launch_bounds__(256) void post_qkv(
    const u16* __restrict__ C1, const float* __restrict__ qw,
    const float* __restrict__ kw, const float* __restrict__ fc,
    const float* __restrict__ fs, u16* __restrict__ qn,
    u16* __restrict__ kv, u16* __restrict__ kpe_sw) {
  int r = blockIdx.x, tid = threadIdx.x;
  int b = r >> 10, t = r & (SS - 1);
  const u16* row = C1 + (long)r * NFUSE;
  u32 qa_ = *(const u32*)&row[tid * 4];
  u32 qb_ = *(const u32*)&row[tid * 4 + 2];
  float q0 = b2f(qa_ & 0xffffu), q1 = b2f(qa_ >> 16);
  float q2 = b2f(qb_ & 0xffffu), q3 = b2f(qb_ >> 16);
  float ssq = q0 * q0 + q1 * q1 + q2 * q2 + q3 * q3;
  u32 ka_ = *(const u32*)&row[QR + tid * 2];
  float k0 = b2f(ka_ & 0xffffu), k1 = b2f(ka_ >> 16);
  float ssk = k0 * k0 + k1 * k1;
  for (int m = 1; m < 64; m <<= 1) {
    ssq += __shfl_xor(ssq, m);
    ssk += __shfl_xor(ssk, m);
  }
  __shared__ float redq[4], redk[4];
  if ((tid & 63) == 0) { redq[tid >> 6] = ssq; redk[tid >> 6] = ssk; }
  __syncthreads();
  float scq = rsqrtf((redq[0] + redq[1] + redq[2] + redq[3]) / QR + EPS_);
  float sck = rsqrtf((redk[0] + redk[1] + redk[2] + redk[3]) / KVR + EPS_);
  const float4 wv4 = *(const float4*)&qw[tid * 4];
  uint2 o;
  o.x = pk2(q0 * scq * wv4.x, q1 * scq * wv4.y);
  o.y = pk2(q2 * scq * wv4.z, q3 * scq * wv4.w);
  *(uint2*)&qn[(long)r * QR + tid * 4] = o;
  int c = tid * 2;
  float y0 = k0 * sck * kw[c], y1 = k1 * sck * kw[c + 1];
  *(u32*)&kv[(long)r * KVR + c] = pk2(y0, y1);
  if (tid < 32) {
    int xm = (t & 7) << 3;
    u32 pa = *(const u32*)&row[QR + KVR + tid * 2];
    float x0 = b2f(pa & 0xffffu), x1 = b2f(pa >> 16);
    float cc = fc[t * 32 + tid], sn = fs[t * 32 + tid];
    *(u32*)&kpe_sw[((long)b * SS + t) * ROPE + ((tid * 2) ^ xm)] =
        pk2(x0 * cc - x1 * sn, x0 * sn + x1 * cc);
  }
}

// ---------------- GEMM: C(M,N) = A(M,K) * B(N,K)^T ----------------
// MODE 0: f32 C.  MODE 1: bf16 C.  MODE 2: q-split + rope epilogue.
// MODE 5: kv-split epilogue — knope (row-XOR swizzle) | vhead (v8-subtiled).
template <int MODE>
__global__ __launch_bounds__(256) void gemm_bt(const u16* __restrict__ Ag,
                                               const u16* __restrict__ Bg,
                                               void* __restrict__ Cg,
                                               void* __restrict__ Cg2,
                                               const float* __restrict__ fcp,
                                               const float* __restrict__ fsp,
                                               int M, int N, int K,
                                               int lda, int ldb, int ldc,
                                               long sA, long sB, long sC,
                                               float oscale) {
  const u16* A = Ag + (long)blockIdx.z * sA;
  const u16* Bm = Bg + (long)blockIdx.z * sB;
  const int nbx = gridDim.x;
  int bidf = blockIdx.y * nbx + blockIdx.x;
  {
    const int nwg = nbx * gridDim.y;
    if ((nwg & 7) == 0)
      bidf = (bidf & 7) * (nwg >> 3) + (bidf >> 3);   // bijective XCD chunks
  }
  const int row0 = (bidf / nbx) * 128;
  const int col0 = (bidf % nbx) * 128;
  const int tid = threadIdx.x;
  const int wave = tid >> 6, lane = tid & 63;
  const int g = lane >> 4, r = lane & 15;
  const int wr = wave >> 1, wc = wave & 1;

  __shared__ u16 As[2][128 * 32];
  __shared__ u16 Bs[2][128 * 32];

  f32x4 acc[4][4] = {};
  const int nk = K >> 5;

  auto stage = [&](int kt, int p) {
    int k0 = kt << 5;
#pragma unroll
    for (int j = 0; j < 2; ++j) {
      int ldsoff = (j * 4096 + wave * 1024) >> 1;
      int rowi = j * 64 + wave * 16 + (lane >> 2);
      int coli = (lane & 3) << 3;
      const u16* ga = A + (long)(row0 + rowi) * lda + k0 + coli;
      gll16(ga, &As[p][ldsoff]);
      int rb = col0 + rowi; if (rb > N - 1) rb = N - 1;
      const u16* gb = Bm + (long)rb * ldb + k0 + coli;
      gll16(gb, &Bs[p][ldsoff]);
    }
  };

  stage(0, 0);
  for (int kt = 0; kt < nk; ++kt) {
    __syncthreads();
    if (kt + 1 < nk) stage(kt + 1, (kt + 1) & 1);
    const int p = kt & 1;
    bf16x8 af[4], bf[4];
#pragma unroll
    for (int i = 0; i < 4; i++) {
      af[i] = *(const bf16x8*)&As[p][(wr * 64 + i * 16 + r) * 32 + g * 8];
      bf[i] = *(const bf16x8*)&Bs[p][(wc * 64 + i * 16 + r) * 32 + g * 8];
    }
#pragma unroll
    for (int i = 0; i < 4; i++)
#pragma unroll
      for (int j = 0; j < 4; j++)
        acc[i][j] = MFMA16(af[i], bf[j], acc[i][j], 0, 0, 0);
  }

#pragma unroll
  for (int i = 0; i < 4; i++)
#pragma unroll
    for (int j = 0; j < 4; j++) {
      int rowb = row0 + wr * 64 + i * 16 + g * 4;
      int colc = col0 + wc * 64 + j * 16 + r;
      if constexpr (MODE == 2) {
        int hh = colc / QKH;
        int dd = colc - hh * QKH;
        if (dd < NOPE) {
          u16* qn = (u16*)Cg;
#pragma unroll
          for (int e = 0; e < 4; e++)
            qn[((long)hh * NTOK + rowb + e) * NOPE + dd] = f2b(acc[i][j][e] * oscale);
        } else {
          u16* qpr = (u16*)Cg2;
          int jr = (dd - NOPE) >> 1;
          const int odd = dd & 1;
#pragma unroll
          for (int e = 0; e < 4; e++) {
            float own = acc[i][j][e];
            float partner = __shfl_xor(own, 1);
            int s = (rowb + e) & (SS - 1);
            float cc = fcp[s * 32 + jr], sn = fsp[s * 32 + jr];
            float y = odd ? (partner * sn + own * cc) : (own * cc - partner * sn);
            qpr[((long)hh * NTOK + rowb + e) * ROPE + (dd - NOPE)] = f2b(y * SCALE_);
          }
        }
      } else if constexpr (MODE == 5) {
        const int h = blockIdx.z;
        if (colc < NOPE) {   // knope, row-XOR swizzled
          u16* C = (u16*)Cg + (long)h * NTOK * NOPE;
#pragma unroll
          for (int e = 0; e < 4; e++) {
            int rr = rowb + e;
            C[(long)rr * NOPE + (colc ^ ((rr & 7) << 3))] = f2b(acc[i][j][e]);
          }
        } else {             // vhead, v8-subtiled
          u16* C = (u16*)Cg2 + (long)h * NTOK * VH;
          int vcol = colc - NOPE;
#pragma unroll
          for (int e = 0; e < 4; e++) {
            int rr = rowb + e;
            C[((long)(rr >> 3) * VH + vcol) * 8 + (rr & 7)] = f2b(acc[i][j][e]);
          }
        }
      } else if (colc < N) {
        if constexpr (MODE == 1) {
          u16* C = (u16*)Cg + (long)blockIdx.z * sC;
#pragma unroll
          for (int e = 0; e < 4; e++)
            C[(long)(rowb + e) * ldc + colc] = f2b(acc[i][j][e] * oscale);
        } else {
          float* C = (float*)Cg + (long)blockIdx.z * sC;
#pragma unroll
          for (int e = 0; e < 4; e++)
            C[(long)(rowb + e) * ldc + colc] = acc[i][j][e] * oscale;
        }
      }
    }
}

// ---------------- flash attention v22: non-absorbed, KVBLK=64 ----------------
// 1024 blocks (4b x 16h x 16 chunks of 64 rows), big chunks first, XCD-pinned.
// 4 waves; per-wave 16 q-rows for QK+softmax; PV: all 64 rows x own 32 V-cols.
// 64-key tiles: halves barriers, rescale and per-key bookkeeping vs KVBLK=32
// (VALU was 52% busy - the binding pipe). LDS ~50 KB -> 3 blocks/CU.
__global__ __launch_bounds__(256) void attn_kernel(
    const u16* __restrict__ qnope, const u16* __restrict__ qpe,
    const u16* __restrict__ knope, const u16* __restrict__ vhead,
    const u16* __restrict__ kpe_sw, u16* __restrict__ oflat) {
  const int bid = blockIdx.x;
  const int xcd = bid & 7, idx = bid >> 3;
  const int b = xcd >> 1;
  const int h = idx & 15;
  const int jj = ((idx >> 4) << 1) | (xcd & 1);   // 0..15
  const int jc = 15 - jj;                         // big chunks first
  const int qa = jc * 64;
  const int nt = jc + 1;                          // 64-key tiles
  const int wv = threadIdx.x >> 6, lane = threadIdx.x & 63;
  const int g = lane >> 4, r = lane & 15;
  const int xm = (r & 7) << 3;
  const int keb = (g * 8) ^ xm;
  const int kob = keb - 2 * (xm & 32);

  __shared__ __attribute__((aligned(16))) u16 Ks[64 * 128];   // 16 KB swz K
  __shared__ __attribute__((aligned(16))) u16 Vs[64 * 128];   // 16 KB subtiled V
  __shared__ __attribute__((aligned(16))) u16 Kp[64 * 64];    // 8 KB swz kpe
  __shared__ __attribute__((aligned(16))) u16 P[64][72];      // 9 KB
  __shared__ float alphab[64];
  __shared__ float lbuf[64];

  const u16* KNg = knope + ((long)h * NTOK + (long)b * SS) * 128;
  const u16* VHg = vhead + (long)h * NTOK * 128;   // subtiled; tok = b*SS+t
  const u16* KPg = kpe_sw + (long)b * SS * ROPE;
  const long vbase = (long)b * SS * 128;

  auto stage = [&](int t0) {
#pragma unroll
    for (int i = 0; i < 4; ++i) {
      int row = wv * 16 + i * 4;   // wave-uniform; each issue = 4 rows x 128
      gll16(KNg + (long)(t0 + row) * 128 + lane * 8, &Ks[row * 128]);
      gll16(VHg + vbase + (long)t0 * 128 + (wv * 4 + i) * 512 + lane * 8,
            &Vs[(wv * 4 + i) * 512]);
    }
#pragma unroll
    for (int i = 0; i < 2; ++i) {
      int row = wv * 16 + i * 8;   // each issue = 8 rows x 64
      gll16(KPg + (long)(t0 + row) * ROPE + lane * 8, &Kp[row * 64]);
    }
  };

  const int q_row = qa + wv * 16 + r;
  const u16* Q  = qnope + ((long)h * NTOK + (long)b * SS + q_row) * 128;
  const u16* Qp = qpe   + ((long)h * NTOK + (long)b * SS + q_row) * ROPE;
  bf16x8 qf[6];
#pragma unroll
  for (int c = 0; c < 4; ++c) qf[c] = *(const bf16x8*)&Q[c * 32 + g * 8];
  qf[4] = *(const bf16x8*)&Qp[g * 8];
  qf[5] = *(const bf16x8*)&Qp[32 + g * 8];

  f32x4 acc[4][2];
#pragma unroll
  for (int i = 0; i < 4; i++)
#pragma unroll
    for (int jn = 0; jn < 2; jn++) acc[i][jn] = f32x4{0.f, 0.f, 0.f, 0.f};
  float m_run = -1e30f, l_run = 0.f;

  stage(0);
  __syncthreads();

  for (int tt = 0; tt < nt; ++tt) {
    const int t0 = tt << 6;

    // QK^T over 64 keys (4 row-groups of 16): 4 nope + 2 rope c-steps
    f32x4 st[4];
#pragma unroll
    for (int jn = 0; jn < 4; jn++) st[jn] = f32x4{0.f, 0.f, 0.f, 0.f};
#pragma unroll
    for (int c = 0; c < 4; ++c) {
      int off = ((c & 1) ? kob : keb) + c * 32;
#pragma unroll
      for (int jn = 0; jn < 4; jn++) {
        bf16x8 k = *(const bf16x8*)&Ks[(jn * 16 + r) * 128 + off];
        st[jn] = MFMA16(k, qf[c], st[jn], 0, 0, 0);
      }
    }
#pragma unroll
    for (int c = 0; c < 2; ++c) {
      int off = c ? (kob + 32) : keb;
#pragma unroll
      for (int jn = 0; jn < 4; jn++) {
        bf16x8 k = *(const bf16x8*)&Kp[(jn * 16 + r) * 64 + off];
        st[jn] = MFMA16(k, qf[4 + c], st[jn], 0, 0, 0);
      }
    }

    // V fragments -> regs (precede B1; stage overwrites Vs)
    bf16x8 vf[2][2];
#pragma unroll
    for (int ks = 0; ks < 2; ++ks)
#pragma unroll
      for (int nc = 0; nc < 2; ++nc)
        vf[ks][nc] = *(const bf16x8*)
            &Vs[((((ks << 2) + g) << 7) + (wv << 5) + (nc << 4) + r) << 3];

    // scores -> sv[16] (mask only diagonal tile), row max
    float sv[16];
    float smax = -1e30f;
    if (t0 + 63 > qa) {
#pragma unroll
      for (int jn = 0; jn < 4; jn++)
#pragma unroll
        for (int i = 0; i < 4; i++) {
          int t = t0 + jn * 16 + g * 4 + i;
          float v = (t <= q_row) ? st[jn][i] : -1e30f;
          sv[jn * 4 + i] = v;
          smax = fmaxf(smax, v);
        }
    } else {
#pragma unroll
      for (int jn = 0; jn < 4; jn++)
#pragma unroll
        for (int i = 0; i < 4; i++) {
          sv[jn * 4 + i] = st[jn][i];
          smax = fmaxf(smax, st[jn][i]);
        }
    }
    smax = fmaxf(smax, __shfl_xor(smax, 16));
    smax = fmaxf(smax, __shfl_xor(smax, 32));
    float m_new = fmaxf(m_run, smax);
    float alpha = __expf(m_run - m_new);
    float ps = 0.f;
#pragma unroll
    for (int i = 0; i < 16; i++) {
      sv[i] = (sv[i] < -1e29f) ? 0.f : __expf(sv[i] - m_new);
      ps += sv[i];
    }
    ps += __shfl_xor(ps, 16);
    ps += __shfl_xor(ps, 32);
    l_run = l_run * alpha + ps;
    m_run = m_new;

#pragma unroll
    for (int jn = 0; jn < 4; jn++) {
      uint2 pw;
      pw.x = pk2(sv[jn * 4], sv[jn * 4 + 1]);
      pw.y = pk2(sv[jn * 4 + 2], sv[jn * 4 + 3]);
      *(uint2*)&P[wv * 16 + r][jn * 16 + g * 4] = pw;
    }
    if (g == 0) alphab[wv * 16 + r] = alpha;
    __syncthreads();                   // B1: P/alpha visible; all LDS reads done
    if (tt + 1 < nt) stage(t0 + 64);   // overwrite K/V/kpe; drained at B2

    // PV: all 64 rows x own 32 cols, 64 keys in two 32-key halves
#pragma unroll
    for (int mc = 0; mc < 4; ++mc) {
      f32x4 a4 = *(const f32x4*)&alphab[mc * 16 + g * 4];
      bf16x8 pa0 = *(const bf16x8*)&P[mc * 16 + r][g * 8];
      bf16x8 pa1 = *(const bf16x8*)&P[mc * 16 + r][32 + g * 8];
#pragma unroll
      for (int nc = 0; nc < 2; ++nc) {
        f32x4 t = acc[mc][nc] * a4;
        t = MFMA16(pa0, vf[0][nc], t, 0, 0, 0);
        acc[mc][nc] = MFMA16(pa1, vf[1][nc], t, 0, 0, 0);
      }
    }
    __syncthreads();                   // B2: stage drained; P safe to rewrite
  }

  if (g == 0) lbuf[wv * 16 + r] = l_run;
  __syncthreads();
  u16* O = oflat + ((long)b * SS + qa) * DIM + h * VH;
#pragma unroll
  for (int mc = 0; mc < 4; ++mc) {
    f32x4 li = *(const f32x4*)&lbuf[mc * 16 + g * 4];
#pragma unroll
    for (int e = 0; e < 4; e++) li[e] = 1.f / li[e];
#pragma unroll
    for (int nc = 0; nc < 2; ++nc) {
      int col = wv * 32 + nc * 16 + r;
#pragma unroll
      for (int e = 0; e < 4; e++)
        O[(long)(mc * 16 + g * 4 + e) * DIM + col] = f2b(acc[mc][nc][e] * li[e]);
    }
  }
}

// ---------------- host launch ----------------
extern "C" void kernel_launch(void* const* d_in, const int* in_sizes, int n_in,
                              void* d_out, int out_size, void* d_ws, size_t ws_size,
                              hipStream_t stream) {
  (void)in_sizes; (void)n_in; (void)out_size; (void)ws_size;
  const float* x    = (const float*)d_in[0];
  const float* fc   = (const float*)d_in[2];
  const float* fs   = (const float*)d_in[3];
  const float* wqa  = (const float*)d_in[4];
  const float* qnw  = (const float*)d_in[5];
  const float* wqb  = (const float*)d_in[6];
  const float* wkva = (const float*)d_in[7];
  const float* kvnw = (const float*)d_in[8];
  const float* wkvb = (const float*)d_in[9];
  const float* wo   = (const float*)d_in[10];
  float* out = (float*)d_out;

  char* w = (char*)d_ws;
  size_t off = 0;
  auto alloc = [&](size_t bytes) {
    void* p = w + off;
    off += (bytes + 255) & ~(size_t)255;
    return p;
  };
  u16* wbcat  = (u16*)alloc((size_t)NH * 256 * KVR * 2);
  u16* wo_b   = (u16*)alloc((size_t)DIM * DIM * 2);
  u16* qnope  = (u16*)alloc((size_t)NH * NTOK * NOPE * 2);
  u16* qpe    = (u16*)alloc((size_t)NH * NTOK * ROPE * 2);
  u16* knope  = (u16*)alloc((size_t)NH * NTOK * NOPE * 2);
  u16* vhead  = (u16*)alloc((size_t)NH * NTOK * VH * 2);
  u16* kvb    = (u16*)alloc((size_t)NTOK * KVR * 2);
  u16* kpe_sw = (u16*)alloc((size_t)BB * SS * ROPE * 2);
  u16* oflat  = (u16*)alloc((size_t)NTOK * DIM * 2);
  u16* x_bf   = (u16*)alloc((size_t)NTOK * DIM * 2);
  u16* wcat   = (u16*)alloc((size_t)NFUSE * DIM * 2);
  u16* wqb_b  = (u16*)alloc((size_t)NH * QKH * QR * 2);
  u16* qn     = (u16*)alloc((size_t)NTOK * QR * 2);
  u16* C1     = (u16*)alloc((size_t)NTOK * NFUSE * 2);

  cvt_all<<<10304, 256, 0, stream>>>(x, x_bf, wqa, wkva, wcat, wqb, wqb_b,
                                     wo, wo_b, wkvb, wbcat);

  // fused [q_a | kv_full] = x @ [wq_a; wkv_a]^T   (4096 x 1600, K=2048) -> bf16 C1
  gemm_bt<1><<<dim3(13, NTOK / 128, 1), 256, 0, stream>>>(
      x_bf, wcat, C1, nullptr, nullptr, nullptr,
      NTOK, NFUSE, DIM, DIM, DIM, NFUSE, 0, 0, 0, 1.f);
  post_qkv<<<NTOK, 256, 0, stream>>>(C1, qnw, kvnw, fc, fs, qn, kvb, kpe_sw);
  // q = qn @ wq_b^T with q-split + rope epilogue (both parts pre-scaled)
  gemm_bt<2><<<dim3(NH * QKH / 128, NTOK / 128, 1), 256, 0, stream>>>(
      qn, wqb_b, qnope, qpe, fc, fs,
      NTOK, NH * QKH, QR, QR, QR, 0, 0, 0, 0, SCALE_);
  // [k_nope | v][h] = kv @ wkv_b[h]^T  (4096 x 256, K=512) -> knope + vhead
  gemm_bt<5><<<dim3(2, NTOK / 128, NH), 256, 0, stream>>>(
      kvb, wbcat, knope, vhead, nullptr, nullptr,
      NTOK, 256, KVR, KVR, KVR, 256,
      0, (long)256 * KVR, 0, 1.f);
  attn_kernel<<<dim3(1024, 1, 1), 256, 0, stream>>>(
      qnope, qpe, knope, vhead, kpe_sw, oflat);
  gemm_bt<0><<<dim3(DIM / 128, NTOK / 128, 1), 256, 0, stream>>>(
      oflat, wo_b, out, nullptr, nullptr, nullptr,
      NTOK, DIM, DIM, DIM, DIM, DIM, 0, 0, 0, 1.f);
}

// Round 23
// 236.539 us; speedup vs baseline: 1.7926x; 1.0202x over previous
//
#include <hip/hip_runtime.h>
#include <hip/hip_bf16.h>
#include <stdint.h>

#define BB 4
#define SS 1024
#define DIM 2048
#define NH 16
#define QR 1024
#define KVR 512
#define NOPE 128
#define ROPE 64
#define VH 128
#define QKH 192
#define NTOK 4096
#define NFUSE 1600   // QR + 576

static constexpr float SCALE_ = 0.07216878364870322f; // 192^-0.5
static constexpr float EPS_ = 1e-6f;

typedef unsigned short u16;
typedef unsigned int u32;
using f32x4  = __attribute__((ext_vector_type(4))) float;
using bf16x8 = __attribute__((ext_vector_type(8))) __bf16;

#define MFMA16 __builtin_amdgcn_mfma_f32_16x16x32_bf16

__device__ __forceinline__ u16 f2b(float f) {
  u32 u = __float_as_uint(f);
  u32 r = u + 0x7fffu + ((u >> 16) & 1u);   // RNE
  return (u16)(r >> 16);
}
__device__ __forceinline__ u32 pk2(float a, float b) {
  return (u32)f2b(a) | ((u32)f2b(b) << 16);
}
__device__ __forceinline__ float b2f(u32 hi16) {
  return __uint_as_float(hi16 << 16);
}
__device__ __forceinline__ void gll16(const u16* g, u16* l) {
  __builtin_amdgcn_global_load_lds(
      (const __attribute__((address_space(1))) void*)g,
      (__attribute__((address_space(3))) void*)l, 16, 0, 0);
}

// ---------------- fused f32->bf16 conversions (6 regions, 1 launch) ----------------
__global__ __launch_bounds__(256) void cvt_all(
    const float* __restrict__ x, u16* __restrict__ x_bf,
    const float* __restrict__ wqa, const float* __restrict__ wkva,
    u16* __restrict__ wcat,
    const float* __restrict__ wqb, u16* __restrict__ wqb_b,
    const float* __restrict__ wo, u16* __restrict__ wo_b,
    const float* __restrict__ wkvb, u16* __restrict__ wbcat) {
  int bid = blockIdx.x;
  int tid = threadIdx.x;
  const float* src; u16* dst; long i;
  if (bid < 4096)      { src = x;    dst = x_bf;  i = (long)bid * 2048; }
  else if (bid < 5120) { src = wqa;  dst = wcat;  i = (long)(bid - 4096) * 2048; }
  else if (bid < 6656) { src = wqb;  dst = wqb_b; i = (long)(bid - 5120) * 2048; }
  else if (bid < 7232) { src = wkva; dst = wcat + (long)QR * DIM; i = (long)(bid - 6656) * 2048; }
  else if (bid < 9280) { src = wo;   dst = wo_b;  i = (long)(bid - 7232) * 2048; }
  else                 { src = wkvb; dst = wbcat; i = (long)(bid - 9280) * 2048; }
  i += tid * 8;
  float4 a = *(const float4*)&src[i];
  float4 b = *(const float4*)&src[i + 4];
  uint4 o;
  o.x = pk2(a.x, a.y); o.y = pk2(a.z, a.w);
  o.z = pk2(b.x, b.y); o.w = pk2(b.z, b.w);
  *(uint4*)&dst[i] = o;
}

// ---------------- post_qkv: rms_q + kv post fused (C1 bf16, ldc=1600) ----------------
__global__ __launch_bounds__(256) void post_qkv(
    const u16* __restrict__ C1, const float* __restrict__ qw,
    const float* __restrict__ kw, const float* __restrict__ fc,
    const float* __restrict__ fs, u16* __restrict__ qn,
    u16* __restrict__ kv, u16* __restrict__ kpe_sw) {
  int r = blockIdx.x, tid = threadIdx.x;
  int b = r >> 10, t = r & (SS - 1);
  const u16* row = C1 + (long)r * NFUSE;
  u32 qa_ = *(const u32*)&row[tid * 4];
  u32 qb_ = *(const u32*)&row[tid * 4 + 2];
  float q0 = b2f(qa_ & 0xffffu), q1 = b2f(qa_ >> 16);
  float q2 = b2f(qb_ & 0xffffu), q3 = b2f(qb_ >> 16);
  float ssq = q0 * q0 + q1 * q1 + q2 * q2 + q3 * q3;
  u32 ka_ = *(const u32*)&row[QR + tid * 2];
  float k0 = b2f(ka_ & 0xffffu), k1 = b2f(ka_ >> 16);
  float ssk = k0 * k0 + k1 * k1;
  for (int m = 1; m < 64; m <<= 1) {
    ssq += __shfl_xor(ssq, m);
    ssk += __shfl_xor(ssk, m);
  }
  __shared__ float redq[4], redk[4];
  if ((tid & 63) == 0) { redq[tid >> 6] = ssq; redk[tid >> 6] = ssk; }
  __syncthreads();
  float scq = rsqrtf((redq[0] + redq[1] + redq[2] + redq[3]) / QR + EPS_);
  float sck = rsqrtf((redk[0] + redk[1] + redk[2] + redk[3]) / KVR + EPS_);
  const float4 wv4 = *(const float4*)&qw[tid * 4];
  uint2 o;
  o.x = pk2(q0 * scq * wv4.x, q1 * scq * wv4.y);
  o.y = pk2(q2 * scq * wv4.z, q3 * scq * wv4.w);
  *(uint2*)&qn[(long)r * QR + tid * 4] = o;
  int c = tid * 2;
  float y0 = k0 * sck * kw[c], y1 = k1 * sck * kw[c + 1];
  *(u32*)&kv[(long)r * KVR + c] = pk2(y0, y1);
  if (tid < 32) {
    int xm = (t & 7) << 3;
    u32 pa = *(const u32*)&row[QR + KVR + tid * 2];
    float x0 = b2f(pa & 0xffffu), x1 = b2f(pa >> 16);
    float cc = fc[t * 32 + tid], sn = fs[t * 32 + tid];
    *(u32*)&kpe_sw[((long)b * SS + t) * ROPE + ((tid * 2) ^ xm)] =
        pk2(x0 * cc - x1 * sn, x0 * sn + x1 * cc);
  }
}

// ---------------- GEMM: C(M,N) = A(M,K) * B(N,K)^T ----------------
// MODE 0: f32 C.  MODE 1: bf16 C.  MODE 2: q-split + rope epilogue.
// MODE 5: kv-split epilogue — knope (row-XOR swizzle) | vhead (v8-subtiled).
template <int MODE>
__global__ __launch_bounds__(256) void gemm_bt(const u16* __restrict__ Ag,
                                               const u16* __restrict__ Bg,
                                               void* __restrict__ Cg,
                                               void* __restrict__ Cg2,
                                               const float* __restrict__ fcp,
                                               const float* __restrict__ fsp,
                                               int M, int N, int K,
                                               int lda, int ldb, int ldc,
                                               long sA, long sB, long sC,
                                               float oscale) {
  const u16* A = Ag + (long)blockIdx.z * sA;
  const u16* Bm = Bg + (long)blockIdx.z * sB;
  const int nbx = gridDim.x;
  int bidf = blockIdx.y * nbx + blockIdx.x;
  {
    const int nwg = nbx * gridDim.y;
    if ((nwg & 7) == 0)
      bidf = (bidf & 7) * (nwg >> 3) + (bidf >> 3);   // bijective XCD chunks
  }
  const int row0 = (bidf / nbx) * 128;
  const int col0 = (bidf % nbx) * 128;
  const int tid = threadIdx.x;
  const int wave = tid >> 6, lane = tid & 63;
  const int g = lane >> 4, r = lane & 15;
  const int wr = wave >> 1, wc = wave & 1;

  __shared__ u16 As[2][128 * 32];
  __shared__ u16 Bs[2][128 * 32];

  f32x4 acc[4][4] = {};
  const int nk = K >> 5;

  auto stage = [&](int kt, int p) {
    int k0 = kt << 5;
#pragma unroll
    for (int j = 0; j < 2; ++j) {
      int ldsoff = (j * 4096 + wave * 1024) >> 1;
      int rowi = j * 64 + wave * 16 + (lane >> 2);
      int coli = (lane & 3) << 3;
      const u16* ga = A + (long)(row0 + rowi) * lda + k0 + coli;
      gll16(ga, &As[p][ldsoff]);
      int rb = col0 + rowi; if (rb > N - 1) rb = N - 1;
      const u16* gb = Bm + (long)rb * ldb + k0 + coli;
      gll16(gb, &Bs[p][ldsoff]);
    }
  };

  stage(0, 0);
  for (int kt = 0; kt < nk; ++kt) {
    __syncthreads();
    if (kt + 1 < nk) stage(kt + 1, (kt + 1) & 1);
    const int p = kt & 1;
    bf16x8 af[4], bf[4];
#pragma unroll
    for (int i = 0; i < 4; i++) {
      af[i] = *(const bf16x8*)&As[p][(wr * 64 + i * 16 + r) * 32 + g * 8];
      bf[i] = *(const bf16x8*)&Bs[p][(wc * 64 + i * 16 + r) * 32 + g * 8];
    }
#pragma unroll
    for (int i = 0; i < 4; i++)
#pragma unroll
      for (int j = 0; j < 4; j++)
        acc[i][j] = MFMA16(af[i], bf[j], acc[i][j], 0, 0, 0);
  }

#pragma unroll
  for (int i = 0; i < 4; i++)
#pragma unroll
    for (int j = 0; j < 4; j++) {
      int rowb = row0 + wr * 64 + i * 16 + g * 4;
      int colc = col0 + wc * 64 + j * 16 + r;
      if constexpr (MODE == 2) {
        int hh = colc / QKH;
        int dd = colc - hh * QKH;
        if (dd < NOPE) {
          u16* qn = (u16*)Cg;
#pragma unroll
          for (int e = 0; e < 4; e++)
            qn[((long)hh * NTOK + rowb + e) * NOPE + dd] = f2b(acc[i][j][e] * oscale);
        } else {
          u16* qpr = (u16*)Cg2;
          int jr = (dd - NOPE) >> 1;
          const int odd = dd & 1;
#pragma unroll
          for (int e = 0; e < 4; e++) {
            float own = acc[i][j][e];
            float partner = __shfl_xor(own, 1);
            int s = (rowb + e) & (SS - 1);
            float cc = fcp[s * 32 + jr], sn = fsp[s * 32 + jr];
            float y = odd ? (partner * sn + own * cc) : (own * cc - partner * sn);
            qpr[((long)hh * NTOK + rowb + e) * ROPE + (dd - NOPE)] = f2b(y * SCALE_);
          }
        }
      } else if constexpr (MODE == 5) {
        const int h = blockIdx.z;
        if (colc < NOPE) {   // knope, row-XOR swizzled
          u16* C = (u16*)Cg + (long)h * NTOK * NOPE;
#pragma unroll
          for (int e = 0; e < 4; e++) {
            int rr = rowb + e;
            C[(long)rr * NOPE + (colc ^ ((rr & 7) << 3))] = f2b(acc[i][j][e]);
          }
        } else {             // vhead, v8-subtiled
          u16* C = (u16*)Cg2 + (long)h * NTOK * VH;
          int vcol = colc - NOPE;
#pragma unroll
          for (int e = 0; e < 4; e++) {
            int rr = rowb + e;
            C[((long)(rr >> 3) * VH + vcol) * 8 + (rr & 7)] = f2b(acc[i][j][e]);
          }
        }
      } else if (colc < N) {
        if constexpr (MODE == 1) {
          u16* C = (u16*)Cg + (long)blockIdx.z * sC;
#pragma unroll
          for (int e = 0; e < 4; e++)
            C[(long)(rowb + e) * ldc + colc] = f2b(acc[i][j][e] * oscale);
        } else {
          float* C = (float*)Cg + (long)blockIdx.z * sC;
#pragma unroll
          for (int e = 0; e < 4; e++)
            C[(long)(rowb + e) * ldc + colc] = acc[i][j][e] * oscale;
        }
      }
    }
}

// ---------------- flash attention v23: non-absorbed, KVBLK=64, paired chunks ----------------
// 512 blocks (4b x 16h x 8 pairs); each block runs chunk pair (15-jp, jp) of
// 64 q-rows => exactly 17 tiles per block (perfect balance, 2 blocks/CU
// co-resident whole kernel). 4 waves; per-wave 16 q-rows for QK+softmax;
// PV: all 64 rows x own 32 V-cols. LDS ~50 KB.
__global__ __launch_bounds__(256) void attn_kernel(
    const u16* __restrict__ qnope, const u16* __restrict__ qpe,
    const u16* __restrict__ knope, const u16* __restrict__ vhead,
    const u16* __restrict__ kpe_sw, u16* __restrict__ oflat) {
  const int bid = blockIdx.x;
  const int xcd = bid & 7, idx = bid >> 3;
  const int b = xcd >> 1;
  const int h = idx & 15;
  const int jp = (idx >> 4) | ((xcd & 1) << 2);   // 0..7
  const int wv = threadIdx.x >> 6, lane = threadIdx.x & 63;
  const int g = lane >> 4, r = lane & 15;
  const int xm = (r & 7) << 3;
  const int keb = (g * 8) ^ xm;
  const int kob = keb - 2 * (xm & 32);

  __shared__ __attribute__((aligned(16))) u16 Ks[64 * 128];   // 16 KB swz K
  __shared__ __attribute__((aligned(16))) u16 Vs[64 * 128];   // 16 KB subtiled V
  __shared__ __attribute__((aligned(16))) u16 Kp[64 * 64];    // 8 KB swz kpe
  __shared__ __attribute__((aligned(16))) u16 P[64][72];      // 9 KB
  __shared__ float alphab[64];
  __shared__ float lbuf[64];

  const u16* KNg = knope + ((long)h * NTOK + (long)b * SS) * 128;
  const u16* VHg = vhead + (long)h * NTOK * 128;   // subtiled; tok = b*SS+t
  const u16* KPg = kpe_sw + (long)b * SS * ROPE;
  const long vbase = (long)b * SS * 128;

  auto stage = [&](int t0) {
#pragma unroll
    for (int i = 0; i < 4; ++i) {
      int row = wv * 16 + i * 4;   // wave-uniform; each issue = 4 rows x 128
      gll16(KNg + (long)(t0 + row) * 128 + lane * 8, &Ks[row * 128]);
      gll16(VHg + vbase + (long)t0 * 128 + (wv * 4 + i) * 512 + lane * 8,
            &Vs[(wv * 4 + i) * 512]);
    }
#pragma unroll
    for (int i = 0; i < 2; ++i) {
      int row = wv * 16 + i * 8;   // each issue = 8 rows x 64
      gll16(KPg + (long)(t0 + row) * ROPE + lane * 8, &Kp[row * 64]);
    }
  };

  for (int seg = 0; seg < 2; ++seg) {
    const int jc = seg ? jp : (15 - jp);   // big chunk first
    const int qa = jc * 64;
    const int nt = jc + 1;                 // 64-key tiles
    const int q_row = qa + wv * 16 + r;

    const u16* Q  = qnope + ((long)h * NTOK + (long)b * SS + q_row) * 128;
    const u16* Qp = qpe   + ((long)h * NTOK + (long)b * SS + q_row) * ROPE;
    bf16x8 qf[6];
#pragma unroll
    for (int c = 0; c < 4; ++c) qf[c] = *(const bf16x8*)&Q[c * 32 + g * 8];
    qf[4] = *(const bf16x8*)&Qp[g * 8];
    qf[5] = *(const bf16x8*)&Qp[32 + g * 8];

    f32x4 acc[4][2];
#pragma unroll
    for (int i = 0; i < 4; i++)
#pragma unroll
      for (int jn = 0; jn < 2; jn++) acc[i][jn] = f32x4{0.f, 0.f, 0.f, 0.f};
    float m_run = -1e30f, l_run = 0.f;

    stage(0);
    __syncthreads();

    for (int tt = 0; tt < nt; ++tt) {
      const int t0 = tt << 6;

      // QK^T over 64 keys (4 row-groups of 16): 4 nope + 2 rope c-steps
      f32x4 st[4];
#pragma unroll
      for (int jn = 0; jn < 4; jn++) st[jn] = f32x4{0.f, 0.f, 0.f, 0.f};
#pragma unroll
      for (int c = 0; c < 4; ++c) {
        int off = ((c & 1) ? kob : keb) + c * 32;
#pragma unroll
        for (int jn = 0; jn < 4; jn++) {
          bf16x8 k = *(const bf16x8*)&Ks[(jn * 16 + r) * 128 + off];
          st[jn] = MFMA16(k, qf[c], st[jn], 0, 0, 0);
        }
      }
#pragma unroll
      for (int c = 0; c < 2; ++c) {
        int off = c ? (kob + 32) : keb;
#pragma unroll
        for (int jn = 0; jn < 4; jn++) {
          bf16x8 k = *(const bf16x8*)&Kp[(jn * 16 + r) * 64 + off];
          st[jn] = MFMA16(k, qf[4 + c], st[jn], 0, 0, 0);
        }
      }

      // V fragments -> regs (precede B1; stage overwrites Vs)
      bf16x8 vf[2][2];
#pragma unroll
      for (int ks = 0; ks < 2; ++ks)
#pragma unroll
        for (int nc = 0; nc < 2; ++nc)
          vf[ks][nc] = *(const bf16x8*)
              &Vs[((((ks << 2) + g) << 7) + (wv << 5) + (nc << 4) + r) << 3];

      // scores -> sv[16] (mask only diagonal tile), row max
      float sv[16];
      float smax = -1e30f;
      if (t0 + 63 > qa) {
#pragma unroll
        for (int jn = 0; jn < 4; jn++)
#pragma unroll
          for (int i = 0; i < 4; i++) {
            int t = t0 + jn * 16 + g * 4 + i;
            float v = (t <= q_row) ? st[jn][i] : -1e30f;
            sv[jn * 4 + i] = v;
            smax = fmaxf(smax, v);
          }
      } else {
#pragma unroll
        for (int jn = 0; jn < 4; jn++)
#pragma unroll
          for (int i = 0; i < 4; i++) {
            sv[jn * 4 + i] = st[jn][i];
            smax = fmaxf(smax, st[jn][i]);
          }
      }
      smax = fmaxf(smax, __shfl_xor(smax, 16));
      smax = fmaxf(smax, __shfl_xor(smax, 32));
      float m_new = fmaxf(m_run, smax);
      float alpha = __expf(m_run - m_new);
      float ps = 0.f;
#pragma unroll
      for (int i = 0; i < 16; i++) {
        sv[i] = (sv[i] < -1e29f) ? 0.f : __expf(sv[i] - m_new);
        ps += sv[i];
      }
      ps += __shfl_xor(ps, 16);
      ps += __shfl_xor(ps, 32);
      l_run = l_run * alpha + ps;
      m_run = m_new;

#pragma unroll
      for (int jn = 0; jn < 4; jn++) {
        uint2 pw;
        pw.x = pk2(sv[jn * 4], sv[jn * 4 + 1]);
        pw.y = pk2(sv[jn * 4 + 2], sv[jn * 4 + 3]);
        *(uint2*)&P[wv * 16 + r][jn * 16 + g * 4] = pw;
      }
      if (g == 0) alphab[wv * 16 + r] = alpha;
      __syncthreads();                   // B1: P/alpha visible; all LDS reads done
      if (tt + 1 < nt) stage(t0 + 64);   // overwrite K/V/kpe; drained at B2

      // PV: all 64 rows x own 32 cols, 64 keys in two 32-key halves
#pragma unroll
      for (int mc = 0; mc < 4; ++mc) {
        f32x4 a4 = *(const f32x4*)&alphab[mc * 16 + g * 4];
        bf16x8 pa0 = *(const bf16x8*)&P[mc * 16 + r][g * 8];
        bf16x8 pa1 = *(const bf16x8*)&P[mc * 16 + r][32 + g * 8];
#pragma unroll
        for (int nc = 0; nc < 2; ++nc) {
          f32x4 t = acc[mc][nc] * a4;
          t = MFMA16(pa0, vf[0][nc], t, 0, 0, 0);
          acc[mc][nc] = MFMA16(pa1, vf[1][nc], t, 0, 0, 0);
        }
      }
      __syncthreads();                   // B2: stage drained; P safe to rewrite
    }

    if (g == 0) lbuf[wv * 16 + r] = l_run;
    __syncthreads();
    u16* O = oflat + ((long)b * SS + qa) * DIM + h * VH;
#pragma unroll
    for (int mc = 0; mc < 4; ++mc) {
      f32x4 li = *(const f32x4*)&lbuf[mc * 16 + g * 4];
#pragma unroll
      for (int e = 0; e < 4; e++) li[e] = 1.f / li[e];
#pragma unroll
      for (int nc = 0; nc < 2; ++nc) {
        int col = wv * 32 + nc * 16 + r;
#pragma unroll
        for (int e = 0; e < 4; e++)
          O[(long)(mc * 16 + g * 4 + e) * DIM + col] = f2b(acc[mc][nc][e] * li[e]);
      }
    }
    __syncthreads();                     // lbuf/LDS safe for next seg
  }
}

// ---------------- host launch ----------------
extern "C" void kernel_launch(void* const* d_in, const int* in_sizes, int n_in,
                              void* d_out, int out_size, void* d_ws, size_t ws_size,
                              hipStream_t stream) {
  (void)in_sizes; (void)n_in; (void)out_size; (void)ws_size;
  const float* x    = (const float*)d_in[0];
  const float* fc   = (const float*)d_in[2];
  const float* fs   = (const float*)d_in[3];
  const float* wqa  = (const float*)d_in[4];
  const float* qnw  = (const float*)d_in[5];
  const float* wqb  = (const float*)d_in[6];
  const float* wkva = (const float*)d_in[7];
  const float* kvnw = (const float*)d_in[8];
  const float* wkvb = (const float*)d_in[9];
  const float* wo   = (const float*)d_in[10];
  float* out = (float*)d_out;

  char* w = (char*)d_ws;
  size_t off = 0;
  auto alloc = [&](size_t bytes) {
    void* p = w + off;
    off += (bytes + 255) & ~(size_t)255;
    return p;
  };
  u16* wbcat  = (u16*)alloc((size_t)NH * 256 * KVR * 2);
  u16* wo_b   = (u16*)alloc((size_t)DIM * DIM * 2);
  u16* qnope  = (u16*)alloc((size_t)NH * NTOK * NOPE * 2);
  u16* qpe    = (u16*)alloc((size_t)NH * NTOK * ROPE * 2);
  u16* knope  = (u16*)alloc((size_t)NH * NTOK * NOPE * 2);
  u16* vhead  = (u16*)alloc((size_t)NH * NTOK * VH * 2);
  u16* kvb    = (u16*)alloc((size_t)NTOK * KVR * 2);
  u16* kpe_sw = (u16*)alloc((size_t)BB * SS * ROPE * 2);
  u16* oflat  = (u16*)alloc((size_t)NTOK * DIM * 2);
  u16* x_bf   = (u16*)alloc((size_t)NTOK * DIM * 2);
  u16* wcat   = (u16*)alloc((size_t)NFUSE * DIM * 2);
  u16* wqb_b  = (u16*)alloc((size_t)NH * QKH * QR * 2);
  u16* qn     = (u16*)alloc((size_t)NTOK * QR * 2);
  u16* C1     = (u16*)alloc((size_t)NTOK * NFUSE * 2);

  cvt_all<<<10304, 256, 0, stream>>>(x, x_bf, wqa, wkva, wcat, wqb, wqb_b,
                                     wo, wo_b, wkvb, wbcat);

  // fused [q_a | kv_full] = x @ [wq_a; wkv_a]^T   (4096 x 1600, K=2048) -> bf16 C1
  gemm_bt<1><<<dim3(13, NTOK / 128, 1), 256, 0, stream>>>(
      x_bf, wcat, C1, nullptr, nullptr, nullptr,
      NTOK, NFUSE, DIM, DIM, DIM, NFUSE, 0, 0, 0, 1.f);
  post_qkv<<<NTOK, 256, 0, stream>>>(C1, qnw, kvnw, fc, fs, qn, kvb, kpe_sw);
  // q = qn @ wq_b^T with q-split + rope epilogue (both parts pre-scaled)
  gemm_bt<2><<<dim3(NH * QKH / 128, NTOK / 128, 1), 256, 0, stream>>>(
      qn, wqb_b, qnope, qpe, fc, fs,
      NTOK, NH * QKH, QR, QR, QR, 0, 0, 0, 0, SCALE_);
  // [k_nope | v][h] = kv @ wkv_b[h]^T  (4096 x 256, K=512) -> knope + vhead
  gemm_bt<5><<<dim3(2, NTOK / 128, NH), 256, 0, stream>>>(
      kvb, wbcat, knope, vhead, nullptr, nullptr,
      NTOK, 256, KVR, KVR, KVR, 256,
      0, (long)256 * KVR, 0, 1.f);
  attn_kernel<<<dim3(512, 1, 1), 256, 0, stream>>>(
      qnope, qpe, knope, vhead, kpe_sw, oflat);
  gemm_bt<0><<<dim3(DIM / 128, NTOK / 128, 1), 256, 0, stream>>>(
      oflat, wo_b, out, nullptr, nullptr, nullptr,
      NTOK, DIM, DIM, DIM, DIM, DIM, 0, 0, 0, 1.f);
}